// Round 1
// baseline (1463.849 us; speedup 1.0000x reference)
//
#include <hip/hip_runtime.h>
#include <math.h>

#define N_HID 256
#define N_HEADS 4
#define N_HC 1024       // HEADS*HID
#define N_GRAPHS 64

// ---------------------------------------------------------------- CSR build
__global__ __launch_bounds__(256) void k_deg(const int* __restrict__ dst, int E,
                                             int* __restrict__ deg) {
    int e = blockIdx.x * 256 + threadIdx.x;
    if (e < E) atomicAdd(&deg[dst[e]], 1);
}

__global__ __launch_bounds__(1024) void k_scan(const int* __restrict__ deg,
                                               int* __restrict__ rowstart, int N) {
    __shared__ int sm[1024];
    __shared__ int carry;
    int t = threadIdx.x;
    if (t == 0) { carry = 0; rowstart[0] = 0; }
    __syncthreads();
    for (int base = 0; base < N; base += 1024) {
        int v = (base + t < N) ? deg[base + t] : 0;
        sm[t] = v; __syncthreads();
        for (int off = 1; off < 1024; off <<= 1) {
            int add = (t >= off) ? sm[t - off] : 0;
            __syncthreads();
            sm[t] += add;
            __syncthreads();
        }
        int inc = sm[t] + carry;
        if (base + t < N) rowstart[base + t + 1] = inc;
        __syncthreads();
        if (t == 1023) carry = sm[1023] + carry;
        __syncthreads();
    }
}

__global__ __launch_bounds__(256) void k_fill(const int* __restrict__ src,
                                              const int* __restrict__ dst, int E,
                                              const int* __restrict__ rowstart,
                                              int* __restrict__ cursor,
                                              int* __restrict__ col) {
    int e = blockIdx.x * 256 + threadIdx.x;
    if (e < E) {
        int d = dst[e];
        int p = atomicAdd(&cursor[d], 1);
        col[rowstart[d] + p] = src[e];
    }
}

// ---------------------------------------------------------------- fp32 GEMM
// C[M,N] = A[M,K] @ B[K,N]  (+bias, relu if EPI==1). 64x64 tile, BK=16.
template <int EPI>
__global__ __launch_bounds__(256) void k_gemm(const float* __restrict__ A,
                                              const float* __restrict__ B,
                                              const float* __restrict__ bias,
                                              float* __restrict__ C,
                                              int M, int N, int K) {
    __shared__ float As[16][68];
    __shared__ float Bs[16][68];
    const int bm = blockIdx.y * 64;
    const int bn = blockIdx.x * 64;
    const int tid = threadIdx.x;
    const int tm = (tid >> 4) << 2;
    const int tn = (tid & 15) << 2;
    const int am = tid >> 2;           // 0..63
    const int ak = (tid & 3) << 2;     // 0,4,8,12
    const int bk = tid >> 4;           // 0..15
    const int bn4 = (tid & 15) << 2;   // 0..60
    const bool arow_ok = (bm + am) < M;
    float acc[4][4] = {};
    for (int k0 = 0; k0 < K; k0 += 16) {
        float4 av = make_float4(0.f, 0.f, 0.f, 0.f);
        if (arow_ok) av = *(const float4*)(A + (size_t)(bm + am) * K + k0 + ak);
        float4 bv = *(const float4*)(B + (size_t)(k0 + bk) * N + bn + bn4);
        As[ak + 0][am] = av.x; As[ak + 1][am] = av.y;
        As[ak + 2][am] = av.z; As[ak + 3][am] = av.w;
        *(float4*)&Bs[bk][bn4] = bv;
        __syncthreads();
#pragma unroll
        for (int k = 0; k < 16; k++) {
            const float4 a = *(const float4*)&As[k][tm];
            const float4 b = *(const float4*)&Bs[k][tn];
            const float aa[4] = {a.x, a.y, a.z, a.w};
            const float bb[4] = {b.x, b.y, b.z, b.w};
#pragma unroll
            for (int i = 0; i < 4; i++)
#pragma unroll
                for (int j = 0; j < 4; j++) acc[i][j] += aa[i] * bb[j];
        }
        __syncthreads();
    }
#pragma unroll
    for (int i = 0; i < 4; i++) {
        int row = bm + tm + i;
        if (row >= M) break;
#pragma unroll
        for (int j = 0; j < 4; j++) {
            float v = acc[i][j];
            if (EPI == 1) {
                v += bias[bn + tn + j];
                v = v > 0.f ? v : 0.f;
            }
            C[(size_t)row * N + bn + tn + j] = v;
        }
    }
}

// ---------------------------------------------------------------- attention scores
// a_s[n,h] = sum_c hW[n,h,c]*as[h,c] ; a_d likewise. One wave per (n,h).
__global__ __launch_bounds__(256) void k_scores(const float* __restrict__ hW,
                                                const float* __restrict__ att_s,
                                                const float* __restrict__ att_d,
                                                float* __restrict__ a_s,
                                                float* __restrict__ a_d, int N) {
    int wid = (blockIdx.x * 256 + threadIdx.x) >> 6;
    int lane = threadIdx.x & 63;
    if (wid >= N * N_HEADS) return;
    int n = wid >> 2, h = wid & 3;
    float4 v = *(const float4*)(hW + (size_t)n * N_HC + h * N_HID + lane * 4);
    float4 a = *(const float4*)(att_s + h * N_HID + lane * 4);
    float4 d = *(const float4*)(att_d + h * N_HID + lane * 4);
    float ss = v.x * a.x + v.y * a.y + v.z * a.z + v.w * a.w;
    float sd = v.x * d.x + v.y * d.y + v.z * d.z + v.w * d.w;
#pragma unroll
    for (int off = 32; off > 0; off >>= 1) {
        ss += __shfl_down(ss, off, 64);
        sd += __shfl_down(sd, off, 64);
    }
    if (lane == 0) { a_s[wid] = ss; a_d[wid] = sd; }
}

// ---------------------------------------------------------------- GAT aggregate
// One block (256 thr) per dst node. Online softmax over incoming edges + self loop.
// thread t owns channel t of each of the 4 heads. Epilogue: +bias, ELU.
__global__ __launch_bounds__(256) void k_gat(const float* __restrict__ hW,
                                             const float* __restrict__ a_s,
                                             const float* __restrict__ a_d,
                                             const int* __restrict__ rowstart,
                                             const int* __restrict__ col,
                                             const float* __restrict__ bias,
                                             float* __restrict__ out, int N) {
    int n = blockIdx.x;
    int t = threadIdx.x;
    float m[N_HEADS], s[N_HEADS], acc[N_HEADS];
#pragma unroll
    for (int h = 0; h < N_HEADS; h++) { m[h] = -INFINITY; s[h] = 0.f; acc[h] = 0.f; }
    float adv[N_HEADS];
#pragma unroll
    for (int h = 0; h < N_HEADS; h++) adv[h] = a_d[n * N_HEADS + h];
    int e0 = rowstart[n], e1 = rowstart[n + 1];
    for (int i = e0; i <= e1; i++) {       // i==e1 -> the self loop
        int sn = (i < e1) ? col[i] : n;
        const float* row = hW + (size_t)sn * N_HC;
#pragma unroll
        for (int h = 0; h < N_HEADS; h++) {
            float sc = a_s[sn * N_HEADS + h] + adv[h];
            float e = sc >= 0.f ? sc : 0.2f * sc;     // leaky_relu(0.2)
            float mn = fmaxf(m[h], e);
            float scale = __expf(m[h] - mn);          // exp(-inf)=0 on first edge
            float w = __expf(e - mn);
            s[h] = s[h] * scale + w;
            acc[h] = acc[h] * scale + w * row[h * N_HID + t];
            m[h] = mn;
        }
    }
#pragma unroll
    for (int h = 0; h < N_HEADS; h++) {
        float v = acc[h] / (s[h] + 1e-16f) + bias[h * N_HID + t];
        out[(size_t)n * N_HC + h * N_HID + t] = v > 0.f ? v : (__expf(v) - 1.f);
    }
}

// ---------------------------------------------------------------- pooling
__global__ __launch_bounds__(128) void k_gbounds(const int* __restrict__ batch, int N,
                                                 int* __restrict__ gstart) {
    int g = threadIdx.x;
    if (g > N_GRAPHS) return;
    if (g == N_GRAPHS) { gstart[N_GRAPHS] = N; return; }
    int lo = 0, hi = N;
    while (lo < hi) {
        int mid = (lo + hi) >> 1;
        if (batch[mid] < g) lo = mid + 1; else hi = mid;
    }
    gstart[g] = lo;
}

// block per graph; thread t handles channels t, t+256, t+512, t+768
__global__ __launch_bounds__(256) void k_pool(const float* __restrict__ h,
                                              const int* __restrict__ gstart,
                                              float* __restrict__ gout) {
    int g = blockIdx.x, t = threadIdx.x;
    int s = gstart[g], e = gstart[g + 1];
    float sum[4] = {0.f, 0.f, 0.f, 0.f};
    float mx[4] = {-INFINITY, -INFINITY, -INFINITY, -INFINITY};
    for (int i = s; i < e; i++) {
        const float* row = h + (size_t)i * N_HC;
#pragma unroll
        for (int j = 0; j < 4; j++) {
            float v = row[t + j * 256];
            sum[j] += v;
            mx[j] = fmaxf(mx[j], v);
        }
    }
    float cnt = fmaxf((float)(e - s), 1.f);
#pragma unroll
    for (int j = 0; j < 4; j++) {
        gout[(size_t)g * 2048 + j * 256 + t] = sum[j] / cnt;
        gout[(size_t)g * 2048 + 1024 + j * 256 + t] = mx[j];
    }
}

// ---------------------------------------------------------------- classifier
__global__ __launch_bounds__(256) void k_cls1(const float* __restrict__ g,
                                              const float* __restrict__ Wc1,
                                              const float* __restrict__ bc1,
                                              float* __restrict__ hcls) {
    __shared__ float gs[2048];
    int gb = blockIdx.x, t = threadIdx.x;
    for (int i = t; i < 2048; i += 256) gs[i] = g[(size_t)gb * 2048 + i];
    __syncthreads();
    float acc = 0.f;
    for (int k = 0; k < 2048; k++) acc += gs[k] * Wc1[(size_t)k * 256 + t];
    float v = acc + bc1[t];
    hcls[gb * 256 + t] = v > 0.f ? v : 0.f;
}

__global__ __launch_bounds__(256) void k_cls2(const float* __restrict__ hcls,
                                              const float* __restrict__ Wc2,
                                              const float* __restrict__ bc2,
                                              float* __restrict__ out) {
    int idx = blockIdx.x * 256 + threadIdx.x;
    if (idx >= N_GRAPHS * 5) return;
    int gb = idx / 5, j = idx % 5;
    float acc = 0.f;
    for (int k = 0; k < 256; k++) acc += hcls[gb * 256 + k] * Wc2[k * 5 + j];
    out[idx] = acc + bc2[j];
}

// ---------------------------------------------------------------- launch
extern "C" void kernel_launch(void* const* d_in, const int* in_sizes, int n_in,
                              void* d_out, int out_size, void* d_ws, size_t ws_size,
                              hipStream_t stream) {
    const float* x    = (const float*)d_in[0];
    const int*   ei   = (const int*)d_in[1];
    const int*   batch= (const int*)d_in[2];
    const float* Wp   = (const float*)d_in[3];
    const float* bp   = (const float*)d_in[4];
    const float* W1   = (const float*)d_in[5];
    const float* as1  = (const float*)d_in[6];
    const float* ad1  = (const float*)d_in[7];
    const float* b1   = (const float*)d_in[8];
    const float* W2   = (const float*)d_in[9];
    const float* as2  = (const float*)d_in[10];
    const float* ad2  = (const float*)d_in[11];
    const float* b2   = (const float*)d_in[12];
    const float* Wc1  = (const float*)d_in[13];
    const float* bc1  = (const float*)d_in[14];
    const float* Wc2  = (const float*)d_in[15];
    const float* bc2  = (const float*)d_in[16];
    float* out = (float*)d_out;

    const int N = in_sizes[0] / 768;   // 20000
    const int E = in_sizes[1] / 2;     // 320000
    const int IN_DIM = 768;

    const int* src = ei;
    const int* dst = ei + E;

    char* ws = (char*)d_ws;
    size_t off = 0;
    auto give = [&](size_t bytes) -> void* {
        void* p = ws + off;
        off = (off + bytes + 255) & ~(size_t)255;
        return p;
    };
    float* h0   = (float*)give((size_t)N * N_HID * 4);   // 20.5 MB
    float* hW   = (float*)give((size_t)N * N_HC * 4);    // 82 MB
    float* h1   = (float*)give((size_t)N * N_HC * 4);    // 82 MB (also h2)
    float* a_s  = (float*)give((size_t)N * N_HEADS * 4);
    float* a_d  = (float*)give((size_t)N * N_HEADS * 4);
    int* deg     = (int*)give((size_t)N * 4);
    int* cursor  = (int*)give((size_t)N * 4);
    int* rowstart= (int*)give((size_t)(N + 1) * 4);
    int* col     = (int*)give((size_t)E * 4);
    int* gstart  = (int*)give((size_t)(N_GRAPHS + 1) * 4);
    float* gpool = (float*)give((size_t)N_GRAPHS * 2048 * 4);
    float* hcls  = (float*)give((size_t)N_GRAPHS * 256 * 4);
    (void)ws_size; (void)n_in; (void)out_size;

    // ---- CSR by destination
    hipMemsetAsync(deg, 0, (size_t)N * 4, stream);
    hipMemsetAsync(cursor, 0, (size_t)N * 4, stream);
    k_deg<<<(E + 255) / 256, 256, 0, stream>>>(dst, E, deg);
    k_scan<<<1, 1024, 0, stream>>>(deg, rowstart, N);
    k_fill<<<(E + 255) / 256, 256, 0, stream>>>(src, dst, E, rowstart, cursor, col);
    k_gbounds<<<1, 128, 0, stream>>>(batch, N, gstart);

    const int MB = (N + 63) / 64;   // 313

    // ---- h0 = relu(x @ Wp + bp)           [N,768]@[768,256]
    k_gemm<1><<<dim3(N_HID / 64, MB), 256, 0, stream>>>(x, Wp, bp, h0, N, N_HID, IN_DIM);

    // ---- GAT layer 1
    k_gemm<0><<<dim3(N_HC / 64, MB), 256, 0, stream>>>(h0, W1, nullptr, hW, N, N_HC, N_HID);
    k_scores<<<N, 256, 0, stream>>>(hW, as1, ad1, a_s, a_d, N);
    k_gat<<<N, 256, 0, stream>>>(hW, a_s, a_d, rowstart, col, b1, h1, N);

    // ---- GAT layer 2
    k_gemm<0><<<dim3(N_HC / 64, MB), 256, 0, stream>>>(h1, W2, nullptr, hW, N, N_HC, N_HC);
    k_scores<<<N, 256, 0, stream>>>(hW, as2, ad2, a_s, a_d, N);
    k_gat<<<N, 256, 0, stream>>>(hW, a_s, a_d, rowstart, col, b2, h1, N);  // h2 -> h1 buf

    // ---- pooling + classifier
    k_pool<<<N_GRAPHS, 256, 0, stream>>>(h1, gstart, gpool);
    k_cls1<<<N_GRAPHS, 256, 0, stream>>>(gpool, Wc1, bc1, hcls);
    k_cls2<<<2, 256, 0, stream>>>(hcls, Wc2, bc2, out);
}

// Round 2
// 1022.348 us; speedup vs baseline: 1.4319x; 1.4319x over previous
//
#include <hip/hip_runtime.h>
#include <math.h>

#define N_HID 256
#define N_HEADS 4
#define N_HC 1024       // HEADS*HID
#define N_GRAPHS 64

typedef __attribute__((ext_vector_type(8))) short short8;
typedef __attribute__((ext_vector_type(4))) float f32x4;

__device__ __forceinline__ unsigned short f2bf(float f) {
    unsigned u = __builtin_bit_cast(unsigned, f);
    unsigned r = (u + 0x7FFFu + ((u >> 16) & 1u)) >> 16;
    return (unsigned short)r;
}
__device__ __forceinline__ float bf2f(unsigned short b) {
    unsigned u = ((unsigned)b) << 16;
    return __builtin_bit_cast(float, u);
}

// ---------------------------------------------------------------- CSR build
__global__ __launch_bounds__(256) void k_deg(const int* __restrict__ dst, int E,
                                             int* __restrict__ deg) {
    int e = blockIdx.x * 256 + threadIdx.x;
    if (e < E) atomicAdd(&deg[dst[e]], 1);
}

__global__ __launch_bounds__(1024) void k_scan(const int* __restrict__ deg,
                                               int* __restrict__ rowstart, int N) {
    __shared__ int sm[1024];
    __shared__ int carry;
    int t = threadIdx.x;
    if (t == 0) { carry = 0; rowstart[0] = 0; }
    __syncthreads();
    for (int base = 0; base < N; base += 1024) {
        int v = (base + t < N) ? deg[base + t] : 0;
        sm[t] = v; __syncthreads();
        for (int off = 1; off < 1024; off <<= 1) {
            int add = (t >= off) ? sm[t - off] : 0;
            __syncthreads();
            sm[t] += add;
            __syncthreads();
        }
        int inc = sm[t] + carry;
        if (base + t < N) rowstart[base + t + 1] = inc;
        __syncthreads();
        if (t == 1023) carry = sm[1023] + carry;
        __syncthreads();
    }
}

__global__ __launch_bounds__(256) void k_fill(const int* __restrict__ src,
                                              const int* __restrict__ dst, int E,
                                              const int* __restrict__ rowstart,
                                              int* __restrict__ cursor,
                                              int* __restrict__ col) {
    int e = blockIdx.x * 256 + threadIdx.x;
    if (e < E) {
        int d = dst[e];
        int p = atomicAdd(&cursor[d], 1);
        col[rowstart[d] + p] = src[e];
    }
}

// ---------------------------------------------------------------- weight split
// W [K][N] fp32 -> Bt_hi/Bt_lo [N][K] bf16 (transposed, split)
__global__ __launch_bounds__(256) void k_wsplit(const float* __restrict__ W,
                                                unsigned short* __restrict__ bth,
                                                unsigned short* __restrict__ btl,
                                                int K, int N) {
    int idx = blockIdx.x * 256 + threadIdx.x;
    if (idx >= N * K) return;
    int n = idx / K, k = idx - n * K;
    float v = W[(size_t)k * N + n];
    unsigned short h = f2bf(v);
    bth[idx] = h;
    btl[idx] = f2bf(v - bf2f(h));
}

// ---------------------------------------------------------------- MFMA GEMM
// C[M,N] = A[M,K](fp32) @ Bt(bf16 hi/lo, [N][K]).  Split-bf16 3-term:
// a*b ~= ah*bh + ah*bl + al*bh, fp32 accumulate.  128x128 tile, BK=32,
// 4 waves (2x2), each wave 64x64 = 4x4 frags of 16x16x32.
template <int EPI>
__global__ __launch_bounds__(256) void k_mfma_gemm(
    const float* __restrict__ A,
    const unsigned short* __restrict__ Bth,
    const unsigned short* __restrict__ Btl,
    const float* __restrict__ bias,
    float* __restrict__ C, int M, int N, int K) {
    constexpr int LDK = 40;  // bf16 elems/row, 80B stride -> 2-way bank alias (free)
    __shared__ unsigned short sAh[128 * LDK];
    __shared__ unsigned short sAl[128 * LDK];
    __shared__ unsigned short sBh[128 * LDK];
    __shared__ unsigned short sBl[128 * LDK];
    const int bm = blockIdx.y * 128, bn = blockIdx.x * 128;
    const int tid = threadIdx.x;
    const int lane = tid & 63, w = tid >> 6;
    const int wr = (w >> 1) * 64, wc = (w & 1) * 64;
    const int sm = tid >> 1;            // staging row 0..127
    const int skb = (tid & 1) * 16;     // staging k base
    const bool rok = (bm + sm) < M;

    f32x4 acc[4][4] = {};

    for (int k0 = 0; k0 < K; k0 += 32) {
        // ---- stage A: fp32 -> hi/lo bf16
        const float* Arow = A + (size_t)(bm + sm) * K + k0 + skb;
#pragma unroll
        for (int j = 0; j < 4; j++) {
            float4 v = rok ? *(const float4*)(Arow + 4 * j)
                           : make_float4(0.f, 0.f, 0.f, 0.f);
            unsigned short h0 = f2bf(v.x), h1 = f2bf(v.y),
                           h2 = f2bf(v.z), h3 = f2bf(v.w);
            ushort4 hv = {h0, h1, h2, h3};
            ushort4 lv = {f2bf(v.x - bf2f(h0)), f2bf(v.y - bf2f(h1)),
                          f2bf(v.z - bf2f(h2)), f2bf(v.w - bf2f(h3))};
            int o = sm * LDK + skb + 4 * j;
            *(ushort4*)&sAh[o] = hv;
            *(ushort4*)&sAl[o] = lv;
        }
        // ---- stage B (already bf16, [N][K] linear)
        const unsigned short* Bh = Bth + (size_t)(bn + sm) * K + k0 + skb;
        const unsigned short* Bl = Btl + (size_t)(bn + sm) * K + k0 + skb;
#pragma unroll
        for (int j = 0; j < 2; j++) {
            float4 hv = *(const float4*)(Bh + 8 * j);
            float4 lv = *(const float4*)(Bl + 8 * j);
            int o = sm * LDK + skb + 8 * j;
            *(float4*)&sBh[o] = hv;
            *(float4*)&sBl[o] = lv;
        }
        __syncthreads();
        // ---- fragments + MFMA
        short8 ah[4], al[4], bh[4], bl[4];
        const int ko = (lane >> 4) * 8;
        const int fr = lane & 15;
#pragma unroll
        for (int i = 0; i < 4; i++) {
            int m = wr + i * 16 + fr;
            ah[i] = *(const short8*)&sAh[m * LDK + ko];
            al[i] = *(const short8*)&sAl[m * LDK + ko];
            int n = wc + i * 16 + fr;
            bh[i] = *(const short8*)&sBh[n * LDK + ko];
            bl[i] = *(const short8*)&sBl[n * LDK + ko];
        }
#pragma unroll
        for (int i = 0; i < 4; i++)
#pragma unroll
            for (int j = 0; j < 4; j++) {
                acc[i][j] = __builtin_amdgcn_mfma_f32_16x16x32_bf16(ah[i], bh[j], acc[i][j], 0, 0, 0);
                acc[i][j] = __builtin_amdgcn_mfma_f32_16x16x32_bf16(ah[i], bl[j], acc[i][j], 0, 0, 0);
                acc[i][j] = __builtin_amdgcn_mfma_f32_16x16x32_bf16(al[i], bh[j], acc[i][j], 0, 0, 0);
            }
        __syncthreads();
    }
    // ---- C write: col = lane&15, row = (lane>>4)*4 + r  (m89-verified)
    const int crow0 = (lane >> 4) * 4;
    const int ccol = lane & 15;
#pragma unroll
    for (int i = 0; i < 4; i++)
#pragma unroll
        for (int j = 0; j < 4; j++) {
            int col = bn + wc + j * 16 + ccol;
            float bv = (EPI == 1) ? bias[col] : 0.f;
#pragma unroll
            for (int r = 0; r < 4; r++) {
                int row = bm + wr + i * 16 + crow0 + r;
                if (row < M) {
                    float v = acc[i][j][r];
                    if (EPI == 1) {
                        v += bv;
                        v = v > 0.f ? v : 0.f;
                    }
                    C[(size_t)row * N + col] = v;
                }
            }
        }
}

// ---------------------------------------------------------------- attention scores
__global__ __launch_bounds__(256) void k_scores(const float* __restrict__ hW,
                                                const float* __restrict__ att_s,
                                                const float* __restrict__ att_d,
                                                float* __restrict__ a_s,
                                                float* __restrict__ a_d, int N) {
    int wid = (blockIdx.x * 256 + threadIdx.x) >> 6;
    int lane = threadIdx.x & 63;
    if (wid >= N * N_HEADS) return;
    int n = wid >> 2, h = wid & 3;
    float4 v = *(const float4*)(hW + (size_t)n * N_HC + h * N_HID + lane * 4);
    float4 a = *(const float4*)(att_s + h * N_HID + lane * 4);
    float4 d = *(const float4*)(att_d + h * N_HID + lane * 4);
    float ss = v.x * a.x + v.y * a.y + v.z * a.z + v.w * a.w;
    float sd = v.x * d.x + v.y * d.y + v.z * d.z + v.w * d.w;
#pragma unroll
    for (int off = 32; off > 0; off >>= 1) {
        ss += __shfl_down(ss, off, 64);
        sd += __shfl_down(sd, off, 64);
    }
    if (lane == 0) { a_s[wid] = ss; a_d[wid] = sd; }
}

// ---------------------------------------------------------------- GAT aggregate
__global__ __launch_bounds__(256) void k_gat(const float* __restrict__ hW,
                                             const float* __restrict__ a_s,
                                             const float* __restrict__ a_d,
                                             const int* __restrict__ rowstart,
                                             const int* __restrict__ col,
                                             const float* __restrict__ bias,
                                             float* __restrict__ out, int N) {
    int n = blockIdx.x;
    int t = threadIdx.x;
    float m[N_HEADS], s[N_HEADS], acc[N_HEADS];
#pragma unroll
    for (int h = 0; h < N_HEADS; h++) { m[h] = -INFINITY; s[h] = 0.f; acc[h] = 0.f; }
    float adv[N_HEADS];
#pragma unroll
    for (int h = 0; h < N_HEADS; h++) adv[h] = a_d[n * N_HEADS + h];
    int e0 = rowstart[n], e1 = rowstart[n + 1];
    for (int i = e0; i <= e1; i++) {       // i==e1 -> the self loop
        int sn = (i < e1) ? col[i] : n;
        const float* row = hW + (size_t)sn * N_HC;
#pragma unroll
        for (int h = 0; h < N_HEADS; h++) {
            float sc = a_s[sn * N_HEADS + h] + adv[h];
            float e = sc >= 0.f ? sc : 0.2f * sc;     // leaky_relu(0.2)
            float mn = fmaxf(m[h], e);
            float scale = __expf(m[h] - mn);
            float wgt = __expf(e - mn);
            s[h] = s[h] * scale + wgt;
            acc[h] = acc[h] * scale + wgt * row[h * N_HID + t];
            m[h] = mn;
        }
    }
#pragma unroll
    for (int h = 0; h < N_HEADS; h++) {
        float v = acc[h] / (s[h] + 1e-16f) + bias[h * N_HID + t];
        out[(size_t)n * N_HC + h * N_HID + t] = v > 0.f ? v : (__expf(v) - 1.f);
    }
}

// ---------------------------------------------------------------- pooling
__global__ __launch_bounds__(128) void k_gbounds(const int* __restrict__ batch, int N,
                                                 int* __restrict__ gstart) {
    int g = threadIdx.x;
    if (g > N_GRAPHS) return;
    if (g == N_GRAPHS) { gstart[N_GRAPHS] = N; return; }
    int lo = 0, hi = N;
    while (lo < hi) {
        int mid = (lo + hi) >> 1;
        if (batch[mid] < g) lo = mid + 1; else hi = mid;
    }
    gstart[g] = lo;
}

__global__ __launch_bounds__(256) void k_pool(const float* __restrict__ h,
                                              const int* __restrict__ gstart,
                                              float* __restrict__ gout) {
    int g = blockIdx.x, t = threadIdx.x;
    int s = gstart[g], e = gstart[g + 1];
    float sum[4] = {0.f, 0.f, 0.f, 0.f};
    float mx[4] = {-INFINITY, -INFINITY, -INFINITY, -INFINITY};
    for (int i = s; i < e; i++) {
        const float* row = h + (size_t)i * N_HC;
#pragma unroll
        for (int j = 0; j < 4; j++) {
            float v = row[t + j * 256];
            sum[j] += v;
            mx[j] = fmaxf(mx[j], v);
        }
    }
    float cnt = fmaxf((float)(e - s), 1.f);
#pragma unroll
    for (int j = 0; j < 4; j++) {
        gout[(size_t)g * 2048 + j * 256 + t] = sum[j] / cnt;
        gout[(size_t)g * 2048 + 1024 + j * 256 + t] = mx[j];
    }
}

// ---------------------------------------------------------------- classifier
__global__ __launch_bounds__(256) void k_cls1(const float* __restrict__ g,
                                              const float* __restrict__ Wc1,
                                              const float* __restrict__ bc1,
                                              float* __restrict__ hcls) {
    __shared__ float gs[2048];
    int gb = blockIdx.x, t = threadIdx.x;
    for (int i = t; i < 2048; i += 256) gs[i] = g[(size_t)gb * 2048 + i];
    __syncthreads();
    float acc = 0.f;
    for (int k = 0; k < 2048; k++) acc += gs[k] * Wc1[(size_t)k * 256 + t];
    float v = acc + bc1[t];
    hcls[gb * 256 + t] = v > 0.f ? v : 0.f;
}

__global__ __launch_bounds__(256) void k_cls2(const float* __restrict__ hcls,
                                              const float* __restrict__ Wc2,
                                              const float* __restrict__ bc2,
                                              float* __restrict__ out) {
    int idx = blockIdx.x * 256 + threadIdx.x;
    if (idx >= N_GRAPHS * 5) return;
    int gb = idx / 5, j = idx % 5;
    float acc = 0.f;
    for (int k = 0; k < 256; k++) acc += hcls[gb * 256 + k] * Wc2[k * 5 + j];
    out[idx] = acc + bc2[j];
}

// ---------------------------------------------------------------- launch
extern "C" void kernel_launch(void* const* d_in, const int* in_sizes, int n_in,
                              void* d_out, int out_size, void* d_ws, size_t ws_size,
                              hipStream_t stream) {
    const float* x    = (const float*)d_in[0];
    const int*   ei   = (const int*)d_in[1];
    const int*   batch= (const int*)d_in[2];
    const float* Wp   = (const float*)d_in[3];
    const float* bp   = (const float*)d_in[4];
    const float* W1   = (const float*)d_in[5];
    const float* as1  = (const float*)d_in[6];
    const float* ad1  = (const float*)d_in[7];
    const float* b1   = (const float*)d_in[8];
    const float* W2   = (const float*)d_in[9];
    const float* as2  = (const float*)d_in[10];
    const float* ad2  = (const float*)d_in[11];
    const float* b2   = (const float*)d_in[12];
    const float* Wc1  = (const float*)d_in[13];
    const float* bc1  = (const float*)d_in[14];
    const float* Wc2  = (const float*)d_in[15];
    const float* bc2  = (const float*)d_in[16];
    float* out = (float*)d_out;

    const int N = in_sizes[0] / 768;   // 20000
    const int E = in_sizes[1] / 2;     // 320000

    const int* src = ei;
    const int* dst = ei + E;

    char* ws = (char*)d_ws;
    size_t off = 0;
    auto give = [&](size_t bytes) -> void* {
        void* p = ws + off;
        off = (off + bytes + 255) & ~(size_t)255;
        return p;
    };
    float* h0   = (float*)give((size_t)N * N_HID * 4);   // 20.5 MB
    float* hW   = (float*)give((size_t)N * N_HC * 4);    // 82 MB
    float* h1   = (float*)give((size_t)N * N_HC * 4);    // 82 MB
    float* a_s  = (float*)give((size_t)N * N_HEADS * 4);
    float* a_d  = (float*)give((size_t)N * N_HEADS * 4);
    int* deg     = (int*)give((size_t)N * 4);
    int* cursor  = (int*)give((size_t)N * 4);
    int* rowstart= (int*)give((size_t)(N + 1) * 4);
    int* col     = (int*)give((size_t)E * 4);
    int* gstart  = (int*)give((size_t)(N_GRAPHS + 1) * 4);
    float* gpool = (float*)give((size_t)N_GRAPHS * 2048 * 4);
    float* hcls  = (float*)give((size_t)N_GRAPHS * 256 * 4);
    unsigned short* bth = (unsigned short*)give((size_t)1024 * 1024 * 2);
    unsigned short* btl = (unsigned short*)give((size_t)1024 * 1024 * 2);
    (void)ws_size; (void)n_in; (void)out_size;

    // ---- CSR by destination
    hipMemsetAsync(deg, 0, (size_t)N * 4, stream);
    hipMemsetAsync(cursor, 0, (size_t)N * 4, stream);
    k_deg<<<(E + 255) / 256, 256, 0, stream>>>(dst, E, deg);
    k_scan<<<1, 1024, 0, stream>>>(deg, rowstart, N);
    k_fill<<<(E + 255) / 256, 256, 0, stream>>>(src, dst, E, rowstart, cursor, col);
    k_gbounds<<<1, 128, 0, stream>>>(batch, N, gstart);

    const int MB = (N + 127) / 128;   // 157

    // ---- h0 = relu(x @ Wp + bp)           [N,768]@[768,256]
    k_wsplit<<<(256 * 768 + 255) / 256, 256, 0, stream>>>(Wp, bth, btl, 768, 256);
    k_mfma_gemm<1><<<dim3(256 / 128, MB), 256, 0, stream>>>(x, bth, btl, bp, h0, N, 256, 768);

    // ---- GAT layer 1: hW = h0 @ W1        [N,256]@[256,1024]
    k_wsplit<<<(1024 * 256 + 255) / 256, 256, 0, stream>>>(W1, bth, btl, 256, 1024);
    k_mfma_gemm<0><<<dim3(1024 / 128, MB), 256, 0, stream>>>(h0, bth, btl, nullptr, hW, N, 1024, 256);
    k_scores<<<N, 256, 0, stream>>>(hW, as1, ad1, a_s, a_d, N);
    k_gat<<<N, 256, 0, stream>>>(hW, a_s, a_d, rowstart, col, b1, h1, N);

    // ---- GAT layer 2: hW = h1 @ W2        [N,1024]@[1024,1024]
    k_wsplit<<<(1024 * 1024 + 255) / 256, 256, 0, stream>>>(W2, bth, btl, 1024, 1024);
    k_mfma_gemm<0><<<dim3(1024 / 128, MB), 256, 0, stream>>>(h1, bth, btl, nullptr, hW, N, 1024, 1024);
    k_scores<<<N, 256, 0, stream>>>(hW, as2, ad2, a_s, a_d, N);
    k_gat<<<N, 256, 0, stream>>>(hW, a_s, a_d, rowstart, col, b2, h1, N);

    // ---- pooling + classifier
    k_pool<<<N_GRAPHS, 256, 0, stream>>>(h1, gstart, gpool);
    k_cls1<<<N_GRAPHS, 256, 0, stream>>>(gpool, Wc1, bc1, hcls);
    k_cls2<<<2, 256, 0, stream>>>(hcls, Wc2, bc2, out);
}

// Round 3
// 956.994 us; speedup vs baseline: 1.5296x; 1.0683x over previous
//
#include <hip/hip_runtime.h>
#include <math.h>

#define N_HID 256
#define N_HEADS 4
#define N_HC 1024       // HEADS*HID
#define N_GRAPHS 64

typedef __attribute__((ext_vector_type(8))) short short8;
typedef __attribute__((ext_vector_type(4))) float f32x4;

__device__ __forceinline__ unsigned short f2bf(float f) {
    unsigned u = __builtin_bit_cast(unsigned, f);
    unsigned r = (u + 0x7FFFu + ((u >> 16) & 1u)) >> 16;
    return (unsigned short)r;
}
__device__ __forceinline__ float bf2f(unsigned short b) {
    unsigned u = ((unsigned)b) << 16;
    return __builtin_bit_cast(float, u);
}

__device__ __forceinline__ void gl_lds16(const unsigned short* g, unsigned short* l) {
    __builtin_amdgcn_global_load_lds(
        (const __attribute__((address_space(1))) unsigned int*)g,
        (__attribute__((address_space(3))) unsigned int*)l, 16, 0, 0);
}

// ---------------------------------------------------------------- CSR build
__global__ __launch_bounds__(256) void k_deg(const int* __restrict__ dst, int E,
                                             int* __restrict__ deg) {
    int e = blockIdx.x * 256 + threadIdx.x;
    if (e < E) atomicAdd(&deg[dst[e]], 1);
}

// single block, 256 threads: per-thread serial chunk + LDS scan of partials
__global__ __launch_bounds__(256) void k_scan(const int* __restrict__ deg,
                                              int* __restrict__ rowstart, int N) {
    __shared__ int part[256];
    const int t = threadIdx.x;
    const int chunk = (N + 255) / 256;
    const int c0 = t * chunk;
    int s = 0;
    for (int i = 0; i < chunk; i++) {
        int idx = c0 + i;
        if (idx < N) s += deg[idx];
    }
    part[t] = s;
    __syncthreads();
    for (int off = 1; off < 256; off <<= 1) {
        int v = (t >= off) ? part[t - off] : 0;
        __syncthreads();
        part[t] += v;
        __syncthreads();
    }
    int run = (t == 0) ? 0 : part[t - 1];
    if (t == 0) rowstart[0] = 0;
    for (int i = 0; i < chunk; i++) {
        int idx = c0 + i;
        if (idx < N) {
            run += deg[idx];
            rowstart[idx + 1] = run;
        }
    }
}

__global__ __launch_bounds__(256) void k_fill(const int* __restrict__ src,
                                              const int* __restrict__ dst, int E,
                                              const int* __restrict__ rowstart,
                                              int* __restrict__ cursor,
                                              int* __restrict__ col) {
    int e = blockIdx.x * 256 + threadIdx.x;
    if (e < E) {
        int d = dst[e];
        int p = atomicAdd(&cursor[d], 1);
        col[rowstart[d] + p] = src[e];
    }
}

// ---------------------------------------------------------------- weight split
// W [K][N] fp32 -> Bt_hi/Bt_lo [N][K] bf16 (transposed, split)
__global__ __launch_bounds__(256) void k_wsplit(const float* __restrict__ W,
                                                unsigned short* __restrict__ bth,
                                                unsigned short* __restrict__ btl,
                                                int K, int N) {
    int idx = blockIdx.x * 256 + threadIdx.x;
    if (idx >= N * K) return;
    int n = idx / K, k = idx - n * K;
    float v = W[(size_t)k * N + n];
    unsigned short h = f2bf(v);
    bth[idx] = h;
    btl[idx] = f2bf(v - bf2f(h));
}

// ---------------------------------------------------------------- MFMA GEMM (fp32 A)
// Used only for GEMM1 (A=x fp32). Epilogue EPI=1: bias+relu -> split bf16 out.
template <int EPI>
__global__ __launch_bounds__(256) void k_mfma_gemm(
    const float* __restrict__ A,
    const unsigned short* __restrict__ Bth,
    const unsigned short* __restrict__ Btl,
    const float* __restrict__ bias,
    float* __restrict__ C,
    unsigned short* __restrict__ Ch,
    unsigned short* __restrict__ Cl,
    int M, int N, int K) {
    constexpr int LDK = 40;
    __shared__ unsigned short sAh[128 * LDK];
    __shared__ unsigned short sAl[128 * LDK];
    __shared__ unsigned short sBh[128 * LDK];
    __shared__ unsigned short sBl[128 * LDK];
    const int bm = blockIdx.y * 128, bn = blockIdx.x * 128;
    const int tid = threadIdx.x;
    const int lane = tid & 63, w = tid >> 6;
    const int wr = (w >> 1) * 64, wc = (w & 1) * 64;
    const int sm = tid >> 1;
    const int skb = (tid & 1) * 16;
    const bool rok = (bm + sm) < M;

    f32x4 acc[4][4] = {};

    for (int k0 = 0; k0 < K; k0 += 32) {
        const float* Arow = A + (size_t)(bm + sm) * K + k0 + skb;
#pragma unroll
        for (int j = 0; j < 4; j++) {
            float4 v = rok ? *(const float4*)(Arow + 4 * j)
                           : make_float4(0.f, 0.f, 0.f, 0.f);
            unsigned short h0 = f2bf(v.x), h1 = f2bf(v.y),
                           h2 = f2bf(v.z), h3 = f2bf(v.w);
            ushort4 hv = {h0, h1, h2, h3};
            ushort4 lv = {f2bf(v.x - bf2f(h0)), f2bf(v.y - bf2f(h1)),
                          f2bf(v.z - bf2f(h2)), f2bf(v.w - bf2f(h3))};
            int o = sm * LDK + skb + 4 * j;
            *(ushort4*)&sAh[o] = hv;
            *(ushort4*)&sAl[o] = lv;
        }
        const unsigned short* Bh = Bth + (size_t)(bn + sm) * K + k0 + skb;
        const unsigned short* Bl = Btl + (size_t)(bn + sm) * K + k0 + skb;
#pragma unroll
        for (int j = 0; j < 2; j++) {
            float4 hv = *(const float4*)(Bh + 8 * j);
            float4 lv = *(const float4*)(Bl + 8 * j);
            int o = sm * LDK + skb + 8 * j;
            *(float4*)&sBh[o] = hv;
            *(float4*)&sBl[o] = lv;
        }
        __syncthreads();
        short8 ah[4], al[4], bh[4], bl[4];
        const int ko = (lane >> 4) * 8;
        const int fr = lane & 15;
#pragma unroll
        for (int i = 0; i < 4; i++) {
            int m = wr + i * 16 + fr;
            ah[i] = *(const short8*)&sAh[m * LDK + ko];
            al[i] = *(const short8*)&sAl[m * LDK + ko];
            int nn = wc + i * 16 + fr;
            bh[i] = *(const short8*)&sBh[nn * LDK + ko];
            bl[i] = *(const short8*)&sBl[nn * LDK + ko];
        }
#pragma unroll
        for (int i = 0; i < 4; i++)
#pragma unroll
            for (int j = 0; j < 4; j++) {
                acc[i][j] = __builtin_amdgcn_mfma_f32_16x16x32_bf16(ah[i], bh[j], acc[i][j], 0, 0, 0);
                acc[i][j] = __builtin_amdgcn_mfma_f32_16x16x32_bf16(ah[i], bl[j], acc[i][j], 0, 0, 0);
                acc[i][j] = __builtin_amdgcn_mfma_f32_16x16x32_bf16(al[i], bh[j], acc[i][j], 0, 0, 0);
            }
        __syncthreads();
    }
    const int crow0 = (lane >> 4) * 4;
    const int ccol = lane & 15;
#pragma unroll
    for (int i = 0; i < 4; i++)
#pragma unroll
        for (int j = 0; j < 4; j++) {
            int cc = bn + wc + j * 16 + ccol;
            float bv = (EPI == 1) ? bias[cc] : 0.f;
#pragma unroll
            for (int r = 0; r < 4; r++) {
                int row = bm + wr + i * 16 + crow0 + r;
                if (row < M) {
                    float v = acc[i][j][r];
                    if (EPI == 1) {
                        v += bv;
                        v = v > 0.f ? v : 0.f;
                        unsigned short hi = f2bf(v);
                        Ch[(size_t)row * N + cc] = hi;
                        Cl[(size_t)row * N + cc] = f2bf(v - bf2f(hi));
                    } else {
                        C[(size_t)row * N + cc] = v;
                    }
                }
            }
        }
}

// ---------------------------------------------------------------- bf16 GEMM (pre-split A,B)
// C[M,N] fp32 = A(hi/lo bf16 [M][K]) @ B(hi/lo bf16 [N][K]).
// 128x128 tile, BK=32, global_load_lds staging (m97 structure).
__global__ __launch_bounds__(256) void k_gemm_bf(
    const unsigned short* __restrict__ Ah, const unsigned short* __restrict__ Al,
    const unsigned short* __restrict__ Bh, const unsigned short* __restrict__ Bl,
    float* __restrict__ C, int M, int N, int K) {
    __shared__ unsigned short sAh[128 * 32];
    __shared__ unsigned short sAl[128 * 32];
    __shared__ unsigned short sBh[128 * 32];
    __shared__ unsigned short sBl[128 * 32];
    const int bm = blockIdx.y * 128, bn = blockIdx.x * 128;
    const int tid = threadIdx.x, lane = tid & 63, w = tid >> 6;
    const int wr = (w >> 1) * 64, wc = (w & 1) * 64;
    // wave w stages buffer w
    const unsigned short* src = (w == 0) ? Ah + (size_t)bm * K
                              : (w == 1) ? Al + (size_t)bm * K
                              : (w == 2) ? Bh + (size_t)bn * K
                                         : Bl + (size_t)bn * K;
    unsigned short* dst = (w == 0) ? sAh : (w == 1) ? sAl : (w == 2) ? sBh : sBl;
    const int ko = (lane >> 4) * 8, fr = lane & 15;
    const int sr = lane >> 2;           // staging row within 16-row chunk
    const int skk = (lane & 3) * 8;     // staging k offset

    f32x4 acc[4][4] = {};

    for (int k0 = 0; k0 < K; k0 += 32) {
#pragma unroll
        for (int c = 0; c < 8; c++) {
            gl_lds16(src + (size_t)(c * 16 + sr) * K + k0 + skk, dst + c * 512);
        }
        __syncthreads();
        short8 ah[4], al[4], bh[4], bl[4];
#pragma unroll
        for (int i = 0; i < 4; i++) {
            ah[i] = *(const short8*)&sAh[(wr + i * 16 + fr) * 32 + ko];
            al[i] = *(const short8*)&sAl[(wr + i * 16 + fr) * 32 + ko];
            bh[i] = *(const short8*)&sBh[(wc + i * 16 + fr) * 32 + ko];
            bl[i] = *(const short8*)&sBl[(wc + i * 16 + fr) * 32 + ko];
        }
#pragma unroll
        for (int i = 0; i < 4; i++)
#pragma unroll
            for (int j = 0; j < 4; j++) {
                acc[i][j] = __builtin_amdgcn_mfma_f32_16x16x32_bf16(ah[i], bh[j], acc[i][j], 0, 0, 0);
                acc[i][j] = __builtin_amdgcn_mfma_f32_16x16x32_bf16(ah[i], bl[j], acc[i][j], 0, 0, 0);
                acc[i][j] = __builtin_amdgcn_mfma_f32_16x16x32_bf16(al[i], bh[j], acc[i][j], 0, 0, 0);
            }
        __syncthreads();
    }
    const int crow0 = (lane >> 4) * 4;
    const int ccol = lane & 15;
#pragma unroll
    for (int i = 0; i < 4; i++)
#pragma unroll
        for (int j = 0; j < 4; j++) {
            int cc = bn + wc + j * 16 + ccol;
#pragma unroll
            for (int r = 0; r < 4; r++) {
                int row = bm + wr + i * 16 + crow0 + r;
                if (row < M) C[(size_t)row * N + cc] = acc[i][j][r];
            }
        }
}

// ---------------------------------------------------------------- attention scores
__global__ __launch_bounds__(256) void k_scores(const float* __restrict__ hW,
                                                const float* __restrict__ att_s,
                                                const float* __restrict__ att_d,
                                                float* __restrict__ a_s,
                                                float* __restrict__ a_d, int N) {
    int wid = (blockIdx.x * 256 + threadIdx.x) >> 6;
    int lane = threadIdx.x & 63;
    if (wid >= N * N_HEADS) return;
    int n = wid >> 2, h = wid & 3;
    float4 v = *(const float4*)(hW + (size_t)n * N_HC + h * N_HID + lane * 4);
    float4 a = *(const float4*)(att_s + h * N_HID + lane * 4);
    float4 d = *(const float4*)(att_d + h * N_HID + lane * 4);
    float ss = v.x * a.x + v.y * a.y + v.z * a.z + v.w * a.w;
    float sd = v.x * d.x + v.y * d.y + v.z * d.z + v.w * d.w;
#pragma unroll
    for (int off = 32; off > 0; off >>= 1) {
        ss += __shfl_down(ss, off, 64);
        sd += __shfl_down(sd, off, 64);
    }
    if (lane == 0) { a_s[wid] = ss; a_d[wid] = sd; }
}

// ---------------------------------------------------------------- GAT aggregate v2
// One block per dst node. Phase A: per-edge softmax weights (computed once,
// wave-reduced max/sum, online across 256-edge chunks). Phase B: gather-FMA.
// OUTM 0: fp32 out; 1: split bf16 out.
template <int OUTM>
__global__ __launch_bounds__(256) void k_gat2(
    const float* __restrict__ hW, const float* __restrict__ a_s,
    const float* __restrict__ a_d, const int* __restrict__ rowstart,
    const int* __restrict__ col, const float* __restrict__ bias,
    float* __restrict__ outf, unsigned short* __restrict__ outh,
    unsigned short* __restrict__ outl, int N) {
    __shared__ int sn_lds[256];
    __shared__ float w_lds[256][4];
    __shared__ float redm[4][4], reds[4][4];
    const int n = blockIdx.x, t = threadIdx.x;
    const int lane = t & 63, w = t >> 6;
    const int e0 = rowstart[n];
    const int deg = rowstart[n + 1] - e0;
    const int tot = deg + 1;   // + self loop
    float adv[4];
#pragma unroll
    for (int h = 0; h < 4; h++) adv[h] = a_d[n * 4 + h];
    float acc[4] = {0.f, 0.f, 0.f, 0.f};
    float M[4] = {-INFINITY, -INFINITY, -INFINITY, -INFINITY};
    float S[4] = {0.f, 0.f, 0.f, 0.f};

    for (int base = 0; base < tot; base += 256) {
        const int cnt = min(256, tot - base);
        const bool act = t < cnt;
        float e[4];
        if (act) {
            const int li = base + t;
            const int sn = (li < deg) ? col[e0 + li] : n;
            sn_lds[t] = sn;
#pragma unroll
            for (int h = 0; h < 4; h++) {
                float sc = a_s[sn * 4 + h] + adv[h];
                e[h] = sc >= 0.f ? sc : 0.2f * sc;   // leaky_relu(0.2)
            }
        } else {
#pragma unroll
            for (int h = 0; h < 4; h++) e[h] = -INFINITY;
        }
        // wave-reduce max
        float mw[4];
#pragma unroll
        for (int h = 0; h < 4; h++) mw[h] = e[h];
#pragma unroll
        for (int off = 32; off > 0; off >>= 1)
#pragma unroll
            for (int h = 0; h < 4; h++)
                mw[h] = fmaxf(mw[h], __shfl_xor(mw[h], off, 64));
        if (lane == 0)
#pragma unroll
            for (int h = 0; h < 4; h++) redm[w][h] = mw[h];
        __syncthreads();   // redm + sn_lds visible
        float newM[4], wv[4];
#pragma unroll
        for (int h = 0; h < 4; h++) {
            newM[h] = fmaxf(fmaxf(fmaxf(redm[0][h], redm[1][h]),
                                  fmaxf(redm[2][h], redm[3][h])), M[h]);
            wv[h] = act ? __expf(e[h] - newM[h]) : 0.f;
        }
        if (act) *(float4*)&w_lds[t][0] = make_float4(wv[0], wv[1], wv[2], wv[3]);
        // wave-reduce sum
        float sw[4];
#pragma unroll
        for (int h = 0; h < 4; h++) sw[h] = wv[h];
#pragma unroll
        for (int off = 32; off > 0; off >>= 1)
#pragma unroll
            for (int h = 0; h < 4; h++) sw[h] += __shfl_xor(sw[h], off, 64);
        if (lane == 0)
#pragma unroll
            for (int h = 0; h < 4; h++) reds[w][h] = sw[h];
        __syncthreads();   // reds + w_lds visible
#pragma unroll
        for (int h = 0; h < 4; h++) {
            float scale = __expf(M[h] - newM[h]);   // exp(-inf)=0 first chunk
            S[h] = S[h] * scale + (reds[0][h] + reds[1][h] + reds[2][h] + reds[3][h]);
            acc[h] *= scale;
            M[h] = newM[h];
        }
        // Phase B: gather-FMA over this chunk's edges
        for (int i = 0; i < cnt; i++) {
            const int sn = sn_lds[i];
            const float* row = hW + (size_t)sn * N_HC;
            const float4 wv4 = *(const float4*)&w_lds[i][0];
            acc[0] += wv4.x * row[t];
            acc[1] += wv4.y * row[256 + t];
            acc[2] += wv4.z * row[512 + t];
            acc[3] += wv4.w * row[768 + t];
        }
        __syncthreads();   // before next chunk overwrites LDS
    }
#pragma unroll
    for (int h = 0; h < 4; h++) {
        float v = acc[h] / (S[h] + 1e-16f) + bias[h * 256 + t];
        v = v > 0.f ? v : (__expf(v) - 1.f);   // ELU
        if (OUTM == 0) {
            outf[(size_t)n * N_HC + h * 256 + t] = v;
        } else {
            unsigned short hi = f2bf(v);
            outh[(size_t)n * N_HC + h * 256 + t] = hi;
            outl[(size_t)n * N_HC + h * 256 + t] = f2bf(v - bf2f(hi));
        }
    }
}

// ---------------------------------------------------------------- pooling
__global__ __launch_bounds__(128) void k_gbounds(const int* __restrict__ batch, int N,
                                                 int* __restrict__ gstart) {
    int g = threadIdx.x;
    if (g > N_GRAPHS) return;
    if (g == N_GRAPHS) { gstart[N_GRAPHS] = N; return; }
    int lo = 0, hi = N;
    while (lo < hi) {
        int mid = (lo + hi) >> 1;
        if (batch[mid] < g) lo = mid + 1; else hi = mid;
    }
    gstart[g] = lo;
}

__global__ __launch_bounds__(256) void k_pool(const float* __restrict__ h,
                                              const int* __restrict__ gstart,
                                              float* __restrict__ gout) {
    int g = blockIdx.x, t = threadIdx.x;
    int s = gstart[g], e = gstart[g + 1];
    float sum[4] = {0.f, 0.f, 0.f, 0.f};
    float mx[4] = {-INFINITY, -INFINITY, -INFINITY, -INFINITY};
    for (int i = s; i < e; i++) {
        const float* row = h + (size_t)i * N_HC;
#pragma unroll
        for (int j = 0; j < 4; j++) {
            float v = row[t + j * 256];
            sum[j] += v;
            mx[j] = fmaxf(mx[j], v);
        }
    }
    float cnt = fmaxf((float)(e - s), 1.f);
#pragma unroll
    for (int j = 0; j < 4; j++) {
        gout[(size_t)g * 2048 + j * 256 + t] = sum[j] / cnt;
        gout[(size_t)g * 2048 + 1024 + j * 256 + t] = mx[j];
    }
}

// ---------------------------------------------------------------- classifier
__global__ __launch_bounds__(256) void k_cls1(const float* __restrict__ g,
                                              const float* __restrict__ Wc1,
                                              const float* __restrict__ bc1,
                                              float* __restrict__ hcls) {
    __shared__ float gs[2048];
    int gb = blockIdx.x, t = threadIdx.x;
    for (int i = t; i < 2048; i += 256) gs[i] = g[(size_t)gb * 2048 + i];
    __syncthreads();
    float acc = 0.f;
    for (int k = 0; k < 2048; k++) acc += gs[k] * Wc1[(size_t)k * 256 + t];
    float v = acc + bc1[t];
    hcls[gb * 256 + t] = v > 0.f ? v : 0.f;
}

__global__ __launch_bounds__(256) void k_cls2(const float* __restrict__ hcls,
                                              const float* __restrict__ Wc2,
                                              const float* __restrict__ bc2,
                                              float* __restrict__ out) {
    int idx = blockIdx.x * 256 + threadIdx.x;
    if (idx >= N_GRAPHS * 5) return;
    int gb = idx / 5, j = idx % 5;
    float acc = 0.f;
    for (int k = 0; k < 256; k++) acc += hcls[gb * 256 + k] * Wc2[k * 5 + j];
    out[idx] = acc + bc2[j];
}

// ---------------------------------------------------------------- launch
extern "C" void kernel_launch(void* const* d_in, const int* in_sizes, int n_in,
                              void* d_out, int out_size, void* d_ws, size_t ws_size,
                              hipStream_t stream) {
    const float* x    = (const float*)d_in[0];
    const int*   ei   = (const int*)d_in[1];
    const int*   batch= (const int*)d_in[2];
    const float* Wp   = (const float*)d_in[3];
    const float* bp   = (const float*)d_in[4];
    const float* W1   = (const float*)d_in[5];
    const float* as1  = (const float*)d_in[6];
    const float* ad1  = (const float*)d_in[7];
    const float* b1   = (const float*)d_in[8];
    const float* W2   = (const float*)d_in[9];
    const float* as2  = (const float*)d_in[10];
    const float* ad2  = (const float*)d_in[11];
    const float* b2   = (const float*)d_in[12];
    const float* Wc1  = (const float*)d_in[13];
    const float* bc1  = (const float*)d_in[14];
    const float* Wc2  = (const float*)d_in[15];
    const float* bc2  = (const float*)d_in[16];
    float* out = (float*)d_out;

    const int N = in_sizes[0] / 768;   // 20000
    const int E = in_sizes[1] / 2;     // 320000
    const int MP = ((N + 127) / 128) * 128;   // 20096 padded rows

    const int* src = ei;
    const int* dst = ei + E;

    char* ws = (char*)d_ws;
    size_t off = 0;
    auto give = [&](size_t bytes) -> void* {
        void* p = ws + off;
        off = (off + bytes + 255) & ~(size_t)255;
        return p;
    };
    unsigned short* h0h = (unsigned short*)give((size_t)MP * N_HID * 2);    // 10.3MB
    unsigned short* h0l = (unsigned short*)give((size_t)MP * N_HID * 2);
    float* hW = (float*)give((size_t)N * N_HC * 4);                          // 82MB
    unsigned short* h1h = (unsigned short*)give((size_t)MP * N_HC * 2);      // 41.2MB
    unsigned short* h1l = (unsigned short*)give((size_t)MP * N_HC * 2);      // 41.2MB
    float* h2 = (float*)h1h;   // aliases h1 split (dead by GAT2)
    float* a_s  = (float*)give((size_t)N * N_HEADS * 4);
    float* a_d  = (float*)give((size_t)N * N_HEADS * 4);
    int* deg     = (int*)give((size_t)N * 4);
    int* cursor  = (int*)give((size_t)N * 4);
    int* rowstart= (int*)give((size_t)(N + 1) * 4);
    int* col     = (int*)give((size_t)E * 4);
    int* gstart  = (int*)give((size_t)(N_GRAPHS + 1) * 4);
    float* gpool = (float*)give((size_t)N_GRAPHS * 2048 * 4);
    float* hcls  = (float*)give((size_t)N_GRAPHS * 256 * 4);
    unsigned short* bth = (unsigned short*)give((size_t)1024 * 1024 * 2);
    unsigned short* btl = (unsigned short*)give((size_t)1024 * 1024 * 2);
    (void)ws_size; (void)n_in; (void)out_size;

    // ---- CSR by destination
    hipMemsetAsync(deg, 0, (size_t)N * 4, stream);
    hipMemsetAsync(cursor, 0, (size_t)N * 4, stream);
    k_deg<<<(E + 255) / 256, 256, 0, stream>>>(dst, E, deg);
    k_scan<<<1, 256, 0, stream>>>(deg, rowstart, N);
    k_fill<<<(E + 255) / 256, 256, 0, stream>>>(src, dst, E, rowstart, cursor, col);
    k_gbounds<<<1, 128, 0, stream>>>(batch, N, gstart);

    const int MB = (N + 127) / 128;   // 157

    // ---- h0 = relu(x @ Wp + bp) -> split bf16   [N,768]@[768,256]
    k_wsplit<<<(256 * 768 + 255) / 256, 256, 0, stream>>>(Wp, bth, btl, 768, 256);
    k_mfma_gemm<1><<<dim3(256 / 128, MB), 256, 0, stream>>>(
        x, bth, btl, bp, nullptr, h0h, h0l, N, 256, 768);

    // ---- GAT layer 1: hW = h0 @ W1        [N,256]@[256,1024]
    k_wsplit<<<(1024 * 256 + 255) / 256, 256, 0, stream>>>(W1, bth, btl, 256, 1024);
    k_gemm_bf<<<dim3(1024 / 128, MB), 256, 0, stream>>>(h0h, h0l, bth, btl, hW, N, 1024, 256);
    k_scores<<<N, 256, 0, stream>>>(hW, as1, ad1, a_s, a_d, N);
    k_gat2<1><<<N, 256, 0, stream>>>(hW, a_s, a_d, rowstart, col, b1,
                                     nullptr, h1h, h1l, N);

    // ---- GAT layer 2: hW = h1 @ W2        [N,1024]@[1024,1024]
    k_wsplit<<<(1024 * 1024 + 255) / 256, 256, 0, stream>>>(W2, bth, btl, 1024, 1024);
    k_gemm_bf<<<dim3(1024 / 128, MB), 256, 0, stream>>>(h1h, h1l, bth, btl, hW, N, 1024, 1024);
    k_scores<<<N, 256, 0, stream>>>(hW, as2, ad2, a_s, a_d, N);
    k_gat2<0><<<N, 256, 0, stream>>>(hW, a_s, a_d, rowstart, col, b2,
                                     h2, nullptr, nullptr, N);

    // ---- pooling + classifier
    k_pool<<<N_GRAPHS, 256, 0, stream>>>(h2, gstart, gpool);
    k_cls1<<<N_GRAPHS, 256, 0, stream>>>(gpool, Wc1, bc1, hcls);
    k_cls2<<<2, 256, 0, stream>>>(hcls, Wc2, bc2, out);
}

// Round 4
// 773.773 us; speedup vs baseline: 1.8918x; 1.2368x over previous
//
#include <hip/hip_runtime.h>
#include <hip/hip_fp16.h>
#include <math.h>

#define N_HID 256
#define N_HEADS 4
#define N_HC 1024
#define N_GRAPHS 64

typedef __attribute__((ext_vector_type(8))) short short8;
typedef __attribute__((ext_vector_type(4))) float f32x4;

__device__ __forceinline__ unsigned short f2bf(float f) {
    unsigned u = __builtin_bit_cast(unsigned, f);
    unsigned r = (u + 0x7FFFu + ((u >> 16) & 1u)) >> 16;
    return (unsigned short)r;
}
__device__ __forceinline__ float bf2f(unsigned short b) {
    unsigned u = ((unsigned)b) << 16;
    return __builtin_bit_cast(float, u);
}

__device__ __forceinline__ void gl_lds16(const unsigned short* g, unsigned short* l) {
    __builtin_amdgcn_global_load_lds(
        (const __attribute__((address_space(1))) unsigned int*)g,
        (__attribute__((address_space(3))) unsigned int*)l, 16, 0, 0);
}

// ---------------------------------------------------------------- CSR build
__global__ __launch_bounds__(256) void k_deg(const int* __restrict__ dst, int E,
                                             int* __restrict__ deg) {
    int e = blockIdx.x * 256 + threadIdx.x;
    if (e < E) atomicAdd(&deg[dst[e]], 1);
}

__global__ __launch_bounds__(256) void k_scan(const int* __restrict__ deg,
                                              int* __restrict__ rowstart, int N) {
    __shared__ int part[256];
    const int t = threadIdx.x;
    const int chunk = (N + 255) / 256;
    const int c0 = t * chunk;
    int s = 0;
    for (int i = 0; i < chunk; i++) {
        int idx = c0 + i;
        if (idx < N) s += deg[idx];
    }
    part[t] = s;
    __syncthreads();
    for (int off = 1; off < 256; off <<= 1) {
        int v = (t >= off) ? part[t - off] : 0;
        __syncthreads();
        part[t] += v;
        __syncthreads();
    }
    int run = (t == 0) ? 0 : part[t - 1];
    if (t == 0) rowstart[0] = 0;
    for (int i = 0; i < chunk; i++) {
        int idx = c0 + i;
        if (idx < N) {
            run += deg[idx];
            rowstart[idx + 1] = run;
        }
    }
}

__global__ __launch_bounds__(256) void k_fill(const int* __restrict__ src,
                                              const int* __restrict__ dst, int E,
                                              const int* __restrict__ rowstart,
                                              int* __restrict__ cursor,
                                              int* __restrict__ col) {
    int e = blockIdx.x * 256 + threadIdx.x;
    if (e < E) {
        int d = dst[e];
        int p = atomicAdd(&cursor[d], 1);
        col[rowstart[d] + p] = src[e];
    }
}

// ---------------------------------------------------------------- weight split
__global__ __launch_bounds__(256) void k_wsplit(const float* __restrict__ W,
                                                unsigned short* __restrict__ bth,
                                                unsigned short* __restrict__ btl,
                                                int K, int N) {
    int idx = blockIdx.x * 256 + threadIdx.x;
    if (idx >= N * K) return;
    int n = idx / K, k = idx - n * K;
    float v = W[(size_t)k * N + n];
    unsigned short h = f2bf(v);
    bth[idx] = h;
    btl[idx] = f2bf(v - bf2f(h));
}

// ---------------------------------------------------------------- va = W1_h @ att_h
// va[v][k] = sum_c W1[k][ (v&3)*256 + c ] * att[(v&3)][c],  v<4: as, v>=4: ad
__global__ __launch_bounds__(256) void k_makeva(const float* __restrict__ W1,
                                                const float* __restrict__ as1,
                                                const float* __restrict__ ad1,
                                                float* __restrict__ va) {
    int b = blockIdx.x;       // 0..7
    int h = b & 3, isd = b >> 2;
    int k = threadIdx.x;      // 0..255
    const float* att = (isd ? ad1 : as1) + h * 256;
    const float* wr = W1 + (size_t)k * 1024 + h * 256;
    float s = 0.f;
    for (int c = 0; c < 256; c++) s += wr[c] * att[c];
    va[b * 256 + k] = s;
}

// ---------------------------------------------------------------- MFMA GEMM (fp32 A, split-bf16 B)
// EPI 0: fp32 C.  EPI 1: bias+relu -> fp16 C.  EPI 2: bias+ELU -> split bf16 C.
// blockIdx.z advances A by aoffz elems (col offset), B by boffz, C by coffz, bias by bofz.
template <int EPI>
__global__ __launch_bounds__(256) void k_mfma_gemm(
    const float* __restrict__ A,
    const unsigned short* __restrict__ Bth,
    const unsigned short* __restrict__ Btl,
    const float* __restrict__ bias,
    float* __restrict__ Cf, __half* __restrict__ C16,
    unsigned short* __restrict__ Ch, unsigned short* __restrict__ Cl,
    int M, int N, int K, int lda, int ldc,
    int aoffz, int boffz, int coffz, int bofz) {
    constexpr int LDK = 40;
    __shared__ unsigned short sAh[128 * LDK];
    __shared__ unsigned short sAl[128 * LDK];
    __shared__ unsigned short sBh[128 * LDK];
    __shared__ unsigned short sBl[128 * LDK];
    const int z = blockIdx.z;
    A += (size_t)z * aoffz;
    Bth += (size_t)z * boffz;
    Btl += (size_t)z * boffz;
    bias += z * bofz;
    const size_t coff = (size_t)z * coffz;
    const int bm = blockIdx.y * 128, bn = blockIdx.x * 128;
    const int tid = threadIdx.x;
    const int lane = tid & 63, w = tid >> 6;
    const int wr = (w >> 1) * 64, wc = (w & 1) * 64;
    const int sm = tid >> 1;
    const int skb = (tid & 1) * 16;
    const bool rok = (bm + sm) < M;

    f32x4 acc[4][4] = {};

    for (int k0 = 0; k0 < K; k0 += 32) {
        const float* Arow = A + (size_t)(bm + sm) * lda + k0 + skb;
#pragma unroll
        for (int j = 0; j < 4; j++) {
            float4 v = rok ? *(const float4*)(Arow + 4 * j)
                           : make_float4(0.f, 0.f, 0.f, 0.f);
            unsigned short h0 = f2bf(v.x), h1 = f2bf(v.y),
                           h2 = f2bf(v.z), h3 = f2bf(v.w);
            ushort4 hv = {h0, h1, h2, h3};
            ushort4 lv = {f2bf(v.x - bf2f(h0)), f2bf(v.y - bf2f(h1)),
                          f2bf(v.z - bf2f(h2)), f2bf(v.w - bf2f(h3))};
            int o = sm * LDK + skb + 4 * j;
            *(ushort4*)&sAh[o] = hv;
            *(ushort4*)&sAl[o] = lv;
        }
        const unsigned short* Bh = Bth + (size_t)(bn + sm) * K + k0 + skb;
        const unsigned short* Bl = Btl + (size_t)(bn + sm) * K + k0 + skb;
#pragma unroll
        for (int j = 0; j < 2; j++) {
            float4 hv = *(const float4*)(Bh + 8 * j);
            float4 lv = *(const float4*)(Bl + 8 * j);
            int o = sm * LDK + skb + 8 * j;
            *(float4*)&sBh[o] = hv;
            *(float4*)&sBl[o] = lv;
        }
        __syncthreads();
        short8 ah[4], al[4], bh[4], bl[4];
        const int ko = (lane >> 4) * 8;
        const int fr = lane & 15;
#pragma unroll
        for (int i = 0; i < 4; i++) {
            int m = wr + i * 16 + fr;
            ah[i] = *(const short8*)&sAh[m * LDK + ko];
            al[i] = *(const short8*)&sAl[m * LDK + ko];
            int nn = wc + i * 16 + fr;
            bh[i] = *(const short8*)&sBh[nn * LDK + ko];
            bl[i] = *(const short8*)&sBl[nn * LDK + ko];
        }
#pragma unroll
        for (int i = 0; i < 4; i++)
#pragma unroll
            for (int j = 0; j < 4; j++) {
                acc[i][j] = __builtin_amdgcn_mfma_f32_16x16x32_bf16(ah[i], bh[j], acc[i][j], 0, 0, 0);
                acc[i][j] = __builtin_amdgcn_mfma_f32_16x16x32_bf16(ah[i], bl[j], acc[i][j], 0, 0, 0);
                acc[i][j] = __builtin_amdgcn_mfma_f32_16x16x32_bf16(al[i], bh[j], acc[i][j], 0, 0, 0);
            }
        __syncthreads();
    }
    const int crow0 = (lane >> 4) * 4;
    const int ccol = lane & 15;
#pragma unroll
    for (int i = 0; i < 4; i++)
#pragma unroll
        for (int j = 0; j < 4; j++) {
            int cc = bn + wc + j * 16 + ccol;
            float bv = (EPI != 0) ? bias[cc] : 0.f;
#pragma unroll
            for (int r = 0; r < 4; r++) {
                int row = bm + wr + i * 16 + crow0 + r;
                if (row < M) {
                    float v = acc[i][j][r];
                    size_t o = (size_t)row * ldc + coff + cc;
                    if (EPI == 1) {
                        v += bv;
                        v = v > 0.f ? v : 0.f;
                        C16[o] = __float2half(v);
                    } else if (EPI == 2) {
                        v += bv;
                        v = v > 0.f ? v : (__expf(v) - 1.f);
                        unsigned short hi = f2bf(v);
                        Ch[o] = hi;
                        Cl[o] = f2bf(v - bf2f(hi));
                    } else {
                        Cf[o] = v;
                    }
                }
            }
        }
}

// ---------------------------------------------------------------- bf16 GEMM (pre-split A,B) -> fp16 C
__global__ __launch_bounds__(256) void k_gemm_bf(
    const unsigned short* __restrict__ Ah, const unsigned short* __restrict__ Al,
    const unsigned short* __restrict__ Bh, const unsigned short* __restrict__ Bl,
    __half* __restrict__ C16, int M, int N, int K) {
    __shared__ unsigned short sAh[128 * 32];
    __shared__ unsigned short sAl[128 * 32];
    __shared__ unsigned short sBh[128 * 32];
    __shared__ unsigned short sBl[128 * 32];
    const int bm = blockIdx.y * 128, bn = blockIdx.x * 128;
    const int tid = threadIdx.x, lane = tid & 63, w = tid >> 6;
    const int wr = (w >> 1) * 64, wc = (w & 1) * 64;
    const unsigned short* src = (w == 0) ? Ah + (size_t)bm * K
                              : (w == 1) ? Al + (size_t)bm * K
                              : (w == 2) ? Bh + (size_t)bn * K
                                         : Bl + (size_t)bn * K;
    unsigned short* dst = (w == 0) ? sAh : (w == 1) ? sAl : (w == 2) ? sBh : sBl;
    const int ko = (lane >> 4) * 8, fr = lane & 15;
    const int sr = lane >> 2;
    const int skk = (lane & 3) * 8;

    f32x4 acc[4][4] = {};

    for (int k0 = 0; k0 < K; k0 += 32) {
#pragma unroll
        for (int c = 0; c < 8; c++) {
            gl_lds16(src + (size_t)(c * 16 + sr) * K + k0 + skk, dst + c * 512);
        }
        __syncthreads();
        short8 ah[4], al[4], bh[4], bl[4];
#pragma unroll
        for (int i = 0; i < 4; i++) {
            ah[i] = *(const short8*)&sAh[(wr + i * 16 + fr) * 32 + ko];
            al[i] = *(const short8*)&sAl[(wr + i * 16 + fr) * 32 + ko];
            bh[i] = *(const short8*)&sBh[(wc + i * 16 + fr) * 32 + ko];
            bl[i] = *(const short8*)&sBl[(wc + i * 16 + fr) * 32 + ko];
        }
#pragma unroll
        for (int i = 0; i < 4; i++)
#pragma unroll
            for (int j = 0; j < 4; j++) {
                acc[i][j] = __builtin_amdgcn_mfma_f32_16x16x32_bf16(ah[i], bh[j], acc[i][j], 0, 0, 0);
                acc[i][j] = __builtin_amdgcn_mfma_f32_16x16x32_bf16(ah[i], bl[j], acc[i][j], 0, 0, 0);
                acc[i][j] = __builtin_amdgcn_mfma_f32_16x16x32_bf16(al[i], bh[j], acc[i][j], 0, 0, 0);
            }
        __syncthreads();
    }
    const int crow0 = (lane >> 4) * 4;
    const int ccol = lane & 15;
#pragma unroll
    for (int i = 0; i < 4; i++)
#pragma unroll
        for (int j = 0; j < 4; j++) {
            int cc = bn + wc + j * 16 + ccol;
#pragma unroll
            for (int r = 0; r < 4; r++) {
                int row = bm + wr + i * 16 + crow0 + r;
                if (row < M) C16[(size_t)row * N + cc] = __float2half(acc[i][j][r]);
            }
        }
}

// ---------------------------------------------------------------- scores from h0 (layer 1)
// a_s[n][h] = h0[n] . va[h],  a_d[n][h] = h0[n] . va[4+h]
__global__ __launch_bounds__(256) void k_score8(const __half* __restrict__ h0,
                                                const float* __restrict__ va,
                                                float* __restrict__ a_s,
                                                float* __restrict__ a_d, int N) {
    __shared__ float sva[8][256];
    int t = threadIdx.x;
    for (int i = t; i < 2048; i += 256) sva[i >> 8][i & 255] = va[i];
    __syncthreads();
    int wv = t >> 6, lane = t & 63;
    int n = blockIdx.x * 4 + wv;
    if (n >= N) return;
    uint2 u = *(const uint2*)(h0 + (size_t)n * 256 + lane * 4);
    __half2 q0 = __builtin_bit_cast(__half2, u.x);
    __half2 q1 = __builtin_bit_cast(__half2, u.y);
    float v0 = __half2float(q0.x), v1 = __half2float(q0.y);
    float v2 = __half2float(q1.x), v3 = __half2float(q1.y);
    float p[8];
#pragma unroll
    for (int v = 0; v < 8; v++) {
        p[v] = v0 * sva[v][lane * 4] + v1 * sva[v][lane * 4 + 1] +
               v2 * sva[v][lane * 4 + 2] + v3 * sva[v][lane * 4 + 3];
    }
#pragma unroll
    for (int off = 32; off > 0; off >>= 1)
#pragma unroll
        for (int v = 0; v < 8; v++) p[v] += __shfl_xor(p[v], off, 64);
    if (lane == 0) {
        *(float4*)&a_s[n * 4] = make_float4(p[0], p[1], p[2], p[3]);
        *(float4*)&a_d[n * 4] = make_float4(p[4], p[5], p[6], p[7]);
    }
}

// ---------------------------------------------------------------- scores from fp16 hW (layer 2)
__global__ __launch_bounds__(256) void k_scores16(const __half* __restrict__ hW,
                                                  const float* __restrict__ att_s,
                                                  const float* __restrict__ att_d,
                                                  float* __restrict__ a_s,
                                                  float* __restrict__ a_d, int N) {
    int wid = (blockIdx.x * 256 + threadIdx.x) >> 6;
    int lane = threadIdx.x & 63;
    if (wid >= N * 4) return;
    int n = wid >> 2, h = wid & 3;
    uint2 u = *(const uint2*)(hW + (size_t)n * 1024 + h * 256 + lane * 4);
    __half2 q0 = __builtin_bit_cast(__half2, u.x);
    __half2 q1 = __builtin_bit_cast(__half2, u.y);
    float4 v = make_float4(__half2float(q0.x), __half2float(q0.y),
                           __half2float(q1.x), __half2float(q1.y));
    float4 a = *(const float4*)(att_s + h * 256 + lane * 4);
    float4 d = *(const float4*)(att_d + h * 256 + lane * 4);
    float ss = v.x * a.x + v.y * a.y + v.z * a.z + v.w * a.w;
    float sd = v.x * d.x + v.y * d.y + v.z * d.z + v.w * d.w;
#pragma unroll
    for (int off = 32; off > 0; off >>= 1) {
        ss += __shfl_down(ss, off, 64);
        sd += __shfl_down(sd, off, 64);
    }
    if (lane == 0) { a_s[wid] = ss; a_d[wid] = sd; }
}

// ---------------------------------------------------------------- GAT gather+aggregate
// L2=0: gather h0 (256-wide fp16), output agg fp32 [N][4*256] (alpha-weighted, /S).
// L2=1: gather hW2 (1024-wide fp16), epilogue bias+ELU, output h2 fp32.
// Even/odd edge split between block halves; channel pair (2cp,2cp+1) per thread.
template <int L2>
__global__ __launch_bounds__(256) void k_gatagg(
    const __half* __restrict__ srcm, const float* __restrict__ a_s,
    const float* __restrict__ a_d, const int* __restrict__ rowstart,
    const int* __restrict__ col, const float* __restrict__ bias,
    float* __restrict__ outp, int N) {
    __shared__ int sn_lds[256];
    __shared__ float w_lds[256][4];
    __shared__ float redm[4][4], reds[4][4];
    const int n = blockIdx.x, t = threadIdx.x;
    const int lane = t & 63, w = t >> 6;
    const int hf = t >> 7, cp = t & 127;
    const int e0 = rowstart[n];
    const int deg = rowstart[n + 1] - e0;
    const int tot = deg + 1;
    float4 adv4 = *(const float4*)&a_d[n * 4];
    const float adv[4] = {adv4.x, adv4.y, adv4.z, adv4.w};
    float acc[4][2] = {};
    float M[4] = {-INFINITY, -INFINITY, -INFINITY, -INFINITY};
    float S[4] = {0.f, 0.f, 0.f, 0.f};

    for (int base = 0; base < tot; base += 256) {
        const int cnt = min(256, tot - base);
        const bool act = t < cnt;
        float e[4];
        if (act) {
            const int li = base + t;
            const int sn = (li < deg) ? col[e0 + li] : n;
            sn_lds[t] = sn;
            float4 asv = *(const float4*)&a_s[sn * 4];
            const float as4[4] = {asv.x, asv.y, asv.z, asv.w};
#pragma unroll
            for (int h = 0; h < 4; h++) {
                float sc = as4[h] + adv[h];
                e[h] = sc >= 0.f ? sc : 0.2f * sc;
            }
        } else {
#pragma unroll
            for (int h = 0; h < 4; h++) e[h] = -INFINITY;
        }
        float mw[4];
#pragma unroll
        for (int h = 0; h < 4; h++) mw[h] = e[h];
#pragma unroll
        for (int off = 32; off > 0; off >>= 1)
#pragma unroll
            for (int h = 0; h < 4; h++)
                mw[h] = fmaxf(mw[h], __shfl_xor(mw[h], off, 64));
        if (lane == 0)
#pragma unroll
            for (int h = 0; h < 4; h++) redm[w][h] = mw[h];
        __syncthreads();
        float newM[4], wv[4];
#pragma unroll
        for (int h = 0; h < 4; h++) {
            newM[h] = fmaxf(fmaxf(fmaxf(redm[0][h], redm[1][h]),
                                  fmaxf(redm[2][h], redm[3][h])), M[h]);
            wv[h] = act ? __expf(e[h] - newM[h]) : 0.f;
        }
        if (act) *(float4*)&w_lds[t][0] = make_float4(wv[0], wv[1], wv[2], wv[3]);
        float sw[4];
#pragma unroll
        for (int h = 0; h < 4; h++) sw[h] = wv[h];
#pragma unroll
        for (int off = 32; off > 0; off >>= 1)
#pragma unroll
            for (int h = 0; h < 4; h++) sw[h] += __shfl_xor(sw[h], off, 64);
        if (lane == 0)
#pragma unroll
            for (int h = 0; h < 4; h++) reds[w][h] = sw[h];
        __syncthreads();
#pragma unroll
        for (int h = 0; h < 4; h++) {
            float scale = __expf(M[h] - newM[h]);
            S[h] = S[h] * scale + (reds[0][h] + reds[1][h] + reds[2][h] + reds[3][h]);
            acc[h][0] *= scale;
            acc[h][1] *= scale;
            M[h] = newM[h];
        }
        // Phase B: gather
        for (int i = hf; i < cnt; i += 2) {
            const int sn = sn_lds[i];
            float4 w4 = *(const float4*)&w_lds[i][0];
            const float wgt[4] = {w4.x, w4.y, w4.z, w4.w};
            if (L2) {
                const __half* rp = srcm + (size_t)sn * 1024;
#pragma unroll
                for (int h = 0; h < 4; h++) {
                    __half2 hv = *(const __half2*)(rp + h * 256 + 2 * cp);
                    acc[h][0] += wgt[h] * __half2float(hv.x);
                    acc[h][1] += wgt[h] * __half2float(hv.y);
                }
            } else {
                __half2 hv = *(const __half2*)(srcm + (size_t)sn * 256 + 2 * cp);
                float vx = __half2float(hv.x), vy = __half2float(hv.y);
#pragma unroll
                for (int h = 0; h < 4; h++) {
                    acc[h][0] += wgt[h] * vx;
                    acc[h][1] += wgt[h] * vy;
                }
            }
        }
        __syncthreads();
    }
    // merge halves via LDS
    float* mg = &w_lds[0][0];
    if (hf) {
#pragma unroll
        for (int h = 0; h < 4; h++) {
            mg[cp * 8 + h * 2] = acc[h][0];
            mg[cp * 8 + h * 2 + 1] = acc[h][1];
        }
    }
    __syncthreads();
    if (!hf) {
#pragma unroll
        for (int h = 0; h < 4; h++) {
            float d = 1.f / (S[h] + 1e-16f);
            float v0 = (acc[h][0] + mg[cp * 8 + h * 2]) * d;
            float v1 = (acc[h][1] + mg[cp * 8 + h * 2 + 1]) * d;
            if (L2) {
                v0 += bias[h * 256 + 2 * cp];
                v1 += bias[h * 256 + 2 * cp + 1];
                v0 = v0 > 0.f ? v0 : (__expf(v0) - 1.f);
                v1 = v1 > 0.f ? v1 : (__expf(v1) - 1.f);
            }
            *(float2*)(outp + (size_t)n * 1024 + h * 256 + 2 * cp) = make_float2(v0, v1);
        }
    }
}

// ---------------------------------------------------------------- pooling
__global__ __launch_bounds__(128) void k_gbounds(const int* __restrict__ batch, int N,
                                                 int* __restrict__ gstart) {
    int g = threadIdx.x;
    if (g > N_GRAPHS) return;
    if (g == N_GRAPHS) { gstart[N_GRAPHS] = N; return; }
    int lo = 0, hi = N;
    while (lo < hi) {
        int mid = (lo + hi) >> 1;
        if (batch[mid] < g) lo = mid + 1; else hi = mid;
    }
    gstart[g] = lo;
}

__global__ __launch_bounds__(256) void k_pool(const float* __restrict__ h,
                                              const int* __restrict__ gstart,
                                              float* __restrict__ gout) {
    int g = blockIdx.x, t = threadIdx.x;
    int s = gstart[g], e = gstart[g + 1];
    float sum[4] = {0.f, 0.f, 0.f, 0.f};
    float mx[4] = {-INFINITY, -INFINITY, -INFINITY, -INFINITY};
    for (int i = s; i < e; i++) {
        const float* row = h + (size_t)i * N_HC;
#pragma unroll
        for (int j = 0; j < 4; j++) {
            float v = row[t + j * 256];
            sum[j] += v;
            mx[j] = fmaxf(mx[j], v);
        }
    }
    float cnt = fmaxf((float)(e - s), 1.f);
#pragma unroll
    for (int j = 0; j < 4; j++) {
        gout[(size_t)g * 2048 + j * 256 + t] = sum[j] / cnt;
        gout[(size_t)g * 2048 + 1024 + j * 256 + t] = mx[j];
    }
}

// ---------------------------------------------------------------- classifier
__global__ __launch_bounds__(256) void k_cls1(const float* __restrict__ g,
                                              const float* __restrict__ Wc1,
                                              const float* __restrict__ bc1,
                                              float* __restrict__ hcls) {
    __shared__ float gs[2048];
    int gb = blockIdx.x, t = threadIdx.x;
    for (int i = t; i < 2048; i += 256) gs[i] = g[(size_t)gb * 2048 + i];
    __syncthreads();
    float acc = 0.f;
    for (int k = 0; k < 2048; k++) acc += gs[k] * Wc1[(size_t)k * 256 + t];
    float v = acc + bc1[t];
    hcls[gb * 256 + t] = v > 0.f ? v : 0.f;
}

__global__ __launch_bounds__(256) void k_cls2(const float* __restrict__ hcls,
                                              const float* __restrict__ Wc2,
                                              const float* __restrict__ bc2,
                                              float* __restrict__ out) {
    int idx = blockIdx.x * 256 + threadIdx.x;
    if (idx >= N_GRAPHS * 5) return;
    int gb = idx / 5, j = idx % 5;
    float acc = 0.f;
    for (int k = 0; k < 256; k++) acc += hcls[gb * 256 + k] * Wc2[k * 5 + j];
    out[idx] = acc + bc2[j];
}

// ---------------------------------------------------------------- launch
extern "C" void kernel_launch(void* const* d_in, const int* in_sizes, int n_in,
                              void* d_out, int out_size, void* d_ws, size_t ws_size,
                              hipStream_t stream) {
    const float* x    = (const float*)d_in[0];
    const int*   ei   = (const int*)d_in[1];
    const int*   batch= (const int*)d_in[2];
    const float* Wp   = (const float*)d_in[3];
    const float* bp   = (const float*)d_in[4];
    const float* W1   = (const float*)d_in[5];
    const float* as1  = (const float*)d_in[6];
    const float* ad1  = (const float*)d_in[7];
    const float* b1   = (const float*)d_in[8];
    const float* W2   = (const float*)d_in[9];
    const float* as2  = (const float*)d_in[10];
    const float* ad2  = (const float*)d_in[11];
    const float* b2   = (const float*)d_in[12];
    const float* Wc1  = (const float*)d_in[13];
    const float* bc1  = (const float*)d_in[14];
    const float* Wc2  = (const float*)d_in[15];
    const float* bc2  = (const float*)d_in[16];
    float* out = (float*)d_out;

    const int N = in_sizes[0] / 768;   // 20000
    const int E = in_sizes[1] / 2;     // 320000
    const int MP = ((N + 127) / 128) * 128;

    const int* src = ei;
    const int* dst = ei + E;

    char* ws = (char*)d_ws;
    size_t off = 0;
    auto give = [&](size_t bytes) -> void* {
        void* p = ws + off;
        off = (off + bytes + 255) & ~(size_t)255;
        return p;
    };
    __half* h0 = (__half*)give((size_t)MP * N_HID * 2);          // 10.3 MB
    float* agg = (float*)give((size_t)N * N_HC * 4);             // 82 MB (reused as h2)
    unsigned short* h1h = (unsigned short*)give((size_t)MP * N_HC * 2);  // 41 MB
    unsigned short* h1l = (unsigned short*)give((size_t)MP * N_HC * 2);  // 41 MB
    __half* hW2 = (__half*)give((size_t)N * N_HC * 2);           // 41 MB
    float* h2 = agg;
    float* va   = (float*)give((size_t)8 * 256 * 4);
    float* a_s  = (float*)give((size_t)N * N_HEADS * 4);
    float* a_d  = (float*)give((size_t)N * N_HEADS * 4);
    int* deg     = (int*)give((size_t)N * 4);
    int* cursor  = (int*)give((size_t)N * 4);
    int* rowstart= (int*)give((size_t)(N + 1) * 4);
    int* col     = (int*)give((size_t)E * 4);
    int* gstart  = (int*)give((size_t)(N_GRAPHS + 1) * 4);
    float* gpool = (float*)give((size_t)N_GRAPHS * 2048 * 4);
    float* hcls  = (float*)give((size_t)N_GRAPHS * 256 * 4);
    unsigned short* bth = (unsigned short*)give((size_t)1024 * 1024 * 2);
    unsigned short* btl = (unsigned short*)give((size_t)1024 * 1024 * 2);
    (void)ws_size; (void)n_in; (void)out_size;

    // ---- CSR by destination
    hipMemsetAsync(deg, 0, (size_t)N * 4, stream);
    hipMemsetAsync(cursor, 0, (size_t)N * 4, stream);
    k_deg<<<(E + 255) / 256, 256, 0, stream>>>(dst, E, deg);
    k_scan<<<1, 256, 0, stream>>>(deg, rowstart, N);
    k_fill<<<(E + 255) / 256, 256, 0, stream>>>(src, dst, E, rowstart, cursor, col);
    k_gbounds<<<1, 128, 0, stream>>>(batch, N, gstart);

    const int MB = (N + 127) / 128;   // 157

    // ---- h0 = relu(x @ Wp + bp) -> fp16   [N,768]@[768,256]
    k_wsplit<<<(256 * 768 + 255) / 256, 256, 0, stream>>>(Wp, bth, btl, 768, 256);
    k_mfma_gemm<1><<<dim3(2, MB, 1), 256, 0, stream>>>(
        x, bth, btl, bp, nullptr, h0, nullptr, nullptr,
        N, 256, 768, 768, 256, 0, 0, 0, 0);

    // ---- layer-1 scores directly from h0
    k_makeva<<<8, 256, 0, stream>>>(W1, as1, ad1, va);
    k_score8<<<(N + 3) / 4, 256, 0, stream>>>(h0, va, a_s, a_d, N);

    // ---- layer-1 aggregate in h0-space, then per-head transform by W1
    k_gatagg<0><<<N, 256, 0, stream>>>(h0, a_s, a_d, rowstart, col, nullptr, agg, N);
    k_wsplit<<<(1024 * 256 + 255) / 256, 256, 0, stream>>>(W1, bth, btl, 256, 1024);
    k_mfma_gemm<2><<<dim3(2, MB, 4), 256, 0, stream>>>(
        agg, bth, btl, b1, nullptr, nullptr, h1h, h1l,
        N, 256, 256, 1024, 1024, 256, 65536, 256, 256);

    // ---- GAT layer 2: hW2 = h1 @ W2 (fp16 out)   [N,1024]@[1024,1024]
    k_wsplit<<<(1024 * 1024 + 255) / 256, 256, 0, stream>>>(W2, bth, btl, 1024, 1024);
    k_gemm_bf<<<dim3(8, MB), 256, 0, stream>>>(h1h, h1l, bth, btl, hW2, N, 1024, 1024);
    k_scores16<<<N, 256, 0, stream>>>(hW2, as2, ad2, a_s, a_d, N);
    k_gatagg<1><<<N, 256, 0, stream>>>(hW2, a_s, a_d, rowstart, col, b2, h2, N);

    // ---- pooling + classifier
    k_pool<<<N_GRAPHS, 256, 0, stream>>>(h2, gstart, gpool);
    k_cls1<<<N_GRAPHS, 256, 0, stream>>>(gpool, Wc1, bc1, hcls);
    k_cls2<<<2, 256, 0, stream>>>(hcls, Wc2, bc2, out);
}

// Round 5
// 659.825 us; speedup vs baseline: 2.2185x; 1.1727x over previous
//
#include <hip/hip_runtime.h>
#include <hip/hip_fp16.h>
#include <math.h>

#define N_HID 256
#define N_HEADS 4
#define N_HC 1024
#define N_GRAPHS 64

typedef __attribute__((ext_vector_type(4))) float f32x4;
typedef _Float16 half8 __attribute__((ext_vector_type(8)));

__device__ __forceinline__ void gl_lds16h(const __half* g, __half* l) {
    __builtin_amdgcn_global_load_lds(
        (const __attribute__((address_space(1))) unsigned int*)g,
        (__attribute__((address_space(3))) unsigned int*)l, 16, 0, 0);
}

// ---------------------------------------------------------------- CSR build
__global__ __launch_bounds__(256) void k_deg(const int* __restrict__ dst, int E,
                                             int* __restrict__ deg) {
    int e = blockIdx.x * 256 + threadIdx.x;
    if (e < E) atomicAdd(&deg[dst[e]], 1);
}

__global__ __launch_bounds__(256) void k_scan(const int* __restrict__ deg,
                                              int* __restrict__ rowstart, int N) {
    __shared__ int part[256];
    const int t = threadIdx.x;
    const int chunk = (N + 255) / 256;
    const int c0 = t * chunk;
    int s = 0;
    for (int i = 0; i < chunk; i++) {
        int idx = c0 + i;
        if (idx < N) s += deg[idx];
    }
    part[t] = s;
    __syncthreads();
    for (int off = 1; off < 256; off <<= 1) {
        int v = (t >= off) ? part[t - off] : 0;
        __syncthreads();
        part[t] += v;
        __syncthreads();
    }
    int run = (t == 0) ? 0 : part[t - 1];
    if (t == 0) rowstart[0] = 0;
    for (int i = 0; i < chunk; i++) {
        int idx = c0 + i;
        if (idx < N) {
            run += deg[idx];
            rowstart[idx + 1] = run;
        }
    }
}

__global__ __launch_bounds__(256) void k_fill(const int* __restrict__ src,
                                              const int* __restrict__ dst, int E,
                                              const int* __restrict__ rowstart,
                                              int* __restrict__ cursor,
                                              int* __restrict__ col) {
    int e = blockIdx.x * 256 + threadIdx.x;
    if (e < E) {
        int d = dst[e];
        int p = atomicAdd(&cursor[d], 1);
        col[rowstart[d] + p] = src[e];
    }
}

// ---------------------------------------------------------------- fp32 -> fp16 convert
__global__ __launch_bounds__(256) void k_f2h(const float* __restrict__ in,
                                             __half* __restrict__ out, int n) {
    int i = (blockIdx.x * 256 + threadIdx.x) * 4;
    if (i >= n) return;
    float4 v = *(const float4*)(in + i);
    __half2 p0, p1;
    p0.x = __float2half(v.x); p0.y = __float2half(v.y);
    p1.x = __float2half(v.z); p1.y = __float2half(v.w);
    *(__half2*)(out + i) = p0;
    *(__half2*)(out + i + 2) = p1;
}

// ---------------------------------------------------------------- weight transpose fp32[K][N] -> fp16[N][K]
__global__ __launch_bounds__(256) void k_wth(const float* __restrict__ W,
                                             __half* __restrict__ wt, int K, int N) {
    int idx = blockIdx.x * 256 + threadIdx.x;
    if (idx >= N * K) return;
    int n = idx / K, k = idx - n * K;
    wt[idx] = __float2half(W[(size_t)k * N + n]);
}

// ---------------------------------------------------------------- va = W1_h @ att_h
__global__ __launch_bounds__(256) void k_makeva(const float* __restrict__ W1,
                                                const float* __restrict__ as1,
                                                const float* __restrict__ ad1,
                                                float* __restrict__ va) {
    int b = blockIdx.x;       // 0..7
    int h = b & 3, isd = b >> 2;
    int k = threadIdx.x;      // 0..255
    const float* att = (isd ? ad1 : as1) + h * 256;
    const float* wr = W1 + (size_t)k * 1024 + h * 256;
    float s = 0.f;
    for (int c = 0; c < 256; c++) s += wr[c] * att[c];
    va[b * 256 + k] = s;
}

// ---------------------------------------------------------------- fp16 MFMA GEMM
// C[M,N] = A[M,K](fp16, row lda) @ BT[N][K](fp16). 128x128 tile, BK=32,
// global_load_lds with XOR slot swizzle (phys_slot = slot ^ ((row>>1)&3)).
// EPI 0: plain fp16 C; 1: bias+relu fp16; 2: bias+ELU fp16.
template <int EPI>
__global__ __launch_bounds__(256) void k_gemm_h(
    const __half* __restrict__ A, const __half* __restrict__ BT,
    const float* __restrict__ bias, __half* __restrict__ C,
    int M, int N, int K, int lda, int ldc,
    int aoffz, int boffz, int coffz, int bofz) {
    __shared__ __half sA[128 * 32];
    __shared__ __half sB[128 * 32];
    const int z = blockIdx.z;
    A += (size_t)z * aoffz;
    BT += (size_t)z * boffz;
    const int bm = blockIdx.y * 128, bn = blockIdx.x * 128;
    const int tid = threadIdx.x, lane = tid & 63, w = tid >> 6;
    const int wr = (w >> 1) * 64, wc = (w & 1) * 64;
    // staging: waves 0,1 -> sA rows (w&1)*64..+63; waves 2,3 -> sB
    const bool isB = (w >= 2);
    const __half* gsrc = isB ? (BT + (size_t)bn * K) : (A + (size_t)bm * lda);
    const int glda = isB ? K : lda;
    __half* sbuf = isB ? sB : sA;
    const int rbase = (w & 1) * 64;
    const int lr = lane >> 2;        // row within 16-row chunk
    const int lsl = lane & 3;        // physical 16B slot this lane fills

    f32x4 acc[4][4] = {};

    for (int k0 = 0; k0 < K; k0 += 32) {
#pragma unroll
        for (int c = 0; c < 4; c++) {
            int row = rbase + c * 16 + lr;
            int slg = lsl ^ ((row >> 1) & 3);   // logical slot to fetch
            gl_lds16h(gsrc + (size_t)row * glda + k0 + slg * 8,
                      sbuf + (rbase + c * 16) * 32);
        }
        __syncthreads();
        half8 af[4], bf[4];
        const int g = lane >> 4, fr = lane & 15;
#pragma unroll
        for (int i = 0; i < 4; i++) {
            int Ra = wr + i * 16 + fr;
            af[i] = *reinterpret_cast<const half8*>(
                &sA[Ra * 32 + ((g ^ ((Ra >> 1) & 3)) << 3)]);
            int Rb = wc + i * 16 + fr;
            bf[i] = *reinterpret_cast<const half8*>(
                &sB[Rb * 32 + ((g ^ ((Rb >> 1) & 3)) << 3)]);
        }
#pragma unroll
        for (int i = 0; i < 4; i++)
#pragma unroll
            for (int j = 0; j < 4; j++)
                acc[i][j] = __builtin_amdgcn_mfma_f32_16x16x32_f16(af[i], bf[j], acc[i][j], 0, 0, 0);
        __syncthreads();
    }
    const int crow0 = (lane >> 4) * 4, ccol = lane & 15;
    const size_t coff = (size_t)z * coffz;
#pragma unroll
    for (int i = 0; i < 4; i++)
#pragma unroll
        for (int j = 0; j < 4; j++) {
            int cc = bn + wc + j * 16 + ccol;
            float bv = 0.f;
            if (EPI != 0) bv = bias[z * bofz + cc];
#pragma unroll
            for (int r = 0; r < 4; r++) {
                int row = bm + wr + i * 16 + crow0 + r;
                if (row < M) {
                    float v = acc[i][j][r];
                    if (EPI == 1) { v += bv; v = v > 0.f ? v : 0.f; }
                    if (EPI == 2) { v += bv; v = v > 0.f ? v : (__expf(v) - 1.f); }
                    C[(size_t)row * ldc + coff + cc] = __float2half(v);
                }
            }
        }
}

// ---------------------------------------------------------------- scores from h0 (256-wide fp16)
__global__ __launch_bounds__(256) void k_score8(const __half* __restrict__ h0,
                                                const float* __restrict__ va,
                                                float* __restrict__ a_s,
                                                float* __restrict__ a_d, int N) {
    __shared__ float sva[8][256];
    int t = threadIdx.x;
    for (int i = t; i < 2048; i += 256) sva[i >> 8][i & 255] = va[i];
    __syncthreads();
    int wv = t >> 6, lane = t & 63;
    int n = blockIdx.x * 4 + wv;
    if (n >= N) return;
    uint2 u = *(const uint2*)(h0 + (size_t)n * 256 + lane * 4);
    __half2 q0 = __builtin_bit_cast(__half2, u.x);
    __half2 q1 = __builtin_bit_cast(__half2, u.y);
    float v0 = __half2float(q0.x), v1 = __half2float(q0.y);
    float v2 = __half2float(q1.x), v3 = __half2float(q1.y);
    float p[8];
#pragma unroll
    for (int v = 0; v < 8; v++) {
        p[v] = v0 * sva[v][lane * 4] + v1 * sva[v][lane * 4 + 1] +
               v2 * sva[v][lane * 4 + 2] + v3 * sva[v][lane * 4 + 3];
    }
#pragma unroll
    for (int off = 32; off > 0; off >>= 1)
#pragma unroll
        for (int v = 0; v < 8; v++) p[v] += __shfl_xor(p[v], off, 64);
    if (lane == 0) {
        *(float4*)&a_s[n * 4] = make_float4(p[0], p[1], p[2], p[3]);
        *(float4*)&a_d[n * 4] = make_float4(p[4], p[5], p[6], p[7]);
    }
}

// ---------------------------------------------------------------- scores from fp16 hW2 (1024-wide)
__global__ __launch_bounds__(256) void k_scores16(const __half* __restrict__ hW,
                                                  const float* __restrict__ att_s,
                                                  const float* __restrict__ att_d,
                                                  float* __restrict__ a_s,
                                                  float* __restrict__ a_d, int N) {
    int wid = (blockIdx.x * 256 + threadIdx.x) >> 6;
    int lane = threadIdx.x & 63;
    if (wid >= N * 4) return;
    int n = wid >> 2, h = wid & 3;
    uint2 u = *(const uint2*)(hW + (size_t)n * 1024 + h * 256 + lane * 4);
    __half2 q0 = __builtin_bit_cast(__half2, u.x);
    __half2 q1 = __builtin_bit_cast(__half2, u.y);
    float4 v = make_float4(__half2float(q0.x), __half2float(q0.y),
                           __half2float(q1.x), __half2float(q1.y));
    float4 a = *(const float4*)(att_s + h * 256 + lane * 4);
    float4 d = *(const float4*)(att_d + h * 256 + lane * 4);
    float ss = v.x * a.x + v.y * a.y + v.z * a.z + v.w * a.w;
    float sd = v.x * d.x + v.y * d.y + v.z * d.z + v.w * d.w;
#pragma unroll
    for (int off = 32; off > 0; off >>= 1) {
        ss += __shfl_down(ss, off, 64);
        sd += __shfl_down(sd, off, 64);
    }
    if (lane == 0) { a_s[wid] = ss; a_d[wid] = sd; }
}

// ---------------------------------------------------------------- GAT gather+aggregate
// L2=0: gather h0 (256-wide fp16) -> agg1 fp16 [N][4*256] (alpha-weighted, /S).
// L2=1: gather hW2 (1024-wide fp16) -> h2 fp32, epilogue bias+ELU.
template <int L2>
__global__ __launch_bounds__(256) void k_gatagg(
    const __half* __restrict__ srcm, const float* __restrict__ a_s,
    const float* __restrict__ a_d, const int* __restrict__ rowstart,
    const int* __restrict__ col, const float* __restrict__ bias,
    float* __restrict__ outf, __half* __restrict__ outh, int N) {
    __shared__ int sn_lds[256];
    __shared__ float w_lds[256][4];
    __shared__ float redm[4][4], reds[4][4];
    const int n = blockIdx.x, t = threadIdx.x;
    const int lane = t & 63, w = t >> 6;
    const int hf = t >> 7, cp = t & 127;
    const int e0 = rowstart[n];
    const int deg = rowstart[n + 1] - e0;
    const int tot = deg + 1;
    float4 adv4 = *(const float4*)&a_d[n * 4];
    const float adv[4] = {adv4.x, adv4.y, adv4.z, adv4.w};
    float acc[4][2] = {};
    float M[4] = {-INFINITY, -INFINITY, -INFINITY, -INFINITY};
    float S[4] = {0.f, 0.f, 0.f, 0.f};

    for (int base = 0; base < tot; base += 256) {
        const int cnt = min(256, tot - base);
        const bool act = t < cnt;
        float e[4];
        if (act) {
            const int li = base + t;
            const int sn = (li < deg) ? col[e0 + li] : n;
            sn_lds[t] = sn;
            float4 asv = *(const float4*)&a_s[sn * 4];
            const float as4[4] = {asv.x, asv.y, asv.z, asv.w};
#pragma unroll
            for (int h = 0; h < 4; h++) {
                float sc = as4[h] + adv[h];
                e[h] = sc >= 0.f ? sc : 0.2f * sc;
            }
        } else {
#pragma unroll
            for (int h = 0; h < 4; h++) e[h] = -INFINITY;
        }
        float mw[4];
#pragma unroll
        for (int h = 0; h < 4; h++) mw[h] = e[h];
#pragma unroll
        for (int off = 32; off > 0; off >>= 1)
#pragma unroll
            for (int h = 0; h < 4; h++)
                mw[h] = fmaxf(mw[h], __shfl_xor(mw[h], off, 64));
        if (lane == 0)
#pragma unroll
            for (int h = 0; h < 4; h++) redm[w][h] = mw[h];
        __syncthreads();
        float newM[4], wv[4];
#pragma unroll
        for (int h = 0; h < 4; h++) {
            newM[h] = fmaxf(fmaxf(fmaxf(redm[0][h], redm[1][h]),
                                  fmaxf(redm[2][h], redm[3][h])), M[h]);
            wv[h] = act ? __expf(e[h] - newM[h]) : 0.f;
        }
        if (act) *(float4*)&w_lds[t][0] = make_float4(wv[0], wv[1], wv[2], wv[3]);
        float sw[4];
#pragma unroll
        for (int h = 0; h < 4; h++) sw[h] = wv[h];
#pragma unroll
        for (int off = 32; off > 0; off >>= 1)
#pragma unroll
            for (int h = 0; h < 4; h++) sw[h] += __shfl_xor(sw[h], off, 64);
        if (lane == 0)
#pragma unroll
            for (int h = 0; h < 4; h++) reds[w][h] = sw[h];
        __syncthreads();
#pragma unroll
        for (int h = 0; h < 4; h++) {
            float scale = __expf(M[h] - newM[h]);
            S[h] = S[h] * scale + (reds[0][h] + reds[1][h] + reds[2][h] + reds[3][h]);
            acc[h][0] *= scale;
            acc[h][1] *= scale;
            M[h] = newM[h];
        }
        for (int i = hf; i < cnt; i += 2) {
            const int sn = sn_lds[i];
            float4 w4 = *(const float4*)&w_lds[i][0];
            const float wgt[4] = {w4.x, w4.y, w4.z, w4.w};
            if (L2) {
                const __half* rp = srcm + (size_t)sn * 1024;
#pragma unroll
                for (int h = 0; h < 4; h++) {
                    __half2 hv = *(const __half2*)(rp + h * 256 + 2 * cp);
                    acc[h][0] += wgt[h] * __half2float(hv.x);
                    acc[h][1] += wgt[h] * __half2float(hv.y);
                }
            } else {
                __half2 hv = *(const __half2*)(srcm + (size_t)sn * 256 + 2 * cp);
                float vx = __half2float(hv.x), vy = __half2float(hv.y);
#pragma unroll
                for (int h = 0; h < 4; h++) {
                    acc[h][0] += wgt[h] * vx;
                    acc[h][1] += wgt[h] * vy;
                }
            }
        }
        __syncthreads();
    }
    float* mg = &w_lds[0][0];
    if (hf) {
#pragma unroll
        for (int h = 0; h < 4; h++) {
            mg[cp * 8 + h * 2] = acc[h][0];
            mg[cp * 8 + h * 2 + 1] = acc[h][1];
        }
    }
    __syncthreads();
    if (!hf) {
#pragma unroll
        for (int h = 0; h < 4; h++) {
            float d = 1.f / (S[h] + 1e-16f);
            float v0 = (acc[h][0] + mg[cp * 8 + h * 2]) * d;
            float v1 = (acc[h][1] + mg[cp * 8 + h * 2 + 1]) * d;
            if (L2) {
                v0 += bias[h * 256 + 2 * cp];
                v1 += bias[h * 256 + 2 * cp + 1];
                v0 = v0 > 0.f ? v0 : (__expf(v0) - 1.f);
                v1 = v1 > 0.f ? v1 : (__expf(v1) - 1.f);
                *(float2*)(outf + (size_t)n * 1024 + h * 256 + 2 * cp) = make_float2(v0, v1);
            } else {
                __half2 o;
                o.x = __float2half(v0);
                o.y = __float2half(v1);
                *(__half2*)(outh + (size_t)n * 1024 + h * 256 + 2 * cp) = o;
            }
        }
    }
}

// ---------------------------------------------------------------- pooling
__global__ __launch_bounds__(128) void k_gbounds(const int* __restrict__ batch, int N,
                                                 int* __restrict__ gstart) {
    int g = threadIdx.x;
    if (g > N_GRAPHS) return;
    if (g == N_GRAPHS) { gstart[N_GRAPHS] = N; return; }
    int lo = 0, hi = N;
    while (lo < hi) {
        int mid = (lo + hi) >> 1;
        if (batch[mid] < g) lo = mid + 1; else hi = mid;
    }
    gstart[g] = lo;
}

__global__ __launch_bounds__(256) void k_pool(const float* __restrict__ h,
                                              const int* __restrict__ gstart,
                                              float* __restrict__ gout) {
    int g = blockIdx.x, t = threadIdx.x;
    int s = gstart[g], e = gstart[g + 1];
    float sum[4] = {0.f, 0.f, 0.f, 0.f};
    float mx[4] = {-INFINITY, -INFINITY, -INFINITY, -INFINITY};
    for (int i = s; i < e; i++) {
        const float* row = h + (size_t)i * N_HC;
#pragma unroll
        for (int j = 0; j < 4; j++) {
            float v = row[t + j * 256];
            sum[j] += v;
            mx[j] = fmaxf(mx[j], v);
        }
    }
    float cnt = fmaxf((float)(e - s), 1.f);
#pragma unroll
    for (int j = 0; j < 4; j++) {
        gout[(size_t)g * 2048 + j * 256 + t] = sum[j] / cnt;
        gout[(size_t)g * 2048 + 1024 + j * 256 + t] = mx[j];
    }
}

// ---------------------------------------------------------------- classifier
__global__ __launch_bounds__(256) void k_cls1(const float* __restrict__ g,
                                              const float* __restrict__ Wc1,
                                              const float* __restrict__ bc1,
                                              float* __restrict__ hcls) {
    __shared__ float gs[2048];
    int gb = blockIdx.x, t = threadIdx.x;
    for (int i = t; i < 2048; i += 256) gs[i] = g[(size_t)gb * 2048 + i];
    __syncthreads();
    float acc = 0.f;
    for (int k = 0; k < 2048; k++) acc += gs[k] * Wc1[(size_t)k * 256 + t];
    float v = acc + bc1[t];
    hcls[gb * 256 + t] = v > 0.f ? v : 0.f;
}

__global__ __launch_bounds__(256) void k_cls2(const float* __restrict__ hcls,
                                              const float* __restrict__ Wc2,
                                              const float* __restrict__ bc2,
                                              float* __restrict__ out) {
    int idx = blockIdx.x * 256 + threadIdx.x;
    if (idx >= N_GRAPHS * 5) return;
    int gb = idx / 5, j = idx % 5;
    float acc = 0.f;
    for (int k = 0; k < 256; k++) acc += hcls[gb * 256 + k] * Wc2[k * 5 + j];
    out[idx] = acc + bc2[j];
}

// ---------------------------------------------------------------- launch
extern "C" void kernel_launch(void* const* d_in, const int* in_sizes, int n_in,
                              void* d_out, int out_size, void* d_ws, size_t ws_size,
                              hipStream_t stream) {
    const float* x    = (const float*)d_in[0];
    const int*   ei   = (const int*)d_in[1];
    const int*   batch= (const int*)d_in[2];
    const float* Wp   = (const float*)d_in[3];
    const float* bp   = (const float*)d_in[4];
    const float* W1   = (const float*)d_in[5];
    const float* as1  = (const float*)d_in[6];
    const float* ad1  = (const float*)d_in[7];
    const float* b1   = (const float*)d_in[8];
    const float* W2   = (const float*)d_in[9];
    const float* as2  = (const float*)d_in[10];
    const float* ad2  = (const float*)d_in[11];
    const float* b2   = (const float*)d_in[12];
    const float* Wc1  = (const float*)d_in[13];
    const float* bc1  = (const float*)d_in[14];
    const float* Wc2  = (const float*)d_in[15];
    const float* bc2  = (const float*)d_in[16];
    float* out = (float*)d_out;

    const int N = in_sizes[0] / 768;   // 20000
    const int E = in_sizes[1] / 2;     // 320000
    const int MP = ((N + 127) / 128) * 128;   // 20096

    const int* src = ei;
    const int* dst = ei + E;

    char* ws = (char*)d_ws;
    size_t off = 0;
    auto give = [&](size_t bytes) -> void* {
        void* p = ws + off;
        off = (off + bytes + 255) & ~(size_t)255;
        return p;
    };
    __half* xh  = (__half*)give((size_t)MP * 768 * 2);       // 30.9 MB
    __half* h0  = (__half*)give((size_t)MP * N_HID * 2);     // 10.3 MB
    __half* agg1= (__half*)give((size_t)MP * N_HC * 2);      // 41 MB
    __half* h1  = (__half*)give((size_t)MP * N_HC * 2);      // 41 MB
    __half* hW2 = (__half*)give((size_t)MP * N_HC * 2);      // 41 MB
    float* h2   = (float*)give((size_t)N * N_HC * 4);        // 82 MB
    __half* WpT = (__half*)give((size_t)768 * 256 * 2);
    __half* W1T = (__half*)give((size_t)256 * 1024 * 2);
    __half* W2T = (__half*)give((size_t)1024 * 1024 * 2);
    float* va   = (float*)give((size_t)8 * 256 * 4);
    float* a_s  = (float*)give((size_t)N * N_HEADS * 4);
    float* a_d  = (float*)give((size_t)N * N_HEADS * 4);
    int* deg     = (int*)give((size_t)N * 4);
    int* cursor  = (int*)give((size_t)N * 4);
    int* rowstart= (int*)give((size_t)(N + 1) * 4);
    int* col     = (int*)give((size_t)E * 4);
    int* gstart  = (int*)give((size_t)(N_GRAPHS + 1) * 4);
    float* gpool = (float*)give((size_t)N_GRAPHS * 2048 * 4);
    float* hcls  = (float*)give((size_t)N_GRAPHS * 256 * 4);
    (void)ws_size; (void)n_in; (void)out_size;

    // ---- CSR by destination + conversions
    hipMemsetAsync(deg, 0, (size_t)N * 4, stream);
    hipMemsetAsync(cursor, 0, (size_t)N * 4, stream);
    k_deg<<<(E + 255) / 256, 256, 0, stream>>>(dst, E, deg);
    k_scan<<<1, 256, 0, stream>>>(deg, rowstart, N);
    k_fill<<<(E + 255) / 256, 256, 0, stream>>>(src, dst, E, rowstart, cursor, col);
    k_gbounds<<<1, 128, 0, stream>>>(batch, N, gstart);

    k_f2h<<<(N * 768 / 4 + 255) / 256, 256, 0, stream>>>(x, xh, N * 768);
    k_wth<<<(256 * 768 + 255) / 256, 256, 0, stream>>>(Wp, WpT, 768, 256);
    k_wth<<<(1024 * 256 + 255) / 256, 256, 0, stream>>>(W1, W1T, 256, 1024);
    k_wth<<<(1024 * 1024 + 255) / 256, 256, 0, stream>>>(W2, W2T, 1024, 1024);

    const int MB = MP / 128;   // 157

    // ---- h0 = relu(xh @ WpT + bp) fp16   [N,768]@[768,256]
    k_gemm_h<1><<<dim3(2, MB, 1), 256, 0, stream>>>(
        xh, WpT, bp, h0, N, 256, 768, 768, 256, 0, 0, 0, 0);

    // ---- layer-1 scores from h0
    k_makeva<<<8, 256, 0, stream>>>(W1, as1, ad1, va);
    k_score8<<<(N + 3) / 4, 256, 0, stream>>>(h0, va, a_s, a_d, N);

    // ---- layer-1 aggregate in h0-space, then per-head transform by W1 (+bias+ELU)
    k_gatagg<0><<<N, 256, 0, stream>>>(h0, a_s, a_d, rowstart, col, nullptr,
                                       nullptr, agg1, N);
    k_gemm_h<2><<<dim3(2, MB, 4), 256, 0, stream>>>(
        agg1, W1T, b1, h1, N, 256, 256, 1024, 1024, 256, 65536, 256, 256);

    // ---- layer 2: hW2 = h1 @ W2T fp16   [N,1024]@[1024,1024]
    k_gemm_h<0><<<dim3(8, MB, 1), 256, 0, stream>>>(
        h1, W2T, nullptr, hW2, N, 1024, 1024, 1024, 1024, 0, 0, 0, 0);
    k_scores16<<<N, 256, 0, stream>>>(hW2, as2, ad2, a_s, a_d, N);
    k_gatagg<1><<<N, 256, 0, stream>>>(hW2, a_s, a_d, rowstart, col, b2,
                                       h2, nullptr, N);

    // ---- pooling + classifier
    k_pool<<<N_GRAPHS, 256, 0, stream>>>(h2, gstart, gpool);
    k_cls1<<<N_GRAPHS, 256, 0, stream>>>(gpool, Wc1, bc1, hcls);
    k_cls2<<<2, 256, 0, stream>>>(hcls, Wc2, bc2, out);
}

// Round 6
// 581.113 us; speedup vs baseline: 2.5190x; 1.1355x over previous
//
#include <hip/hip_runtime.h>
#include <hip/hip_fp16.h>
#include <math.h>

#define N_HID 256
#define N_HEADS 4
#define N_HC 1024
#define N_GRAPHS 64

typedef __attribute__((ext_vector_type(4))) float f32x4;
typedef _Float16 half8 __attribute__((ext_vector_type(8)));

__device__ __forceinline__ void gl_lds16h(const __half* g, __half* l) {
    __builtin_amdgcn_global_load_lds(
        (const __attribute__((address_space(1))) unsigned int*)g,
        (__attribute__((address_space(3))) unsigned int*)l, 16, 0, 0);
}

// ---------------------------------------------------------------- CSR build
__global__ __launch_bounds__(256) void k_deg(const int* __restrict__ dst, int E,
                                             int* __restrict__ deg) {
    int e = blockIdx.x * 256 + threadIdx.x;
    if (e < E) atomicAdd(&deg[dst[e]], 1);
}

__global__ __launch_bounds__(256) void k_scan(const int* __restrict__ deg,
                                              int* __restrict__ rowstart, int N) {
    __shared__ int part[256];
    const int t = threadIdx.x;
    const int chunk = (N + 255) / 256;
    const int c0 = t * chunk;
    int s = 0;
    for (int i = 0; i < chunk; i++) {
        int idx = c0 + i;
        if (idx < N) s += deg[idx];
    }
    part[t] = s;
    __syncthreads();
    for (int off = 1; off < 256; off <<= 1) {
        int v = (t >= off) ? part[t - off] : 0;
        __syncthreads();
        part[t] += v;
        __syncthreads();
    }
    int run = (t == 0) ? 0 : part[t - 1];
    if (t == 0) rowstart[0] = 0;
    for (int i = 0; i < chunk; i++) {
        int idx = c0 + i;
        if (idx < N) {
            run += deg[idx];
            rowstart[idx + 1] = run;
        }
    }
}

__global__ __launch_bounds__(256) void k_fill(const int* __restrict__ src,
                                              const int* __restrict__ dst, int E,
                                              const int* __restrict__ rowstart,
                                              int* __restrict__ cursor,
                                              int* __restrict__ col) {
    int e = blockIdx.x * 256 + threadIdx.x;
    if (e < E) {
        int d = dst[e];
        int p = atomicAdd(&cursor[d], 1);
        col[rowstart[d] + p] = src[e];
    }
}

// ---------------------------------------------------------------- tiled transpose fp32[K][N] -> fp16[N][K]
__global__ __launch_bounds__(256) void k_wtt(const float* __restrict__ W,
                                             __half* __restrict__ WT, int K, int N) {
    __shared__ float tile[32][33];
    const int k0 = blockIdx.y * 32, n0 = blockIdx.x * 32;
    const int tr = threadIdx.x >> 5, tc = threadIdx.x & 31;
#pragma unroll
    for (int rr = 0; rr < 4; rr++) {
        int k = k0 + tr + rr * 8;
        tile[tr + rr * 8][tc] = W[(size_t)k * N + n0 + tc];
    }
    __syncthreads();
#pragma unroll
    for (int rr = 0; rr < 4; rr++) {
        int n = n0 + tr + rr * 8;
        WT[(size_t)n * K + k0 + tc] = __float2half(tile[tc][tr + rr * 8]);
    }
}

// ---------------------------------------------------------------- va = W1_h @ att_h (from W1T fp16)
__global__ __launch_bounds__(256) void k_makeva(const __half* __restrict__ W1T,
                                                const float* __restrict__ as1,
                                                const float* __restrict__ ad1,
                                                float* __restrict__ va) {
    __shared__ float satt[256];
    int b = blockIdx.x;       // 0..7
    int h = b & 3, isd = b >> 2;
    int k = threadIdx.x;      // 0..255
    const float* att = (isd ? ad1 : as1) + h * 256;
    satt[k] = att[k];
    __syncthreads();
    const __half* wr = W1T + (size_t)(h * 256) * 256 + k;
    float s = 0.f;
    for (int c = 0; c < 256; c++) s += __half2float(wr[(size_t)c * 256]) * satt[c];
    va[b * 256 + k] = s;
}

// ---------------------------------------------------------------- fp16 MFMA GEMM (fp16 A via gl_lds)
// C[M,N] = A[M,K](fp16) @ BT[N][K](fp16). 128x128 tile, BK=32, XOR slot swizzle.
// EPI 0: plain fp16 C; 2: bias+ELU fp16.
template <int EPI>
__global__ __launch_bounds__(256) void k_gemm_h(
    const __half* __restrict__ A, const __half* __restrict__ BT,
    const float* __restrict__ bias, __half* __restrict__ C,
    int M, int N, int K, int lda, int ldc,
    int aoffz, int boffz, int coffz, int bofz) {
    __shared__ __half sA[128 * 32];
    __shared__ __half sB[128 * 32];
    const int z = blockIdx.z;
    A += (size_t)z * aoffz;
    BT += (size_t)z * boffz;
    const int bm = blockIdx.y * 128, bn = blockIdx.x * 128;
    const int tid = threadIdx.x, lane = tid & 63, w = tid >> 6;
    const int wr = (w >> 1) * 64, wc = (w & 1) * 64;
    const bool isB = (w >= 2);
    const __half* gsrc = isB ? (BT + (size_t)bn * K) : (A + (size_t)bm * lda);
    const int glda = isB ? K : lda;
    __half* sbuf = isB ? sB : sA;
    const int rbase = (w & 1) * 64;
    const int lr = lane >> 2;
    const int lsl = lane & 3;

    f32x4 acc[4][4] = {};

    for (int k0 = 0; k0 < K; k0 += 32) {
#pragma unroll
        for (int c = 0; c < 4; c++) {
            int row = rbase + c * 16 + lr;
            int slg = lsl ^ ((row >> 1) & 3);
            gl_lds16h(gsrc + (size_t)row * glda + k0 + slg * 8,
                      sbuf + (rbase + c * 16) * 32);
        }
        __syncthreads();
        half8 af[4], bf[4];
        const int g = lane >> 4, fr = lane & 15;
#pragma unroll
        for (int i = 0; i < 4; i++) {
            int Ra = wr + i * 16 + fr;
            af[i] = *reinterpret_cast<const half8*>(
                &sA[Ra * 32 + ((g ^ ((Ra >> 1) & 3)) << 3)]);
            int Rb = wc + i * 16 + fr;
            bf[i] = *reinterpret_cast<const half8*>(
                &sB[Rb * 32 + ((g ^ ((Rb >> 1) & 3)) << 3)]);
        }
#pragma unroll
        for (int i = 0; i < 4; i++)
#pragma unroll
            for (int j = 0; j < 4; j++)
                acc[i][j] = __builtin_amdgcn_mfma_f32_16x16x32_f16(af[i], bf[j], acc[i][j], 0, 0, 0);
        __syncthreads();
    }
    const int crow0 = (lane >> 4) * 4, ccol = lane & 15;
    const size_t coff = (size_t)z * coffz;
#pragma unroll
    for (int i = 0; i < 4; i++)
#pragma unroll
        for (int j = 0; j < 4; j++) {
            int cc = bn + wc + j * 16 + ccol;
            float bv = 0.f;
            if (EPI != 0) bv = bias[z * bofz + cc];
#pragma unroll
            for (int r = 0; r < 4; r++) {
                int row = bm + wr + i * 16 + crow0 + r;
                if (row < M) {
                    float v = acc[i][j][r];
                    if (EPI == 2) { v += bv; v = v > 0.f ? v : (__expf(v) - 1.f); }
                    C[(size_t)row * ldc + coff + cc] = __float2half(v);
                }
            }
        }
}

// ---------------------------------------------------------------- fp32-A MFMA GEMM (fused convert), bias+relu
__global__ __launch_bounds__(256) void k_gemm_x(
    const float* __restrict__ A, const __half* __restrict__ BT,
    const float* __restrict__ bias, __half* __restrict__ C,
    int M, int N, int K, int lda) {
    __shared__ __half sA[128 * 32];
    __shared__ __half sB[128 * 32];
    const int bm = blockIdx.y * 128, bn = blockIdx.x * 128;
    const int tid = threadIdx.x, lane = tid & 63, w = tid >> 6;
    const int wr = (w >> 1) * 64, wc = (w & 1) * 64;
    const int sm = tid >> 1, skb = (tid & 1) * 16;
    const bool rok = (bm + sm) < M;
    const int ph0 = (((tid & 1) * 2 + 0) ^ ((sm >> 1) & 3)) << 3;
    const int ph1 = (((tid & 1) * 2 + 1) ^ ((sm >> 1) & 3)) << 3;
    const int lr = lane >> 2, lsl = lane & 3;

    f32x4 acc[4][4] = {};

    for (int k0 = 0; k0 < K; k0 += 32) {
        // B stage via gl_lds (pre-swizzled source)
#pragma unroll
        for (int c = 0; c < 2; c++) {
            int rb = (w + c * 4) * 16;
            int row = rb + lr;
            int slg = lsl ^ ((row >> 1) & 3);
            gl_lds16h(BT + (size_t)(bn + row) * K + k0 + slg * 8, sB + rb * 32);
        }
        // A stage: fp32 -> fp16 in reg, swizzled ds_write
        {
            const float* Arow = A + (size_t)(bm + sm) * lda + k0 + skb;
            float4 v0 = make_float4(0.f, 0.f, 0.f, 0.f), v1 = v0, v2 = v0, v3 = v0;
            if (rok) {
                v0 = *(const float4*)(Arow + 0);
                v1 = *(const float4*)(Arow + 4);
                v2 = *(const float4*)(Arow + 8);
                v3 = *(const float4*)(Arow + 12);
            }
            half8 ha, hb;
            ha[0] = (_Float16)v0.x; ha[1] = (_Float16)v0.y;
            ha[2] = (_Float16)v0.z; ha[3] = (_Float16)v0.w;
            ha[4] = (_Float16)v1.x; ha[5] = (_Float16)v1.y;
            ha[6] = (_Float16)v1.z; ha[7] = (_Float16)v1.w;
            hb[0] = (_Float16)v2.x; hb[1] = (_Float16)v2.y;
            hb[2] = (_Float16)v2.z; hb[3] = (_Float16)v2.w;
            hb[4] = (_Float16)v3.x; hb[5] = (_Float16)v3.y;
            hb[6] = (_Float16)v3.z; hb[7] = (_Float16)v3.w;
            *reinterpret_cast<half8*>(&sA[sm * 32 + ph0]) = ha;
            *reinterpret_cast<half8*>(&sA[sm * 32 + ph1]) = hb;
        }
        __syncthreads();
        half8 af[4], bf[4];
        const int g = lane >> 4, fr = lane & 15;
#pragma unroll
        for (int i = 0; i < 4; i++) {
            int Ra = wr + i * 16 + fr;
            af[i] = *reinterpret_cast<const half8*>(
                &sA[Ra * 32 + ((g ^ ((Ra >> 1) & 3)) << 3)]);
            int Rb = wc + i * 16 + fr;
            bf[i] = *reinterpret_cast<const half8*>(
                &sB[Rb * 32 + ((g ^ ((Rb >> 1) & 3)) << 3)]);
        }
#pragma unroll
        for (int i = 0; i < 4; i++)
#pragma unroll
            for (int j = 0; j < 4; j++)
                acc[i][j] = __builtin_amdgcn_mfma_f32_16x16x32_f16(af[i], bf[j], acc[i][j], 0, 0, 0);
        __syncthreads();
    }
    const int crow0 = (lane >> 4) * 4, ccol = lane & 15;
#pragma unroll
    for (int i = 0; i < 4; i++)
#pragma unroll
        for (int j = 0; j < 4; j++) {
            int cc = bn + wc + j * 16 + ccol;
            float bv = bias[cc];
#pragma unroll
            for (int r = 0; r < 4; r++) {
                int row = bm + wr + i * 16 + crow0 + r;
                if (row < M) {
                    float v = acc[i][j][r] + bv;
                    v = v > 0.f ? v : 0.f;
                    C[(size_t)row * N + cc] = __float2half(v);
                }
            }
        }
}

// ---------------------------------------------------------------- scores from h0 (256-wide fp16)
__global__ __launch_bounds__(256) void k_score8(const __half* __restrict__ h0,
                                                const float* __restrict__ va,
                                                float* __restrict__ a_s,
                                                float* __restrict__ a_d, int N) {
    __shared__ float sva[8][256];
    int t = threadIdx.x;
    for (int i = t; i < 2048; i += 256) sva[i >> 8][i & 255] = va[i];
    __syncthreads();
    int wv = t >> 6, lane = t & 63;
    int n = blockIdx.x * 4 + wv;
    if (n >= N) return;
    uint2 u = *(const uint2*)(h0 + (size_t)n * 256 + lane * 4);
    __half2 q0 = __builtin_bit_cast(__half2, u.x);
    __half2 q1 = __builtin_bit_cast(__half2, u.y);
    float v0 = __half2float(q0.x), v1 = __half2float(q0.y);
    float v2 = __half2float(q1.x), v3 = __half2float(q1.y);
    float p[8];
#pragma unroll
    for (int v = 0; v < 8; v++) {
        p[v] = v0 * sva[v][lane * 4] + v1 * sva[v][lane * 4 + 1] +
               v2 * sva[v][lane * 4 + 2] + v3 * sva[v][lane * 4 + 3];
    }
#pragma unroll
    for (int off = 32; off > 0; off >>= 1)
#pragma unroll
        for (int v = 0; v < 8; v++) p[v] += __shfl_xor(p[v], off, 64);
    if (lane == 0) {
        *(float4*)&a_s[n * 4] = make_float4(p[0], p[1], p[2], p[3]);
        *(float4*)&a_d[n * 4] = make_float4(p[4], p[5], p[6], p[7]);
    }
}

// ---------------------------------------------------------------- scores from fp16 hW2 (1024-wide)
__global__ __launch_bounds__(256) void k_scores16(const __half* __restrict__ hW,
                                                  const float* __restrict__ att_s,
                                                  const float* __restrict__ att_d,
                                                  float* __restrict__ a_s,
                                                  float* __restrict__ a_d, int N) {
    int wid = (blockIdx.x * 256 + threadIdx.x) >> 6;
    int lane = threadIdx.x & 63;
    if (wid >= N * 4) return;
    int n = wid >> 2, h = wid & 3;
    uint2 u = *(const uint2*)(hW + (size_t)n * 1024 + h * 256 + lane * 4);
    __half2 q0 = __builtin_bit_cast(__half2, u.x);
    __half2 q1 = __builtin_bit_cast(__half2, u.y);
    float4 v = make_float4(__half2float(q0.x), __half2float(q0.y),
                           __half2float(q1.x), __half2float(q1.y));
    float4 a = *(const float4*)(att_s + h * 256 + lane * 4);
    float4 d = *(const float4*)(att_d + h * 256 + lane * 4);
    float ss = v.x * a.x + v.y * a.y + v.z * a.z + v.w * a.w;
    float sd = v.x * d.x + v.y * d.y + v.z * d.z + v.w * d.w;
#pragma unroll
    for (int off = 32; off > 0; off >>= 1) {
        ss += __shfl_down(ss, off, 64);
        sd += __shfl_down(sd, off, 64);
    }
    if (lane == 0) { a_s[wid] = ss; a_d[wid] = sd; }
}

// ---------------------------------------------------------------- GAT layer-1 gather (wave per node)
// gather h0 (256-wide fp16) -> agg1 fp16 [N][1024] (alpha-weighted, /S)
__global__ __launch_bounds__(256) void k_gat_w1(
    const __half* __restrict__ h0, const float* __restrict__ a_s,
    const float* __restrict__ a_d, const int* __restrict__ rowstart,
    const int* __restrict__ col, __half* __restrict__ agg1, int N) {
    __shared__ float wal[4][64][4];
    __shared__ int wsn[4][64];
    const int w = threadIdx.x >> 6, lane = threadIdx.x & 63;
    const int n = blockIdx.x * 4 + w;
    if (n >= N) return;
    const int e0 = rowstart[n];
    const int deg = rowstart[n + 1] - e0;
    const int tot = deg + 1;
    float4 adv4 = *(const float4*)&a_d[n * 4];
    const float adv[4] = {adv4.x, adv4.y, adv4.z, adv4.w};
    float M[4] = {-INFINITY, -INFINITY, -INFINITY, -INFINITY};
    float S[4] = {0.f, 0.f, 0.f, 0.f};
    float acc[4][4] = {};

    for (int base = 0; base < tot; base += 64) {
        const int cnt = min(64, tot - base);
        const bool act = lane < cnt;
        float e[4];
        int sn = n;
        if (act) {
            const int li = base + lane;
            sn = (li < deg) ? col[e0 + li] : n;
            float4 asv = *(const float4*)&a_s[sn * 4];
            const float as4[4] = {asv.x, asv.y, asv.z, asv.w};
#pragma unroll
            for (int h = 0; h < 4; h++) {
                float sc = as4[h] + adv[h];
                e[h] = sc >= 0.f ? sc : 0.2f * sc;
            }
        } else {
#pragma unroll
            for (int h = 0; h < 4; h++) e[h] = -INFINITY;
        }
        float mw[4] = {e[0], e[1], e[2], e[3]};
#pragma unroll
        for (int off = 32; off > 0; off >>= 1)
#pragma unroll
            for (int h = 0; h < 4; h++)
                mw[h] = fmaxf(mw[h], __shfl_xor(mw[h], off, 64));
        float wv[4], sw[4];
#pragma unroll
        for (int h = 0; h < 4; h++) {
            mw[h] = fmaxf(mw[h], M[h]);
            wv[h] = act ? __expf(e[h] - mw[h]) : 0.f;
            sw[h] = wv[h];
        }
        wsn[w][lane] = sn;
        *(float4*)&wal[w][lane][0] = make_float4(wv[0], wv[1], wv[2], wv[3]);
#pragma unroll
        for (int off = 32; off > 0; off >>= 1)
#pragma unroll
            for (int h = 0; h < 4; h++) sw[h] += __shfl_xor(sw[h], off, 64);
#pragma unroll
        for (int h = 0; h < 4; h++) {
            float scale = __expf(M[h] - mw[h]);
            S[h] = S[h] * scale + sw[h];
#pragma unroll
            for (int c = 0; c < 4; c++) acc[h][c] *= scale;
            M[h] = mw[h];
        }
        for (int i = 0; i < cnt; i++) {
            const int s2 = wsn[w][i];
            float4 wg = *(const float4*)&wal[w][i][0];
            const float wgt[4] = {wg.x, wg.y, wg.z, wg.w};
            uint2 u = *(const uint2*)(h0 + (size_t)s2 * 256 + lane * 4);
            __half2 q0 = __builtin_bit_cast(__half2, u.x);
            __half2 q1 = __builtin_bit_cast(__half2, u.y);
            const float v[4] = {__half2float(q0.x), __half2float(q0.y),
                                __half2float(q1.x), __half2float(q1.y)};
#pragma unroll
            for (int h = 0; h < 4; h++)
#pragma unroll
                for (int c = 0; c < 4; c++) acc[h][c] += wgt[h] * v[c];
        }
    }
#pragma unroll
    for (int h = 0; h < 4; h++) {
        float d = 1.f / (S[h] + 1e-16f);
        __half2 o0, o1;
        o0.x = __float2half(acc[h][0] * d); o0.y = __float2half(acc[h][1] * d);
        o1.x = __float2half(acc[h][2] * d); o1.y = __float2half(acc[h][3] * d);
        *(__half2*)(agg1 + (size_t)n * 1024 + h * 256 + lane * 4) = o0;
        *(__half2*)(agg1 + (size_t)n * 1024 + h * 256 + lane * 4 + 2) = o1;
    }
}

// ---------------------------------------------------------------- GAT layer-2 gather (wave per node)
// gather hW2 (1024-wide fp16) -> h2 fp16, epilogue bias+ELU
__global__ __launch_bounds__(256) void k_gat_w2(
    const __half* __restrict__ hW, const float* __restrict__ a_s,
    const float* __restrict__ a_d, const int* __restrict__ rowstart,
    const int* __restrict__ col, const float* __restrict__ bias,
    __half* __restrict__ h2, int N) {
    __shared__ float wal[4][64][4];
    __shared__ int wsn[4][64];
    const int w = threadIdx.x >> 6, lane = threadIdx.x & 63;
    const int n = blockIdx.x * 4 + w;
    if (n >= N) return;
    const int e0 = rowstart[n];
    const int deg = rowstart[n + 1] - e0;
    const int tot = deg + 1;
    float4 adv4 = *(const float4*)&a_d[n * 4];
    const float adv[4] = {adv4.x, adv4.y, adv4.z, adv4.w};
    float M[4] = {-INFINITY, -INFINITY, -INFINITY, -INFINITY};
    float S[4] = {0.f, 0.f, 0.f, 0.f};
    float acc[2][8] = {};
    const bool hiq = (lane & 32) != 0;   // head parity within pass

    for (int base = 0; base < tot; base += 64) {
        const int cnt = min(64, tot - base);
        const bool act = lane < cnt;
        float e[4];
        int sn = n;
        if (act) {
            const int li = base + lane;
            sn = (li < deg) ? col[e0 + li] : n;
            float4 asv = *(const float4*)&a_s[sn * 4];
            const float as4[4] = {asv.x, asv.y, asv.z, asv.w};
#pragma unroll
            for (int h = 0; h < 4; h++) {
                float sc = as4[h] + adv[h];
                e[h] = sc >= 0.f ? sc : 0.2f * sc;
            }
        } else {
#pragma unroll
            for (int h = 0; h < 4; h++) e[h] = -INFINITY;
        }
        float mw[4] = {e[0], e[1], e[2], e[3]};
#pragma unroll
        for (int off = 32; off > 0; off >>= 1)
#pragma unroll
            for (int h = 0; h < 4; h++)
                mw[h] = fmaxf(mw[h], __shfl_xor(mw[h], off, 64));
        float wv[4], sw[4];
#pragma unroll
        for (int h = 0; h < 4; h++) {
            mw[h] = fmaxf(mw[h], M[h]);
            wv[h] = act ? __expf(e[h] - mw[h]) : 0.f;
            sw[h] = wv[h];
        }
        wsn[w][lane] = sn;
        *(float4*)&wal[w][lane][0] = make_float4(wv[0], wv[1], wv[2], wv[3]);
#pragma unroll
        for (int off = 32; off > 0; off >>= 1)
#pragma unroll
            for (int h = 0; h < 4; h++) sw[h] += __shfl_xor(sw[h], off, 64);
#pragma unroll
        for (int h = 0; h < 4; h++) {
            float scale = __expf(M[h] - mw[h]);
            S[h] = S[h] * scale + sw[h];
            M[h] = mw[h];
#pragma unroll
            for (int p = 0; p < 2; p++) {
                int hh = p * 2 + (hiq ? 1 : 0);
                if (hh == h) {
#pragma unroll
                    for (int c = 0; c < 8; c++) acc[p][c] *= scale;
                }
            }
        }
        for (int i = 0; i < cnt; i++) {
            const int s2 = wsn[w][i];
            float4 wg = *(const float4*)&wal[w][i][0];
            const float wlo = hiq ? wg.y : wg.x;   // pass 0 head
            const float whi = hiq ? wg.w : wg.z;   // pass 1 head
            const __half* rp = hW + (size_t)s2 * 1024 + lane * 8;
            half8 h0v = *reinterpret_cast<const half8*>(rp);
            half8 h1v = *reinterpret_cast<const half8*>(rp + 512);
#pragma unroll
            for (int c = 0; c < 8; c++) {
                acc[0][c] += wlo * (float)h0v[c];
                acc[1][c] += whi * (float)h1v[c];
            }
        }
    }
    const float d0 = 1.f / (S[hiq ? 1 : 0] + 1e-16f);
    const float d1 = 1.f / (S[hiq ? 3 : 2] + 1e-16f);
#pragma unroll
    for (int p = 0; p < 2; p++) {
        const float dp = p == 0 ? d0 : d1;
        const int chb = p * 512 + lane * 8;
        float4 b0 = *(const float4*)&bias[chb];
        float4 b1 = *(const float4*)&bias[chb + 4];
        const float bb[8] = {b0.x, b0.y, b0.z, b0.w, b1.x, b1.y, b1.z, b1.w};
        half8 o;
#pragma unroll
        for (int c = 0; c < 8; c++) {
            float v = acc[p][c] * dp + bb[c];
            v = v > 0.f ? v : (__expf(v) - 1.f);
            o[c] = (_Float16)v;
        }
        *reinterpret_cast<half8*>(h2 + (size_t)n * 1024 + chb) = o;
    }
}

// ---------------------------------------------------------------- pooling
__global__ __launch_bounds__(128) void k_gbounds(const int* __restrict__ batch, int N,
                                                 int* __restrict__ gstart) {
    int g = threadIdx.x;
    if (g > N_GRAPHS) return;
    if (g == N_GRAPHS) { gstart[N_GRAPHS] = N; return; }
    int lo = 0, hi = N;
    while (lo < hi) {
        int mid = (lo + hi) >> 1;
        if (batch[mid] < g) lo = mid + 1; else hi = mid;
    }
    gstart[g] = lo;
}

__global__ __launch_bounds__(256) void k_pool(const __half* __restrict__ h,
                                              const int* __restrict__ gstart,
                                              float* __restrict__ gout) {
    int g = blockIdx.x, t = threadIdx.x;
    int s = gstart[g], e = gstart[g + 1];
    float sum[2][2] = {};
    float mx[2][2] = {{-INFINITY, -INFINITY}, {-INFINITY, -INFINITY}};
    for (int i = s; i < e; i++) {
        const __half* row = h + (size_t)i * N_HC;
#pragma unroll
        for (int j = 0; j < 2; j++) {
            __half2 hv = *(const __half2*)(row + j * 512 + 2 * t);
            float v0 = __half2float(hv.x), v1 = __half2float(hv.y);
            sum[j][0] += v0; sum[j][1] += v1;
            mx[j][0] = fmaxf(mx[j][0], v0);
            mx[j][1] = fmaxf(mx[j][1], v1);
        }
    }
    float cnt = fmaxf((float)(e - s), 1.f);
#pragma unroll
    for (int j = 0; j < 2; j++) {
        *(float2*)(gout + (size_t)g * 2048 + j * 512 + 2 * t) =
            make_float2(sum[j][0] / cnt, sum[j][1] / cnt);
        *(float2*)(gout + (size_t)g * 2048 + 1024 + j * 512 + 2 * t) =
            make_float2(mx[j][0], mx[j][1]);
    }
}

// ---------------------------------------------------------------- classifier
__global__ __launch_bounds__(256) void k_cls1(const float* __restrict__ g,
                                              const float* __restrict__ Wc1,
                                              const float* __restrict__ bc1,
                                              float* __restrict__ hcls) {
    __shared__ float gs[2048];
    int gb = blockIdx.x, t = threadIdx.x;
    for (int i = t; i < 2048; i += 256) gs[i] = g[(size_t)gb * 2048 + i];
    __syncthreads();
    float acc = 0.f;
    for (int k = 0; k < 2048; k++) acc += gs[k] * Wc1[(size_t)k * 256 + t];
    float v = acc + bc1[t];
    hcls[gb * 256 + t] = v > 0.f ? v : 0.f;
}

__global__ __launch_bounds__(256) void k_cls2(const float* __restrict__ hcls,
                                              const float* __restrict__ Wc2,
                                              const float* __restrict__ bc2,
                                              float* __restrict__ out) {
    int idx = blockIdx.x * 256 + threadIdx.x;
    if (idx >= N_GRAPHS * 5) return;
    int gb = idx / 5, j = idx % 5;
    float acc = 0.f;
    for (int k = 0; k < 256; k++) acc += hcls[gb * 256 + k] * Wc2[k * 5 + j];
    out[idx] = acc + bc2[j];
}

// ---------------------------------------------------------------- launch
extern "C" void kernel_launch(void* const* d_in, const int* in_sizes, int n_in,
                              void* d_out, int out_size, void* d_ws, size_t ws_size,
                              hipStream_t stream) {
    const float* x    = (const float*)d_in[0];
    const int*   ei   = (const int*)d_in[1];
    const int*   batch= (const int*)d_in[2];
    const float* Wp   = (const float*)d_in[3];
    const float* bp   = (const float*)d_in[4];
    const float* W1   = (const float*)d_in[5];
    const float* as1  = (const float*)d_in[6];
    const float* ad1  = (const float*)d_in[7];
    const float* b1   = (const float*)d_in[8];
    const float* W2   = (const float*)d_in[9];
    const float* as2  = (const float*)d_in[10];
    const float* ad2  = (const float*)d_in[11];
    const float* b2   = (const float*)d_in[12];
    const float* Wc1  = (const float*)d_in[13];
    const float* bc1  = (const float*)d_in[14];
    const float* Wc2  = (const float*)d_in[15];
    const float* bc2  = (const float*)d_in[16];
    float* out = (float*)d_out;

    const int N = in_sizes[0] / 768;   // 20000
    const int E = in_sizes[1] / 2;     // 320000
    const int MP = ((N + 127) / 128) * 128;   // 20096

    const int* src = ei;
    const int* dst = ei + E;

    char* ws = (char*)d_ws;
    size_t off = 0;
    auto give = [&](size_t bytes) -> void* {
        void* p = ws + off;
        off = (off + bytes + 255) & ~(size_t)255;
        return p;
    };
    __half* h0  = (__half*)give((size_t)MP * N_HID * 2);     // 10.3 MB
    __half* agg1= (__half*)give((size_t)MP * N_HC * 2);      // 41 MB
    __half* h1  = (__half*)give((size_t)MP * N_HC * 2);      // 41 MB
    __half* hW2 = (__half*)give((size_t)MP * N_HC * 2);      // 41 MB
    __half* h2  = (__half*)give((size_t)MP * N_HC * 2);      // 41 MB
    __half* WpT = (__half*)give((size_t)768 * 256 * 2);
    __half* W1T = (__half*)give((size_t)256 * 1024 * 2);
    __half* W2T = (__half*)give((size_t)1024 * 1024 * 2);
    float* va   = (float*)give((size_t)8 * 256 * 4);
    float* a_s  = (float*)give((size_t)N * N_HEADS * 4);
    float* a_d  = (float*)give((size_t)N * N_HEADS * 4);
    int* deg     = (int*)give((size_t)N * 4);
    int* cursor  = (int*)give((size_t)N * 4);
    int* rowstart= (int*)give((size_t)(N + 1) * 4);
    int* col     = (int*)give((size_t)E * 4);
    int* gstart  = (int*)give((size_t)(N_GRAPHS + 1) * 4);
    float* gpool = (float*)give((size_t)N_GRAPHS * 2048 * 4);
    float* hcls  = (float*)give((size_t)N_GRAPHS * 256 * 4);
    (void)ws_size; (void)n_in; (void)out_size;

    // ---- CSR + prep
    hipMemsetAsync(deg, 0, (size_t)N * 4, stream);
    hipMemsetAsync(cursor, 0, (size_t)N * 4, stream);
    k_deg<<<(E + 255) / 256, 256, 0, stream>>>(dst, E, deg);
    k_scan<<<1, 256, 0, stream>>>(deg, rowstart, N);
    k_fill<<<(E + 255) / 256, 256, 0, stream>>>(src, dst, E, rowstart, cursor, col);
    k_gbounds<<<1, 128, 0, stream>>>(batch, N, gstart);

    k_wtt<<<dim3(256 / 32, 768 / 32), 256, 0, stream>>>(Wp, WpT, 768, 256);
    k_wtt<<<dim3(1024 / 32, 256 / 32), 256, 0, stream>>>(W1, W1T, 256, 1024);
    k_wtt<<<dim3(1024 / 32, 1024 / 32), 256, 0, stream>>>(W2, W2T, 1024, 1024);

    const int MB = MP / 128;   // 157

    // ---- h0 = relu(x @ WpT + bp) fp16 (fused fp32->fp16 A convert)
    k_gemm_x<<<dim3(2, MB), 256, 0, stream>>>(x, WpT, bp, h0, N, 256, 768, 768);

    // ---- layer-1 scores from h0
    k_makeva<<<8, 256, 0, stream>>>(W1T, as1, ad1, va);
    k_score8<<<(N + 3) / 4, 256, 0, stream>>>(h0, va, a_s, a_d, N);

    // ---- layer-1 aggregate in h0-space, then per-head transform by W1 (+bias+ELU)
    k_gat_w1<<<(N + 3) / 4, 256, 0, stream>>>(h0, a_s, a_d, rowstart, col, agg1, N);
    k_gemm_h<2><<<dim3(2, MB, 4), 256, 0, stream>>>(
        agg1, W1T, b1, h1, N, 256, 256, 1024, 1024, 256, 65536, 256, 256);

    // ---- layer 2
    k_gemm_h<0><<<dim3(8, MB, 1), 256, 0, stream>>>(
        h1, W2T, nullptr, hW2, N, 1024, 1024, 1024, 1024, 0, 0, 0, 0);
    k_scores16<<<N, 256, 0, stream>>>(hW2, as2, ad2, a_s, a_d, N);
    k_gat_w2<<<(N + 3) / 4, 256, 0, stream>>>(hW2, a_s, a_d, rowstart, col, b2, h2, N);

    // ---- pooling + classifier
    k_pool<<<N_GRAPHS, 256, 0, stream>>>(h2, gstart, gpool);
    k_cls1<<<N_GRAPHS, 256, 0, stream>>>(gpool, Wc1, bc1, hcls);
    k_cls2<<<2, 256, 0, stream>>>(hcls, Wc2, bc2, out);
}

// Round 7
// 561.617 us; speedup vs baseline: 2.6065x; 1.0347x over previous
//
#include <hip/hip_runtime.h>
#include <hip/hip_fp16.h>
#include <math.h>

#define N_HID 256
#define N_HEADS 4
#define N_HC 1024
#define N_GRAPHS 64

typedef __attribute__((ext_vector_type(4))) float f32x4;
typedef _Float16 half8 __attribute__((ext_vector_type(8)));
typedef _Float16 half4 __attribute__((ext_vector_type(4)));

__device__ __forceinline__ void gl_lds16h(const __half* g, __half* l) {
    __builtin_amdgcn_global_load_lds(
        (const __attribute__((address_space(1))) unsigned int*)g,
        (__attribute__((address_space(3))) unsigned int*)l, 16, 0, 0);
}

// ---------------------------------------------------------------- CSR build
__global__ __launch_bounds__(256) void k_deg(const int* __restrict__ dst, int E,
                                             int* __restrict__ deg) {
    int e = blockIdx.x * 256 + threadIdx.x;
    if (e < E) atomicAdd(&deg[dst[e]], 1);
}

__global__ __launch_bounds__(256) void k_scan(const int* __restrict__ deg,
                                              int* __restrict__ rowstart, int N) {
    __shared__ int part[256];
    const int t = threadIdx.x;
    const int chunk = (N + 255) / 256;
    const int c0 = t * chunk;
    int s = 0;
    for (int i = 0; i < chunk; i++) {
        int idx = c0 + i;
        if (idx < N) s += deg[idx];
    }
    part[t] = s;
    __syncthreads();
    for (int off = 1; off < 256; off <<= 1) {
        int v = (t >= off) ? part[t - off] : 0;
        __syncthreads();
        part[t] += v;
        __syncthreads();
    }
    int run = (t == 0) ? 0 : part[t - 1];
    if (t == 0) rowstart[0] = 0;
    for (int i = 0; i < chunk; i++) {
        int idx = c0 + i;
        if (idx < N) {
            run += deg[idx];
            rowstart[idx + 1] = run;
        }
    }
}

__global__ __launch_bounds__(256) void k_fill(const int* __restrict__ src,
                                              const int* __restrict__ dst, int E,
                                              const int* __restrict__ rowstart,
                                              int* __restrict__ cursor,
                                              int* __restrict__ col) {
    int e = blockIdx.x * 256 + threadIdx.x;
    if (e < E) {
        int d = dst[e];
        int p = atomicAdd(&cursor[d], 1);
        col[rowstart[d] + p] = src[e];
    }
}

// ---------------------------------------------------------------- tiled transpose fp32[K][N] -> fp16[N][K]
__global__ __launch_bounds__(256) void k_wtt(const float* __restrict__ W,
                                             __half* __restrict__ WT, int K, int N) {
    __shared__ float tile[32][33];
    const int k0 = blockIdx.y * 32, n0 = blockIdx.x * 32;
    const int tr = threadIdx.x >> 5, tc = threadIdx.x & 31;
#pragma unroll
    for (int rr = 0; rr < 4; rr++) {
        int k = k0 + tr + rr * 8;
        tile[tr + rr * 8][tc] = W[(size_t)k * N + n0 + tc];
    }
    __syncthreads();
#pragma unroll
    for (int rr = 0; rr < 4; rr++) {
        int n = n0 + tr + rr * 8;
        WT[(size_t)n * K + k0 + tc] = __float2half(tile[tc][tr + rr * 8]);
    }
}

// ---------------------------------------------------------------- va = W1_h @ att_h (from W1T fp16)
__global__ __launch_bounds__(256) void k_makeva(const __half* __restrict__ W1T,
                                                const float* __restrict__ as1,
                                                const float* __restrict__ ad1,
                                                float* __restrict__ va) {
    __shared__ float satt[256];
    int b = blockIdx.x;       // 0..7
    int h = b & 3, isd = b >> 2;
    int k = threadIdx.x;      // 0..255
    const float* att = (isd ? ad1 : as1) + h * 256;
    satt[k] = att[k];
    __syncthreads();
    const __half* wr = W1T + (size_t)(h * 256) * 256 + k;
    float s = 0.f;
    for (int c = 0; c < 256; c++) s += __half2float(wr[(size_t)c * 256]) * satt[c];
    va[b * 256 + k] = s;
}

// ---------------------------------------------------------------- fp16 MFMA GEMM (fp16 A via gl_lds)
template <int EPI>
__global__ __launch_bounds__(256) void k_gemm_h(
    const __half* __restrict__ A, const __half* __restrict__ BT,
    const float* __restrict__ bias, __half* __restrict__ C,
    int M, int N, int K, int lda, int ldc,
    int aoffz, int boffz, int coffz, int bofz) {
    __shared__ __half sA[128 * 32];
    __shared__ __half sB[128 * 32];
    const int z = blockIdx.z;
    A += (size_t)z * aoffz;
    BT += (size_t)z * boffz;
    const int bm = blockIdx.y * 128, bn = blockIdx.x * 128;
    const int tid = threadIdx.x, lane = tid & 63, w = tid >> 6;
    const int wr = (w >> 1) * 64, wc = (w & 1) * 64;
    const bool isB = (w >= 2);
    const __half* gsrc = isB ? (BT + (size_t)bn * K) : (A + (size_t)bm * lda);
    const int glda = isB ? K : lda;
    __half* sbuf = isB ? sB : sA;
    const int rbase = (w & 1) * 64;
    const int lr = lane >> 2;
    const int lsl = lane & 3;

    f32x4 acc[4][4] = {};

    for (int k0 = 0; k0 < K; k0 += 32) {
#pragma unroll
        for (int c = 0; c < 4; c++) {
            int row = rbase + c * 16 + lr;
            int slg = lsl ^ ((row >> 1) & 3);
            gl_lds16h(gsrc + (size_t)row * glda + k0 + slg * 8,
                      sbuf + (rbase + c * 16) * 32);
        }
        __syncthreads();
        half8 af[4], bf[4];
        const int g = lane >> 4, fr = lane & 15;
#pragma unroll
        for (int i = 0; i < 4; i++) {
            int Ra = wr + i * 16 + fr;
            af[i] = *reinterpret_cast<const half8*>(
                &sA[Ra * 32 + ((g ^ ((Ra >> 1) & 3)) << 3)]);
            int Rb = wc + i * 16 + fr;
            bf[i] = *reinterpret_cast<const half8*>(
                &sB[Rb * 32 + ((g ^ ((Rb >> 1) & 3)) << 3)]);
        }
#pragma unroll
        for (int i = 0; i < 4; i++)
#pragma unroll
            for (int j = 0; j < 4; j++)
                acc[i][j] = __builtin_amdgcn_mfma_f32_16x16x32_f16(af[i], bf[j], acc[i][j], 0, 0, 0);
        __syncthreads();
    }
    const int crow0 = (lane >> 4) * 4, ccol = lane & 15;
    const size_t coff = (size_t)z * coffz;
#pragma unroll
    for (int i = 0; i < 4; i++)
#pragma unroll
        for (int j = 0; j < 4; j++) {
            int cc = bn + wc + j * 16 + ccol;
            float bv = 0.f;
            if (EPI != 0) bv = bias[z * bofz + cc];
#pragma unroll
            for (int r = 0; r < 4; r++) {
                int row = bm + wr + i * 16 + crow0 + r;
                if (row < M) {
                    float v = acc[i][j][r];
                    if (EPI == 2) { v += bv; v = v > 0.f ? v : (__expf(v) - 1.f); }
                    C[(size_t)row * ldc + coff + cc] = __float2half(v);
                }
            }
        }
}

// ---------------------------------------------------------------- fp32-A MFMA GEMM (fused convert), bias+relu
__global__ __launch_bounds__(256) void k_gemm_x(
    const float* __restrict__ A, const __half* __restrict__ BT,
    const float* __restrict__ bias, __half* __restrict__ C,
    int M, int N, int K, int lda) {
    __shared__ __half sA[128 * 32];
    __shared__ __half sB[128 * 32];
    const int bm = blockIdx.y * 128, bn = blockIdx.x * 128;
    const int tid = threadIdx.x, lane = tid & 63, w = tid >> 6;
    const int wr = (w >> 1) * 64, wc = (w & 1) * 64;
    const int sm = tid >> 1, skb = (tid & 1) * 16;
    const bool rok = (bm + sm) < M;
    const int ph0 = (((tid & 1) * 2 + 0) ^ ((sm >> 1) & 3)) << 3;
    const int ph1 = (((tid & 1) * 2 + 1) ^ ((sm >> 1) & 3)) << 3;
    const int lr = lane >> 2, lsl = lane & 3;

    f32x4 acc[4][4] = {};

    for (int k0 = 0; k0 < K; k0 += 32) {
#pragma unroll
        for (int c = 0; c < 2; c++) {
            int rb = (w + c * 4) * 16;
            int row = rb + lr;
            int slg = lsl ^ ((row >> 1) & 3);
            gl_lds16h(BT + (size_t)(bn + row) * K + k0 + slg * 8, sB + rb * 32);
        }
        {
            const float* Arow = A + (size_t)(bm + sm) * lda + k0 + skb;
            float4 v0 = make_float4(0.f, 0.f, 0.f, 0.f), v1 = v0, v2 = v0, v3 = v0;
            if (rok) {
                v0 = *(const float4*)(Arow + 0);
                v1 = *(const float4*)(Arow + 4);
                v2 = *(const float4*)(Arow + 8);
                v3 = *(const float4*)(Arow + 12);
            }
            half8 ha, hb;
            ha[0] = (_Float16)v0.x; ha[1] = (_Float16)v0.y;
            ha[2] = (_Float16)v0.z; ha[3] = (_Float16)v0.w;
            ha[4] = (_Float16)v1.x; ha[5] = (_Float16)v1.y;
            ha[6] = (_Float16)v1.z; ha[7] = (_Float16)v1.w;
            hb[0] = (_Float16)v2.x; hb[1] = (_Float16)v2.y;
            hb[2] = (_Float16)v2.z; hb[3] = (_Float16)v2.w;
            hb[4] = (_Float16)v3.x; hb[5] = (_Float16)v3.y;
            hb[6] = (_Float16)v3.z; hb[7] = (_Float16)v3.w;
            *reinterpret_cast<half8*>(&sA[sm * 32 + ph0]) = ha;
            *reinterpret_cast<half8*>(&sA[sm * 32 + ph1]) = hb;
        }
        __syncthreads();
        half8 af[4], bf[4];
        const int g = lane >> 4, fr = lane & 15;
#pragma unroll
        for (int i = 0; i < 4; i++) {
            int Ra = wr + i * 16 + fr;
            af[i] = *reinterpret_cast<const half8*>(
                &sA[Ra * 32 + ((g ^ ((Ra >> 1) & 3)) << 3)]);
            int Rb = wc + i * 16 + fr;
            bf[i] = *reinterpret_cast<const half8*>(
                &sB[Rb * 32 + ((g ^ ((Rb >> 1) & 3)) << 3)]);
        }
#pragma unroll
        for (int i = 0; i < 4; i++)
#pragma unroll
            for (int j = 0; j < 4; j++)
                acc[i][j] = __builtin_amdgcn_mfma_f32_16x16x32_f16(af[i], bf[j], acc[i][j], 0, 0, 0);
        __syncthreads();
    }
    const int crow0 = (lane >> 4) * 4, ccol = lane & 15;
#pragma unroll
    for (int i = 0; i < 4; i++)
#pragma unroll
        for (int j = 0; j < 4; j++) {
            int cc = bn + wc + j * 16 + ccol;
            float bv = bias[cc];
#pragma unroll
            for (int r = 0; r < 4; r++) {
                int row = bm + wr + i * 16 + crow0 + r;
                if (row < M) {
                    float v = acc[i][j][r] + bv;
                    v = v > 0.f ? v : 0.f;
                    C[(size_t)row * N + cc] = __float2half(v);
                }
            }
        }
}

// ---------------------------------------------------------------- scores from h0 (256-wide fp16)
__global__ __launch_bounds__(256) void k_score8(const __half* __restrict__ h0,
                                                const float* __restrict__ va,
                                                float* __restrict__ a_s,
                                                float* __restrict__ a_d, int N) {
    __shared__ float sva[8][256];
    int t = threadIdx.x;
    for (int i = t; i < 2048; i += 256) sva[i >> 8][i & 255] = va[i];
    __syncthreads();
    int wv = t >> 6, lane = t & 63;
    int n = blockIdx.x * 4 + wv;
    if (n >= N) return;
    uint2 u = *(const uint2*)(h0 + (size_t)n * 256 + lane * 4);
    __half2 q0 = __builtin_bit_cast(__half2, u.x);
    __half2 q1 = __builtin_bit_cast(__half2, u.y);
    float v0 = __half2float(q0.x), v1 = __half2float(q0.y);
    float v2 = __half2float(q1.x), v3 = __half2float(q1.y);
    float p[8];
#pragma unroll
    for (int v = 0; v < 8; v++) {
        p[v] = v0 * sva[v][lane * 4] + v1 * sva[v][lane * 4 + 1] +
               v2 * sva[v][lane * 4 + 2] + v3 * sva[v][lane * 4 + 3];
    }
#pragma unroll
    for (int off = 32; off > 0; off >>= 1)
#pragma unroll
        for (int v = 0; v < 8; v++) p[v] += __shfl_xor(p[v], off, 64);
    if (lane == 0) {
        *(float4*)&a_s[n * 4] = make_float4(p[0], p[1], p[2], p[3]);
        *(float4*)&a_d[n * 4] = make_float4(p[4], p[5], p[6], p[7]);
    }
}

// ---------------------------------------------------------------- scores from fp16 hW2 (1024-wide)
__global__ __launch_bounds__(256) void k_scores16(const __half* __restrict__ hW,
                                                  const float* __restrict__ att_s,
                                                  const float* __restrict__ att_d,
                                                  float* __restrict__ a_s,
                                                  float* __restrict__ a_d, int N) {
    int wid = (blockIdx.x * 256 + threadIdx.x) >> 6;
    int lane = threadIdx.x & 63;
    if (wid >= N * 4) return;
    int n = wid >> 2, h = wid & 3;
    uint2 u = *(const uint2*)(hW + (size_t)n * 1024 + h * 256 + lane * 4);
    __half2 q0 = __builtin_bit_cast(__half2, u.x);
    __half2 q1 = __builtin_bit_cast(__half2, u.y);
    float4 v = make_float4(__half2float(q0.x), __half2float(q0.y),
                           __half2float(q1.x), __half2float(q1.y));
    float4 a = *(const float4*)(att_s + h * 256 + lane * 4);
    float4 d = *(const float4*)(att_d + h * 256 + lane * 4);
    float ss = v.x * a.x + v.y * a.y + v.z * a.z + v.w * a.w;
    float sd = v.x * d.x + v.y * d.y + v.z * d.z + v.w * d.w;
#pragma unroll
    for (int off = 32; off > 0; off >>= 1) {
        ss += __shfl_down(ss, off, 64);
        sd += __shfl_down(sd, off, 64);
    }
    if (lane == 0) { a_s[wid] = ss; a_d[wid] = sd; }
}

// ---------------------------------------------------------------- GAT layer-1 gather
// 2 waves per node (head-pairs). Wave (ni,q): node blockIdx*2+ni, heads {2q, 2q+1}.
// Gathers full 256-wide h0 row (8B/lane), 8 FMA/edge/lane. No __syncthreads.
__global__ __launch_bounds__(256) void k_gat_w1(
    const __half* __restrict__ h0, const float* __restrict__ a_s,
    const float* __restrict__ a_d, const int* __restrict__ rowstart,
    const int* __restrict__ col, __half* __restrict__ agg1, int N) {
    __shared__ int wsn[4][64];
    __shared__ float wal[4][64][2];
    const int w = threadIdx.x >> 6, lane = threadIdx.x & 63;
    const int ni = w >> 1, q = w & 1;
    const int n = blockIdx.x * 2 + ni;
    if (n >= N) return;
    const int hh0 = q * 2;
    const int e0 = rowstart[n];
    const int deg = rowstart[n + 1] - e0;
    const int tot = deg + 1;
    const float adv0 = a_d[n * 4 + hh0], adv1 = a_d[n * 4 + hh0 + 1];
    float M0 = -INFINITY, M1 = -INFINITY, S0 = 0.f, S1 = 0.f;
    float acc0[4] = {}, acc1[4] = {};

    for (int base = 0; base < tot; base += 64) {
        const int cnt = min(64, tot - base);
        const bool act = lane < cnt;
        int sn = n;
        float ev0 = -INFINITY, ev1 = -INFINITY;
        if (act) {
            const int li = base + lane;
            sn = (li < deg) ? col[e0 + li] : n;
            float s0 = a_s[sn * 4 + hh0] + adv0;
            float s1 = a_s[sn * 4 + hh0 + 1] + adv1;
            ev0 = s0 >= 0.f ? s0 : 0.2f * s0;
            ev1 = s1 >= 0.f ? s1 : 0.2f * s1;
        }
        float m0 = ev0, m1 = ev1;
#pragma unroll
        for (int off = 32; off > 0; off >>= 1) {
            m0 = fmaxf(m0, __shfl_xor(m0, off, 64));
            m1 = fmaxf(m1, __shfl_xor(m1, off, 64));
        }
        m0 = fmaxf(m0, M0); m1 = fmaxf(m1, M1);
        float w0 = act ? __expf(ev0 - m0) : 0.f;
        float w1 = act ? __expf(ev1 - m1) : 0.f;
        wsn[w][lane] = sn;
        wal[w][lane][0] = w0;
        wal[w][lane][1] = w1;
        float s0 = w0, s1 = w1;
#pragma unroll
        for (int off = 32; off > 0; off >>= 1) {
            s0 += __shfl_xor(s0, off, 64);
            s1 += __shfl_xor(s1, off, 64);
        }
        float sc0 = __expf(M0 - m0), sc1 = __expf(M1 - m1);
        S0 = S0 * sc0 + s0; S1 = S1 * sc1 + s1;
        M0 = m0; M1 = m1;
#pragma unroll
        for (int c = 0; c < 4; c++) { acc0[c] *= sc0; acc1[c] *= sc1; }
#pragma unroll 2
        for (int i = 0; i < cnt; i++) {
            const int s2 = wsn[w][i];
            const float a0 = wal[w][i][0], a1 = wal[w][i][1];
            uint2 u = *(const uint2*)(h0 + (size_t)s2 * 256 + lane * 4);
            __half2 p0 = __builtin_bit_cast(__half2, u.x);
            __half2 p1 = __builtin_bit_cast(__half2, u.y);
            const float v[4] = {__half2float(p0.x), __half2float(p0.y),
                                __half2float(p1.x), __half2float(p1.y)};
#pragma unroll
            for (int c = 0; c < 4; c++) {
                acc0[c] += a0 * v[c];
                acc1[c] += a1 * v[c];
            }
        }
    }
    const float d0 = 1.f / (S0 + 1e-16f), d1 = 1.f / (S1 + 1e-16f);
    half4 o0, o1;
#pragma unroll
    for (int c = 0; c < 4; c++) {
        o0[c] = (_Float16)(acc0[c] * d0);
        o1[c] = (_Float16)(acc1[c] * d1);
    }
    *reinterpret_cast<half4*>(agg1 + (size_t)n * 1024 + hh0 * 256 + lane * 4) = o0;
    *reinterpret_cast<half4*>(agg1 + (size_t)n * 1024 + (hh0 + 1) * 256 + lane * 4) = o1;
}

// ---------------------------------------------------------------- GAT layer-2 gather
// 2 waves per node (channel halves). Wave (ni,q): node blockIdx*2+ni,
// channels q*512..q*512+511 (heads 2q, 2q+1). 16B/lane/edge. No __syncthreads.
__global__ __launch_bounds__(256) void k_gat_w2(
    const __half* __restrict__ hW, const float* __restrict__ a_s,
    const float* __restrict__ a_d, const int* __restrict__ rowstart,
    const int* __restrict__ col, const float* __restrict__ bias,
    __half* __restrict__ h2, int N) {
    __shared__ int wsn[4][64];
    __shared__ float wal[4][64][2];
    const int w = threadIdx.x >> 6, lane = threadIdx.x & 63;
    const int ni = w >> 1, q = w & 1;
    const int n = blockIdx.x * 2 + ni;
    if (n >= N) return;
    const int hh0 = q * 2;
    const int hiq = lane >> 5;      // which of the 2 heads this lane's channels fall in
    const int e0 = rowstart[n];
    const int deg = rowstart[n + 1] - e0;
    const int tot = deg + 1;
    const float adv0 = a_d[n * 4 + hh0], adv1 = a_d[n * 4 + hh0 + 1];
    float M0 = -INFINITY, M1 = -INFINITY, S0 = 0.f, S1 = 0.f;
    float acc[8] = {};

    for (int base = 0; base < tot; base += 64) {
        const int cnt = min(64, tot - base);
        const bool act = lane < cnt;
        int sn = n;
        float ev0 = -INFINITY, ev1 = -INFINITY;
        if (act) {
            const int li = base + lane;
            sn = (li < deg) ? col[e0 + li] : n;
            float s0 = a_s[sn * 4 + hh0] + adv0;
            float s1 = a_s[sn * 4 + hh0 + 1] + adv1;
            ev0 = s0 >= 0.f ? s0 : 0.2f * s0;
            ev1 = s1 >= 0.f ? s1 : 0.2f * s1;
        }
        float m0 = ev0, m1 = ev1;
#pragma unroll
        for (int off = 32; off > 0; off >>= 1) {
            m0 = fmaxf(m0, __shfl_xor(m0, off, 64));
            m1 = fmaxf(m1, __shfl_xor(m1, off, 64));
        }
        m0 = fmaxf(m0, M0); m1 = fmaxf(m1, M1);
        float w0 = act ? __expf(ev0 - m0) : 0.f;
        float w1 = act ? __expf(ev1 - m1) : 0.f;
        wsn[w][lane] = sn;
        wal[w][lane][0] = w0;
        wal[w][lane][1] = w1;
        float s0 = w0, s1 = w1;
#pragma unroll
        for (int off = 32; off > 0; off >>= 1) {
            s0 += __shfl_xor(s0, off, 64);
            s1 += __shfl_xor(s1, off, 64);
        }
        float sc0 = __expf(M0 - m0), sc1 = __expf(M1 - m1);
        S0 = S0 * sc0 + s0; S1 = S1 * sc1 + s1;
        M0 = m0; M1 = m1;
        const float accsc = hiq ? sc1 : sc0;
#pragma unroll
        for (int c = 0; c < 8; c++) acc[c] *= accsc;
        const __half* gbase = hW + q * 512 + lane * 8;
#pragma unroll 2
        for (int i = 0; i < cnt; i++) {
            const int s2 = wsn[w][i];
            const float a = wal[w][i][hiq];
            half8 v = *reinterpret_cast<const half8*>(gbase + (size_t)s2 * 1024);
#pragma unroll
            for (int c = 0; c < 8; c++) acc[c] += a * (float)v[c];
        }
    }
    const float S = hiq ? S1 : S0;
    const float d = 1.f / (S + 1e-16f);
    const int chb = q * 512 + lane * 8;
    float4 b0 = *(const float4*)&bias[chb];
    float4 b1 = *(const float4*)&bias[chb + 4];
    const float bb[8] = {b0.x, b0.y, b0.z, b0.w, b1.x, b1.y, b1.z, b1.w};
    half8 o;
#pragma unroll
    for (int c = 0; c < 8; c++) {
        float v = acc[c] * d + bb[c];
        v = v > 0.f ? v : (__expf(v) - 1.f);
        o[c] = (_Float16)v;
    }
    *reinterpret_cast<half8*>(h2 + (size_t)n * 1024 + chb) = o;
}

// ---------------------------------------------------------------- pooling
__global__ __launch_bounds__(128) void k_gbounds(const int* __restrict__ batch, int N,
                                                 int* __restrict__ gstart) {
    int g = threadIdx.x;
    if (g > N_GRAPHS) return;
    if (g == N_GRAPHS) { gstart[N_GRAPHS] = N; return; }
    int lo = 0, hi = N;
    while (lo < hi) {
        int mid = (lo + hi) >> 1;
        if (batch[mid] < g) lo = mid + 1; else hi = mid;
    }
    gstart[g] = lo;
}

// grid (64 graphs, 4 channel slices), block 128, half2 per thread
__global__ __launch_bounds__(128) void k_pool(const __half* __restrict__ h,
                                              const int* __restrict__ gstart,
                                              float* __restrict__ gout) {
    int g = blockIdx.x, t = threadIdx.x;
    int c = blockIdx.y * 256 + 2 * t;
    int s = gstart[g], e = gstart[g + 1];
    float s0 = 0.f, s1 = 0.f;
    float m0 = -INFINITY, m1 = -INFINITY;
    for (int i = s; i < e; i++) {
        __half2 hv = *(const __half2*)(h + (size_t)i * N_HC + c);
        float v0 = __half2float(hv.x), v1 = __half2float(hv.y);
        s0 += v0; s1 += v1;
        m0 = fmaxf(m0, v0); m1 = fmaxf(m1, v1);
    }
    float cnt = fmaxf((float)(e - s), 1.f);
    *(float2*)(gout + (size_t)g * 2048 + c) = make_float2(s0 / cnt, s1 / cnt);
    *(float2*)(gout + (size_t)g * 2048 + 1024 + c) = make_float2(m0, m1);
}

// ---------------------------------------------------------------- classifier
__global__ __launch_bounds__(256) void k_cls1(const float* __restrict__ g,
                                              const float* __restrict__ Wc1,
                                              const float* __restrict__ bc1,
                                              float* __restrict__ hcls) {
    __shared__ float gs[2048];
    int gb = blockIdx.x, t = threadIdx.x;
    for (int i = t; i < 2048; i += 256) gs[i] = g[(size_t)gb * 2048 + i];
    __syncthreads();
    float acc = 0.f;
    for (int k = 0; k < 2048; k++) acc += gs[k] * Wc1[(size_t)k * 256 + t];
    float v = acc + bc1[t];
    hcls[gb * 256 + t] = v > 0.f ? v : 0.f;
}

__global__ __launch_bounds__(256) void k_cls2(const float* __restrict__ hcls,
                                              const float* __restrict__ Wc2,
                                              const float* __restrict__ bc2,
                                              float* __restrict__ out) {
    int idx = blockIdx.x * 256 + threadIdx.x;
    if (idx >= N_GRAPHS * 5) return;
    int gb = idx / 5, j = idx % 5;
    float acc = 0.f;
    for (int k = 0; k < 256; k++) acc += hcls[gb * 256 + k] * Wc2[k * 5 + j];
    out[idx] = acc + bc2[j];
}

// ---------------------------------------------------------------- launch
extern "C" void kernel_launch(void* const* d_in, const int* in_sizes, int n_in,
                              void* d_out, int out_size, void* d_ws, size_t ws_size,
                              hipStream_t stream) {
    const float* x    = (const float*)d_in[0];
    const int*   ei   = (const int*)d_in[1];
    const int*   batch= (const int*)d_in[2];
    const float* Wp   = (const float*)d_in[3];
    const float* bp   = (const float*)d_in[4];
    const float* W1   = (const float*)d_in[5];
    const float* as1  = (const float*)d_in[6];
    const float* ad1  = (const float*)d_in[7];
    const float* b1   = (const float*)d_in[8];
    const float* W2   = (const float*)d_in[9];
    const float* as2  = (const float*)d_in[10];
    const float* ad2  = (const float*)d_in[11];
    const float* b2   = (const float*)d_in[12];
    const float* Wc1  = (const float*)d_in[13];
    const float* bc1  = (const float*)d_in[14];
    const float* Wc2  = (const float*)d_in[15];
    const float* bc2  = (const float*)d_in[16];
    float* out = (float*)d_out;

    const int N = in_sizes[0] / 768;   // 20000
    const int E = in_sizes[1] / 2;     // 320000
    const int MP = ((N + 127) / 128) * 128;   // 20096

    const int* src = ei;
    const int* dst = ei + E;

    char* ws = (char*)d_ws;
    size_t off = 0;
    auto give = [&](size_t bytes) -> void* {
        void* p = ws + off;
        off = (off + bytes + 255) & ~(size_t)255;
        return p;
    };
    __half* h0  = (__half*)give((size_t)MP * N_HID * 2);     // 10.3 MB
    __half* agg1= (__half*)give((size_t)MP * N_HC * 2);      // 41 MB
    __half* h1  = (__half*)give((size_t)MP * N_HC * 2);      // 41 MB
    __half* hW2 = (__half*)give((size_t)MP * N_HC * 2);      // 41 MB
    __half* h2  = (__half*)give((size_t)MP * N_HC * 2);      // 41 MB
    __half* WpT = (__half*)give((size_t)768 * 256 * 2);
    __half* W1T = (__half*)give((size_t)256 * 1024 * 2);
    __half* W2T = (__half*)give((size_t)1024 * 1024 * 2);
    float* va   = (float*)give((size_t)8 * 256 * 4);
    float* a_s  = (float*)give((size_t)N * N_HEADS * 4);
    float* a_d  = (float*)give((size_t)N * N_HEADS * 4);
    int* deg     = (int*)give((size_t)N * 4);
    int* cursor  = (int*)give((size_t)N * 4);
    int* rowstart= (int*)give((size_t)(N + 1) * 4);
    int* col     = (int*)give((size_t)E * 4);
    int* gstart  = (int*)give((size_t)(N_GRAPHS + 1) * 4);
    float* gpool = (float*)give((size_t)N_GRAPHS * 2048 * 4);
    float* hcls  = (float*)give((size_t)N_GRAPHS * 256 * 4);
    (void)ws_size; (void)n_in; (void)out_size;

    // ---- CSR + prep
    hipMemsetAsync(deg, 0, (size_t)N * 4, stream);
    hipMemsetAsync(cursor, 0, (size_t)N * 4, stream);
    k_deg<<<(E + 255) / 256, 256, 0, stream>>>(dst, E, deg);
    k_scan<<<1, 256, 0, stream>>>(deg, rowstart, N);
    k_fill<<<(E + 255) / 256, 256, 0, stream>>>(src, dst, E, rowstart, cursor, col);
    k_gbounds<<<1, 128, 0, stream>>>(batch, N, gstart);

    k_wtt<<<dim3(256 / 32, 768 / 32), 256, 0, stream>>>(Wp, WpT, 768, 256);
    k_wtt<<<dim3(1024 / 32, 256 / 32), 256, 0, stream>>>(W1, W1T, 256, 1024);
    k_wtt<<<dim3(1024 / 32, 1024 / 32), 256, 0, stream>>>(W2, W2T, 1024, 1024);

    const int MB = MP / 128;   // 157

    // ---- h0 = relu(x @ WpT + bp) fp16 (fused fp32->fp16 A convert)
    k_gemm_x<<<dim3(2, MB), 256, 0, stream>>>(x, WpT, bp, h0, N, 256, 768, 768);

    // ---- layer-1 scores from h0
    k_makeva<<<8, 256, 0, stream>>>(W1T, as1, ad1, va);
    k_score8<<<(N + 3) / 4, 256, 0, stream>>>(h0, va, a_s, a_d, N);

    // ---- layer-1 aggregate in h0-space, then per-head transform by W1 (+bias+ELU)
    k_gat_w1<<<(N + 1) / 2, 256, 0, stream>>>(h0, a_s, a_d, rowstart, col, agg1, N);
    k_gemm_h<2><<<dim3(2, MB, 4), 256, 0, stream>>>(
        agg1, W1T, b1, h1, N, 256, 256, 1024, 1024, 256, 65536, 256, 256);

    // ---- layer 2
    k_gemm_h<0><<<dim3(8, MB, 1), 256, 0, stream>>>(
        h1, W2T, nullptr, hW2, N, 1024, 1024, 1024, 1024, 0, 0, 0, 0);
    k_scores16<<<N, 256, 0, stream>>>(hW2, as2, ad2, a_s, a_d, N);
    k_gat_w2<<<(N + 1) / 2, 256, 0, stream>>>(hW2, a_s, a_d, rowstart, col, b2, h2, N);

    // ---- pooling + classifier
    k_pool<<<dim3(N_GRAPHS, 4), 128, 0, stream>>>(h2, gstart, gpool);
    k_cls1<<<N_GRAPHS, 256, 0, stream>>>(gpool, Wc1, bc1, hcls);
    k_cls2<<<2, 256, 0, stream>>>(hcls, Wc2, bc2, out);
}

// Round 8
// 553.201 us; speedup vs baseline: 2.6461x; 1.0152x over previous
//
#include <hip/hip_runtime.h>
#include <hip/hip_fp16.h>
#include <math.h>

#define N_HID 256
#define N_HEADS 4
#define N_HC 1024
#define N_GRAPHS 64

typedef __attribute__((ext_vector_type(4))) float f32x4;
typedef _Float16 half8 __attribute__((ext_vector_type(8)));
typedef _Float16 half4 __attribute__((ext_vector_type(4)));

__device__ __forceinline__ void gl_lds16h(const __half* g, __half* l) {
    __builtin_amdgcn_global_load_lds(
        (const __attribute__((address_space(1))) unsigned int*)g,
        (__attribute__((address_space(3))) unsigned int*)l, 16, 0, 0);
}

// ---------------------------------------------------------------- CSR build
__global__ __launch_bounds__(256) void k_deg(const int* __restrict__ dst, int E,
                                             int* __restrict__ deg) {
    int e = blockIdx.x * 256 + threadIdx.x;
    if (e < E) atomicAdd(&deg[dst[e]], 1);
}

__global__ __launch_bounds__(1024) void k_scan(const int* __restrict__ deg,
                                               int* __restrict__ rowstart, int N) {
    __shared__ int part[1024];
    const int t = threadIdx.x;
    const int chunk = (N + 1023) / 1024;
    const int c0 = t * chunk;
    int s = 0;
    for (int i = 0; i < chunk; i++) {
        int idx = c0 + i;
        if (idx < N) s += deg[idx];
    }
    part[t] = s;
    __syncthreads();
    for (int off = 1; off < 1024; off <<= 1) {
        int v = (t >= off) ? part[t - off] : 0;
        __syncthreads();
        part[t] += v;
        __syncthreads();
    }
    int run = (t == 0) ? 0 : part[t - 1];
    if (t == 0) rowstart[0] = 0;
    for (int i = 0; i < chunk; i++) {
        int idx = c0 + i;
        if (idx < N) {
            run += deg[idx];
            rowstart[idx + 1] = run;
        }
    }
}

__global__ __launch_bounds__(256) void k_fill(const int* __restrict__ src,
                                              const int* __restrict__ dst, int E,
                                              const int* __restrict__ rowstart,
                                              int* __restrict__ cursor,
                                              int* __restrict__ col) {
    int e = blockIdx.x * 256 + threadIdx.x;
    if (e < E) {
        int d = dst[e];
        int p = atomicAdd(&cursor[d], 1);
        col[rowstart[d] + p] = src[e];
    }
}

// ---------------------------------------------------------------- tiled transpose fp32[K][N] -> fp16[N][K]
__global__ __launch_bounds__(256) void k_wtt(const float* __restrict__ W,
                                             __half* __restrict__ WT, int K, int N) {
    __shared__ float tile[32][33];
    const int k0 = blockIdx.y * 32, n0 = blockIdx.x * 32;
    const int tr = threadIdx.x >> 5, tc = threadIdx.x & 31;
#pragma unroll
    for (int rr = 0; rr < 4; rr++) {
        int k = k0 + tr + rr * 8;
        tile[tr + rr * 8][tc] = W[(size_t)k * N + n0 + tc];
    }
    __syncthreads();
#pragma unroll
    for (int rr = 0; rr < 4; rr++) {
        int n = n0 + tr + rr * 8;
        WT[(size_t)n * K + k0 + tc] = __float2half(tile[tc][tr + rr * 8]);
    }
}

// ---------------------------------------------------------------- va = W1_h @ att_h (from W1T fp16)
__global__ __launch_bounds__(256) void k_makeva(const __half* __restrict__ W1T,
                                                const float* __restrict__ as1,
                                                const float* __restrict__ ad1,
                                                float* __restrict__ va) {
    __shared__ float satt[256];
    int b = blockIdx.x;       // 0..7
    int h = b & 3, isd = b >> 2;
    int k = threadIdx.x;      // 0..255
    const float* att = (isd ? ad1 : as1) + h * 256;
    satt[k] = att[k];
    __syncthreads();
    const __half* wr = W1T + (size_t)(h * 256) * 256 + k;
    float s = 0.f;
    for (int c = 0; c < 256; c++) s += __half2float(wr[(size_t)c * 256]) * satt[c];
    va[b * 256 + k] = s;
}

// ---------------------------------------------------------------- fp16 MFMA GEMM (3D grid, W1 transform)
template <int EPI>
__global__ __launch_bounds__(256) void k_gemm_h(
    const __half* __restrict__ A, const __half* __restrict__ BT,
    const float* __restrict__ bias, __half* __restrict__ C,
    int M, int N, int K, int lda, int ldc,
    int aoffz, int boffz, int coffz, int bofz) {
    __shared__ __half sA[128 * 32];
    __shared__ __half sB[128 * 32];
    const int z = blockIdx.z;
    A += (size_t)z * aoffz;
    BT += (size_t)z * boffz;
    const int bm = blockIdx.y * 128, bn = blockIdx.x * 128;
    const int tid = threadIdx.x, lane = tid & 63, w = tid >> 6;
    const int wr = (w >> 1) * 64, wc = (w & 1) * 64;
    const bool isB = (w >= 2);
    const __half* gsrc = isB ? (BT + (size_t)bn * K) : (A + (size_t)bm * lda);
    const int glda = isB ? K : lda;
    __half* sbuf = isB ? sB : sA;
    const int rbase = (w & 1) * 64;
    const int lr = lane >> 2;
    const int lsl = lane & 3;

    f32x4 acc[4][4] = {};

    for (int k0 = 0; k0 < K; k0 += 32) {
#pragma unroll
        for (int c = 0; c < 4; c++) {
            int row = rbase + c * 16 + lr;
            int slg = lsl ^ ((row >> 1) & 3);
            gl_lds16h(gsrc + (size_t)row * glda + k0 + slg * 8,
                      sbuf + (rbase + c * 16) * 32);
        }
        __syncthreads();
        half8 af[4], bf[4];
        const int g = lane >> 4, fr = lane & 15;
#pragma unroll
        for (int i = 0; i < 4; i++) {
            int Ra = wr + i * 16 + fr;
            af[i] = *reinterpret_cast<const half8*>(
                &sA[Ra * 32 + ((g ^ ((Ra >> 1) & 3)) << 3)]);
            int Rb = wc + i * 16 + fr;
            bf[i] = *reinterpret_cast<const half8*>(
                &sB[Rb * 32 + ((g ^ ((Rb >> 1) & 3)) << 3)]);
        }
#pragma unroll
        for (int i = 0; i < 4; i++)
#pragma unroll
            for (int j = 0; j < 4; j++)
                acc[i][j] = __builtin_amdgcn_mfma_f32_16x16x32_f16(af[i], bf[j], acc[i][j], 0, 0, 0);
        __syncthreads();
    }
    const int crow0 = (lane >> 4) * 4, ccol = lane & 15;
    const size_t coff = (size_t)z * coffz;
#pragma unroll
    for (int i = 0; i < 4; i++)
#pragma unroll
        for (int j = 0; j < 4; j++) {
            int cc = bn + wc + j * 16 + ccol;
            float bv = 0.f;
            if (EPI != 0) bv = bias[z * bofz + cc];
#pragma unroll
            for (int r = 0; r < 4; r++) {
                int row = bm + wr + i * 16 + crow0 + r;
                if (row < M) {
                    float v = acc[i][j][r];
                    if (EPI == 2) { v += bv; v = v > 0.f ? v : (__expf(v) - 1.f); }
                    C[(size_t)row * ldc + coff + cc] = __float2half(v);
                }
            }
        }
}

// ---------------------------------------------------------------- W2 GEMM, XCD co-scheduled, fused layer-2 scores
// hW2 = h1 @ W2T (K=N=1024). All 8 col-blocks of a row-stripe land on one XCD
// (bid%8 == const) so the A-stripe is fetched into that XCD's L2 once.
// Epilogue: partial a_s2/a_d2 dots (16-lane shuffle reduce + atomicAdd).
__global__ __launch_bounds__(256) void k_gemm_w2(
    const __half* __restrict__ A, const __half* __restrict__ BT,
    const float* __restrict__ as2, const float* __restrict__ ad2,
    __half* __restrict__ C, float* __restrict__ a_s, float* __restrict__ a_d,
    int M, int NROW) {
    constexpr int K = 1024;
    __shared__ __half sA[128 * 32];
    __shared__ __half sB[128 * 32];
    const int bid = blockIdx.x;
    const int xcd = bid & 7, j0 = bid >> 3;
    const int br = xcd + 8 * (j0 >> 3);
    const int bc = j0 & 7;
    if (br >= NROW) return;
    const int bm = br * 128, bn = bc * 128;
    const int tid = threadIdx.x, lane = tid & 63, w = tid >> 6;
    const int wr = (w >> 1) * 64, wc = (w & 1) * 64;
    const bool isB = (w >= 2);
    const __half* gsrc = isB ? (BT + (size_t)bn * K) : (A + (size_t)bm * K);
    __half* sbuf = isB ? sB : sA;
    const int rbase = (w & 1) * 64;
    const int lr = lane >> 2;
    const int lsl = lane & 3;

    f32x4 acc[4][4] = {};

    for (int k0 = 0; k0 < K; k0 += 32) {
#pragma unroll
        for (int c = 0; c < 4; c++) {
            int row = rbase + c * 16 + lr;
            int slg = lsl ^ ((row >> 1) & 3);
            gl_lds16h(gsrc + (size_t)row * K + k0 + slg * 8,
                      sbuf + (rbase + c * 16) * 32);
        }
        __syncthreads();
        half8 af[4], bf[4];
        const int g = lane >> 4, fr = lane & 15;
#pragma unroll
        for (int i = 0; i < 4; i++) {
            int Ra = wr + i * 16 + fr;
            af[i] = *reinterpret_cast<const half8*>(
                &sA[Ra * 32 + ((g ^ ((Ra >> 1) & 3)) << 3)]);
            int Rb = wc + i * 16 + fr;
            bf[i] = *reinterpret_cast<const half8*>(
                &sB[Rb * 32 + ((g ^ ((Rb >> 1) & 3)) << 3)]);
        }
#pragma unroll
        for (int i = 0; i < 4; i++)
#pragma unroll
            for (int j = 0; j < 4; j++)
                acc[i][j] = __builtin_amdgcn_mfma_f32_16x16x32_f16(af[i], bf[j], acc[i][j], 0, 0, 0);
        __syncthreads();
    }
    const int crow0 = (lane >> 4) * 4, ccol = lane & 15;
    const int h = bn >> 8;   // 128-col tile never straddles a 256 head boundary
    float asv[4], adv[4];
#pragma unroll
    for (int j = 0; j < 4; j++) {
        int cc = bn + wc + j * 16 + ccol;
        asv[j] = as2[cc];
        adv[j] = ad2[cc];
    }
#pragma unroll
    for (int i = 0; i < 4; i++)
#pragma unroll
        for (int r = 0; r < 4; r++) {
            int row = bm + wr + i * 16 + crow0 + r;
            float ps = 0.f, pd = 0.f;
#pragma unroll
            for (int j = 0; j < 4; j++) {
                float v = acc[i][j][r];
                ps += v * asv[j];
                pd += v * adv[j];
            }
#pragma unroll
            for (int off = 1; off < 16; off <<= 1) {
                ps += __shfl_xor(ps, off, 64);
                pd += __shfl_xor(pd, off, 64);
            }
            if ((lane & 15) == 0 && row < M) {
                atomicAdd(&a_s[row * 4 + h], ps);
                atomicAdd(&a_d[row * 4 + h], pd);
            }
        }
#pragma unroll
    for (int i = 0; i < 4; i++)
#pragma unroll
        for (int j = 0; j < 4; j++) {
            int cc = bn + wc + j * 16 + ccol;
#pragma unroll
            for (int r = 0; r < 4; r++) {
                int row = bm + wr + i * 16 + crow0 + r;
                if (row < M) C[(size_t)row * 1024 + cc] = __float2half(acc[i][j][r]);
            }
        }
}

// ---------------------------------------------------------------- fp32-A MFMA GEMM (fused convert), bias+relu
// XCD co-scheduled: both col-blocks of a row-stripe on one XCD.
__global__ __launch_bounds__(256) void k_gemm_x(
    const float* __restrict__ A, const __half* __restrict__ BT,
    const float* __restrict__ bias, __half* __restrict__ C,
    int M, int NROW, int K, int lda) {
    __shared__ __half sA[128 * 32];
    __shared__ __half sB[128 * 32];
    const int bid = blockIdx.x;
    const int xcd = bid & 7, j0 = bid >> 3;
    const int br = xcd + 8 * (j0 >> 1);
    const int bc = j0 & 1;
    if (br >= NROW) return;
    const int bm = br * 128, bn = bc * 128;
    const int tid = threadIdx.x, lane = tid & 63, w = tid >> 6;
    const int wr = (w >> 1) * 64, wc = (w & 1) * 64;
    const int sm = tid >> 1, skb = (tid & 1) * 16;
    const bool rok = (bm + sm) < M;
    const int ph0 = (((tid & 1) * 2 + 0) ^ ((sm >> 1) & 3)) << 3;
    const int ph1 = (((tid & 1) * 2 + 1) ^ ((sm >> 1) & 3)) << 3;
    const int lr = lane >> 2, lsl = lane & 3;

    f32x4 acc[4][4] = {};

    for (int k0 = 0; k0 < K; k0 += 32) {
#pragma unroll
        for (int c = 0; c < 2; c++) {
            int rb = (w + c * 4) * 16;
            int row = rb + lr;
            int slg = lsl ^ ((row >> 1) & 3);
            gl_lds16h(BT + (size_t)(bn + row) * K + k0 + slg * 8, sB + rb * 32);
        }
        {
            const float* Arow = A + (size_t)(bm + sm) * lda + k0 + skb;
            float4 v0 = make_float4(0.f, 0.f, 0.f, 0.f), v1 = v0, v2 = v0, v3 = v0;
            if (rok) {
                v0 = *(const float4*)(Arow + 0);
                v1 = *(const float4*)(Arow + 4);
                v2 = *(const float4*)(Arow + 8);
                v3 = *(const float4*)(Arow + 12);
            }
            half8 ha, hb;
            ha[0] = (_Float16)v0.x; ha[1] = (_Float16)v0.y;
            ha[2] = (_Float16)v0.z; ha[3] = (_Float16)v0.w;
            ha[4] = (_Float16)v1.x; ha[5] = (_Float16)v1.y;
            ha[6] = (_Float16)v1.z; ha[7] = (_Float16)v1.w;
            hb[0] = (_Float16)v2.x; hb[1] = (_Float16)v2.y;
            hb[2] = (_Float16)v2.z; hb[3] = (_Float16)v2.w;
            hb[4] = (_Float16)v3.x; hb[5] = (_Float16)v3.y;
            hb[6] = (_Float16)v3.z; hb[7] = (_Float16)v3.w;
            *reinterpret_cast<half8*>(&sA[sm * 32 + ph0]) = ha;
            *reinterpret_cast<half8*>(&sA[sm * 32 + ph1]) = hb;
        }
        __syncthreads();
        half8 af[4], bf[4];
        const int g = lane >> 4, fr = lane & 15;
#pragma unroll
        for (int i = 0; i < 4; i++) {
            int Ra = wr + i * 16 + fr;
            af[i] = *reinterpret_cast<const half8*>(
                &sA[Ra * 32 + ((g ^ ((Ra >> 1) & 3)) << 3)]);
            int Rb = wc + i * 16 + fr;
            bf[i] = *reinterpret_cast<const half8*>(
                &sB[Rb * 32 + ((g ^ ((Rb >> 1) & 3)) << 3)]);
        }
#pragma unroll
        for (int i = 0; i < 4; i++)
#pragma unroll
            for (int j = 0; j < 4; j++)
                acc[i][j] = __builtin_amdgcn_mfma_f32_16x16x32_f16(af[i], bf[j], acc[i][j], 0, 0, 0);
        __syncthreads();
    }
    const int crow0 = (lane >> 4) * 4, ccol = lane & 15;
#pragma unroll
    for (int i = 0; i < 4; i++)
#pragma unroll
        for (int j = 0; j < 4; j++) {
            int cc = bn + wc + j * 16 + ccol;
            float bv = bias[cc];
#pragma unroll
            for (int r = 0; r < 4; r++) {
                int row = bm + wr + i * 16 + crow0 + r;
                if (row < M) {
                    float v = acc[i][j][r] + bv;
                    v = v > 0.f ? v : 0.f;
                    C[(size_t)row * 256 + cc] = __float2half(v);
                }
            }
        }
}

// ---------------------------------------------------------------- scores from h0 (256-wide fp16)
__global__ __launch_bounds__(256) void k_score8(const __half* __restrict__ h0,
                                                const float* __restrict__ va,
                                                float* __restrict__ a_s,
                                                float* __restrict__ a_d, int N) {
    __shared__ float sva[8][256];
    int t = threadIdx.x;
    for (int i = t; i < 2048; i += 256) sva[i >> 8][i & 255] = va[i];
    __syncthreads();
    int wv = t >> 6, lane = t & 63;
    int n = blockIdx.x * 4 + wv;
    if (n >= N) return;
    uint2 u = *(const uint2*)(h0 + (size_t)n * 256 + lane * 4);
    __half2 q0 = __builtin_bit_cast(__half2, u.x);
    __half2 q1 = __builtin_bit_cast(__half2, u.y);
    float v0 = __half2float(q0.x), v1 = __half2float(q0.y);
    float v2 = __half2float(q1.x), v3 = __half2float(q1.y);
    float p[8];
#pragma unroll
    for (int v = 0; v < 8; v++) {
        p[v] = v0 * sva[v][lane * 4] + v1 * sva[v][lane * 4 + 1] +
               v2 * sva[v][lane * 4 + 2] + v3 * sva[v][lane * 4 + 3];
    }
#pragma unroll
    for (int off = 32; off > 0; off >>= 1)
#pragma unroll
        for (int v = 0; v < 8; v++) p[v] += __shfl_xor(p[v], off, 64);
    if (lane == 0) {
        *(float4*)&a_s[n * 4] = make_float4(p[0], p[1], p[2], p[3]);
        *(float4*)&a_d[n * 4] = make_float4(p[4], p[5], p[6], p[7]);
    }
}

// ---------------------------------------------------------------- GAT layer-1 gather
__global__ __launch_bounds__(256) void k_gat_w1(
    const __half* __restrict__ h0, const float* __restrict__ a_s,
    const float* __restrict__ a_d, const int* __restrict__ rowstart,
    const int* __restrict__ col, __half* __restrict__ agg1, int N) {
    __shared__ int wsn[4][64];
    __shared__ float wal[4][64][2];
    const int w = threadIdx.x >> 6, lane = threadIdx.x & 63;
    const int ni = w >> 1, q = w & 1;
    const int n = blockIdx.x * 2 + ni;
    if (n >= N) return;
    const int hh0 = q * 2;
    const int e0 = rowstart[n];
    const int deg = rowstart[n + 1] - e0;
    const int tot = deg + 1;
    const float adv0 = a_d[n * 4 + hh0], adv1 = a_d[n * 4 + hh0 + 1];
    float M0 = -INFINITY, M1 = -INFINITY, S0 = 0.f, S1 = 0.f;
    float acc0[4] = {}, acc1[4] = {};

    for (int base = 0; base < tot; base += 64) {
        const int cnt = min(64, tot - base);
        const bool act = lane < cnt;
        int sn = n;
        float ev0 = -INFINITY, ev1 = -INFINITY;
        if (act) {
            const int li = base + lane;
            sn = (li < deg) ? col[e0 + li] : n;
            float s0 = a_s[sn * 4 + hh0] + adv0;
            float s1 = a_s[sn * 4 + hh0 + 1] + adv1;
            ev0 = s0 >= 0.f ? s0 : 0.2f * s0;
            ev1 = s1 >= 0.f ? s1 : 0.2f * s1;
        }
        float m0 = ev0, m1 = ev1;
#pragma unroll
        for (int off = 32; off > 0; off >>= 1) {
            m0 = fmaxf(m0, __shfl_xor(m0, off, 64));
            m1 = fmaxf(m1, __shfl_xor(m1, off, 64));
        }
        m0 = fmaxf(m0, M0); m1 = fmaxf(m1, M1);
        float w0 = act ? __expf(ev0 - m0) : 0.f;
        float w1 = act ? __expf(ev1 - m1) : 0.f;
        wsn[w][lane] = sn;
        wal[w][lane][0] = w0;
        wal[w][lane][1] = w1;
        float s0 = w0, s1 = w1;
#pragma unroll
        for (int off = 32; off > 0; off >>= 1) {
            s0 += __shfl_xor(s0, off, 64);
            s1 += __shfl_xor(s1, off, 64);
        }
        float sc0 = __expf(M0 - m0), sc1 = __expf(M1 - m1);
        S0 = S0 * sc0 + s0; S1 = S1 * sc1 + s1;
        M0 = m0; M1 = m1;
#pragma unroll
        for (int c = 0; c < 4; c++) { acc0[c] *= sc0; acc1[c] *= sc1; }
#pragma unroll 2
        for (int i = 0; i < cnt; i++) {
            const int s2 = wsn[w][i];
            const float a0 = wal[w][i][0], a1 = wal[w][i][1];
            uint2 u = *(const uint2*)(h0 + (size_t)s2 * 256 + lane * 4);
            __half2 p0 = __builtin_bit_cast(__half2, u.x);
            __half2 p1 = __builtin_bit_cast(__half2, u.y);
            const float v[4] = {__half2float(p0.x), __half2float(p0.y),
                                __half2float(p1.x), __half2float(p1.y)};
#pragma unroll
            for (int c = 0; c < 4; c++) {
                acc0[c] += a0 * v[c];
                acc1[c] += a1 * v[c];
            }
        }
    }
    const float d0 = 1.f / (S0 + 1e-16f), d1 = 1.f / (S1 + 1e-16f);
    half4 o0, o1;
#pragma unroll
    for (int c = 0; c < 4; c++) {
        o0[c] = (_Float16)(acc0[c] * d0);
        o1[c] = (_Float16)(acc1[c] * d1);
    }
    *reinterpret_cast<half4*>(agg1 + (size_t)n * 1024 + hh0 * 256 + lane * 4) = o0;
    *reinterpret_cast<half4*>(agg1 + (size_t)n * 1024 + (hh0 + 1) * 256 + lane * 4) = o1;
}

// ---------------------------------------------------------------- GAT layer-2 gather
__global__ __launch_bounds__(256) void k_gat_w2(
    const __half* __restrict__ hW, const float* __restrict__ a_s,
    const float* __restrict__ a_d, const int* __restrict__ rowstart,
    const int* __restrict__ col, const float* __restrict__ bias,
    __half* __restrict__ h2, int N) {
    __shared__ int wsn[4][64];
    __shared__ float wal[4][64][2];
    const int w = threadIdx.x >> 6, lane = threadIdx.x & 63;
    const int ni = w >> 1, q = w & 1;
    const int n = blockIdx.x * 2 + ni;
    if (n >= N) return;
    const int hh0 = q * 2;
    const int hiq = lane >> 5;
    const int e0 = rowstart[n];
    const int deg = rowstart[n + 1] - e0;
    const int tot = deg + 1;
    const float adv0 = a_d[n * 4 + hh0], adv1 = a_d[n * 4 + hh0 + 1];
    float M0 = -INFINITY, M1 = -INFINITY, S0 = 0.f, S1 = 0.f;
    float acc[8] = {};

    for (int base = 0; base < tot; base += 64) {
        const int cnt = min(64, tot - base);
        const bool act = lane < cnt;
        int sn = n;
        float ev0 = -INFINITY, ev1 = -INFINITY;
        if (act) {
            const int li = base + lane;
            sn = (li < deg) ? col[e0 + li] : n;
            float s0 = a_s[sn * 4 + hh0] + adv0;
            float s1 = a_s[sn * 4 + hh0 + 1] + adv1;
            ev0 = s0 >= 0.f ? s0 : 0.2f * s0;
            ev1 = s1 >= 0.f ? s1 : 0.2f * s1;
        }
        float m0 = ev0, m1 = ev1;
#pragma unroll
        for (int off = 32; off > 0; off >>= 1) {
            m0 = fmaxf(m0, __shfl_xor(m0, off, 64));
            m1 = fmaxf(m1, __shfl_xor(m1, off, 64));
        }
        m0 = fmaxf(m0, M0); m1 = fmaxf(m1, M1);
        float w0 = act ? __expf(ev0 - m0) : 0.f;
        float w1 = act ? __expf(ev1 - m1) : 0.f;
        wsn[w][lane] = sn;
        wal[w][lane][0] = w0;
        wal[w][lane][1] = w1;
        float s0 = w0, s1 = w1;
#pragma unroll
        for (int off = 32; off > 0; off >>= 1) {
            s0 += __shfl_xor(s0, off, 64);
            s1 += __shfl_xor(s1, off, 64);
        }
        float sc0 = __expf(M0 - m0), sc1 = __expf(M1 - m1);
        S0 = S0 * sc0 + s0; S1 = S1 * sc1 + s1;
        M0 = m0; M1 = m1;
        const float accsc = hiq ? sc1 : sc0;
#pragma unroll
        for (int c = 0; c < 8; c++) acc[c] *= accsc;
        const __half* gbase = hW + q * 512 + lane * 8;
#pragma unroll 2
        for (int i = 0; i < cnt; i++) {
            const int s2 = wsn[w][i];
            const float a = wal[w][i][hiq];
            half8 v = *reinterpret_cast<const half8*>(gbase + (size_t)s2 * 1024);
#pragma unroll
            for (int c = 0; c < 8; c++) acc[c] += a * (float)v[c];
        }
    }
    const float S = hiq ? S1 : S0;
    const float d = 1.f / (S + 1e-16f);
    const int chb = q * 512 + lane * 8;
    float4 b0 = *(const float4*)&bias[chb];
    float4 b1 = *(const float4*)&bias[chb + 4];
    const float bb[8] = {b0.x, b0.y, b0.z, b0.w, b1.x, b1.y, b1.z, b1.w};
    half8 o;
#pragma unroll
    for (int c = 0; c < 8; c++) {
        float v = acc[c] * d + bb[c];
        v = v > 0.f ? v : (__expf(v) - 1.f);
        o[c] = (_Float16)v;
    }
    *reinterpret_cast<half8*>(h2 + (size_t)n * 1024 + chb) = o;
}

// ---------------------------------------------------------------- pooling
__global__ __launch_bounds__(128) void k_gbounds(const int* __restrict__ batch, int N,
                                                 int* __restrict__ gstart) {
    int g = threadIdx.x;
    if (g > N_GRAPHS) return;
    if (g == N_GRAPHS) { gstart[N_GRAPHS] = N; return; }
    int lo = 0, hi = N;
    while (lo < hi) {
        int mid = (lo + hi) >> 1;
        if (batch[mid] < g) lo = mid + 1; else hi = mid;
    }
    gstart[g] = lo;
}

__global__ __launch_bounds__(128) void k_pool(const __half* __restrict__ h,
                                              const int* __restrict__ gstart,
                                              float* __restrict__ gout) {
    int g = blockIdx.x, t = threadIdx.x;
    int c = blockIdx.y * 256 + 2 * t;
    int s = gstart[g], e = gstart[g + 1];
    float s0 = 0.f, s1 = 0.f;
    float m0 = -INFINITY, m1 = -INFINITY;
    for (int i = s; i < e; i++) {
        __half2 hv = *(const __half2*)(h + (size_t)i * N_HC + c);
        float v0 = __half2float(hv.x), v1 = __half2float(hv.y);
        s0 += v0; s1 += v1;
        m0 = fmaxf(m0, v0); m1 = fmaxf(m1, v1);
    }
    float cnt = fmaxf((float)(e - s), 1.f);
    *(float2*)(gout + (size_t)g * 2048 + c) = make_float2(s0 / cnt, s1 / cnt);
    *(float2*)(gout + (size_t)g * 2048 + 1024 + c) = make_float2(m0, m1);
}

// ---------------------------------------------------------------- classifier
__global__ __launch_bounds__(256) void k_cls1(const float* __restrict__ g,
                                              const float* __restrict__ Wc1,
                                              const float* __restrict__ bc1,
                                              float* __restrict__ hcls) {
    __shared__ float gs[2048];
    int gb = blockIdx.x, t = threadIdx.x;
    for (int i = t; i < 2048; i += 256) gs[i] = g[(size_t)gb * 2048 + i];
    __syncthreads();
    float acc = 0.f;
    for (int k = 0; k < 2048; k++) acc += gs[k] * Wc1[(size_t)k * 256 + t];
    float v = acc + bc1[t];
    hcls[gb * 256 + t] = v > 0.f ? v : 0.f;
}

__global__ __launch_bounds__(256) void k_cls2(const float* __restrict__ hcls,
                                              const float* __restrict__ Wc2,
                                              const float* __restrict__ bc2,
                                              float* __restrict__ out) {
    int idx = blockIdx.x * 256 + threadIdx.x;
    if (idx >= N_GRAPHS * 5) return;
    int gb = idx / 5, j = idx % 5;
    float acc = 0.f;
    for (int k = 0; k < 256; k++) acc += hcls[gb * 256 + k] * Wc2[k * 5 + j];
    out[idx] = acc + bc2[j];
}

// ---------------------------------------------------------------- launch
extern "C" void kernel_launch(void* const* d_in, const int* in_sizes, int n_in,
                              void* d_out, int out_size, void* d_ws, size_t ws_size,
                              hipStream_t stream) {
    const float* x    = (const float*)d_in[0];
    const int*   ei   = (const int*)d_in[1];
    const int*   batch= (const int*)d_in[2];
    const float* Wp   = (const float*)d_in[3];
    const float* bp   = (const float*)d_in[4];
    const float* W1   = (const float*)d_in[5];
    const float* as1  = (const float*)d_in[6];
    const float* ad1  = (const float*)d_in[7];
    const float* b1   = (const float*)d_in[8];
    const float* W2   = (const float*)d_in[9];
    const float* as2  = (const float*)d_in[10];
    const float* ad2  = (const float*)d_in[11];
    const float* b2   = (const float*)d_in[12];
    const float* Wc1  = (const float*)d_in[13];
    const float* bc1  = (const float*)d_in[14];
    const float* Wc2  = (const float*)d_in[15];
    const float* bc2  = (const float*)d_in[16];
    float* out = (float*)d_out;

    const int N = in_sizes[0] / 768;   // 20000
    const int E = in_sizes[1] / 2;     // 320000
    const int MP = ((N + 127) / 128) * 128;   // 20096
    const int MB = MP / 128;                  // 157

    const int* src = ei;
    const int* dst = ei + E;

    char* ws = (char*)d_ws;
    size_t off = 0;
    auto give = [&](size_t bytes) -> void* {
        void* p = ws + off;
        off = (off + bytes + 255) & ~(size_t)255;
        return p;
    };
    __half* h0  = (__half*)give((size_t)MP * N_HID * 2);
    __half* agg1= (__half*)give((size_t)MP * N_HC * 2);
    __half* h1  = (__half*)give((size_t)MP * N_HC * 2);
    __half* hW2 = (__half*)give((size_t)MP * N_HC * 2);
    __half* h2  = (__half*)give((size_t)MP * N_HC * 2);
    __half* WpT = (__half*)give((size_t)768 * 256 * 2);
    __half* W1T = (__half*)give((size_t)256 * 1024 * 2);
    __half* W2T = (__half*)give((size_t)1024 * 1024 * 2);
    float* va   = (float*)give((size_t)8 * 256 * 4);
    float* a_s1 = (float*)give((size_t)N * N_HEADS * 4);
    float* a_d1 = (float*)give((size_t)N * N_HEADS * 4);
    float* a_s2 = (float*)give((size_t)N * N_HEADS * 4);
    float* a_d2 = (float*)give((size_t)N * N_HEADS * 4);
    int* deg     = (int*)give((size_t)N * 4);
    int* cursor  = (int*)give((size_t)N * 4);
    int* rowstart= (int*)give((size_t)(N + 1) * 4);
    int* col     = (int*)give((size_t)E * 4);
    int* gstart  = (int*)give((size_t)(N_GRAPHS + 1) * 4);
    float* gpool = (float*)give((size_t)N_GRAPHS * 2048 * 4);
    float* hcls  = (float*)give((size_t)N_GRAPHS * 256 * 4);
    (void)ws_size; (void)n_in; (void)out_size;

    // ---- CSR + prep
    hipMemsetAsync(deg, 0, (size_t)N * 4, stream);
    hipMemsetAsync(cursor, 0, (size_t)N * 4, stream);
    hipMemsetAsync(a_s2, 0, (size_t)N * N_HEADS * 4, stream);
    hipMemsetAsync(a_d2, 0, (size_t)N * N_HEADS * 4, stream);
    k_deg<<<(E + 255) / 256, 256, 0, stream>>>(dst, E, deg);
    k_scan<<<1, 1024, 0, stream>>>(deg, rowstart, N);
    k_fill<<<(E + 255) / 256, 256, 0, stream>>>(src, dst, E, rowstart, cursor, col);
    k_gbounds<<<1, 128, 0, stream>>>(batch, N, gstart);

    k_wtt<<<dim3(256 / 32, 768 / 32), 256, 0, stream>>>(Wp, WpT, 768, 256);
    k_wtt<<<dim3(1024 / 32, 256 / 32), 256, 0, stream>>>(W1, W1T, 256, 1024);
    k_wtt<<<dim3(1024 / 32, 1024 / 32), 256, 0, stream>>>(W2, W2T, 1024, 1024);
    k_makeva<<<8, 256, 0, stream>>>(W1T, as1, ad1, va);

    const int NROWPAD = ((MB + 7) / 8) * 8;   // 160

    // ---- h0 = relu(x @ WpT + bp) fp16 (co-scheduled grid, 2 col-blocks)
    k_gemm_x<<<NROWPAD * 2, 256, 0, stream>>>(x, WpT, bp, h0, N, MB, 768, 768);

    // ---- layer-1 scores + aggregate + per-head transform
    k_score8<<<(N + 3) / 4, 256, 0, stream>>>(h0, va, a_s1, a_d1, N);
    k_gat_w1<<<(N + 1) / 2, 256, 0, stream>>>(h0, a_s1, a_d1, rowstart, col, agg1, N);
    k_gemm_h<2><<<dim3(2, MB, 4), 256, 0, stream>>>(
        agg1, W1T, b1, h1, N, 256, 256, 1024, 1024, 256, 65536, 256, 256);

    // ---- layer 2: hW2 = h1 @ W2T with fused scores (co-scheduled grid)
    k_gemm_w2<<<NROWPAD * 8, 256, 0, stream>>>(
        h1, W2T, as2, ad2, hW2, a_s2, a_d2, N, MB);
    k_gat_w2<<<(N + 1) / 2, 256, 0, stream>>>(hW2, a_s2, a_d2, rowstart, col, b2, h2, N);

    // ---- pooling + classifier
    k_pool<<<dim3(N_GRAPHS, 4), 128, 0, stream>>>(h2, gstart, gpool);
    k_cls1<<<N_GRAPHS, 256, 0, stream>>>(gpool, Wc1, bc1, hcls);
    k_cls2<<<2, 256, 0, stream>>>(hcls, Wc2, bc2, out);
}